// Round 7
// baseline (1263.773 us; speedup 1.0000x reference)
//
#include <hip/hip_runtime.h>

// Problem constants (match reference)
constexpr int Bz = 8192;   // batch
constexpr int Sz = 115;    // state dim
constexpr int Ez = 3072;   // embedding dim
constexpr int NEz = 4096;  // num keys
// C=128, A=23, K=10, TAU=1, EPS=1e-5

typedef __attribute__((ext_vector_type(8))) short short8;
typedef __attribute__((ext_vector_type(4))) float floatx4;
typedef unsigned short ushort_t;
typedef unsigned int uint_t;

__device__ __forceinline__ ushort_t f2bf(float f) {
  uint_t u = __float_as_uint(f);
  uint_t r = (u + 0x7FFFu + ((u >> 16) & 1u)) >> 16;   // RNE
  return (ushort_t)r;
}
__device__ __forceinline__ float bf2f(ushort_t b) {
  uint_t u = ((uint_t)b) << 16;
  return __uint_as_float(u);
}
// fp32 -> fp16 -> order-preserving u16 key (monotone total order)
__device__ __forceinline__ ushort_t f2key(float v) {
  _Float16 h = (_Float16)v;
  ushort_t b = __builtin_bit_cast(ushort_t, h);
  return b ^ ((b & 0x8000u) ? 0xFFFFu : 0x8000u);
}
__device__ __forceinline__ uint_t umax_(uint_t a, uint_t b) { return a > b ? a : b; }

// async global->LDS, 16 B per lane; lds dest = wave-uniform base + lane*16
__device__ __forceinline__ void gload16(const ushort_t* g, ushort_t* l) {
  __builtin_amdgcn_global_load_lds(
      (__attribute__((address_space(1))) const void*)g,
      (__attribute__((address_space(3))) void*)l, 16, 0, 0);
}

// =====================================================================
// Generic fp32 tiled GEMM: C = act(A@B + bias). Used for critic L2 + fallback.
// =====================================================================
template<bool RELU, bool BIAS>
__global__ __launch_bounds__(256)
void gemm128(const float* __restrict__ A, const float* __restrict__ Bm,
             const float* __restrict__ bias, float* __restrict__ C,
             int N, int Kd)
{
  __shared__ float As[16][132];
  __shared__ float Bs[16][132];
  const int t  = threadIdx.x;
  const int tx = t & 15, ty = t >> 4;
  const int row0 = blockIdx.y * 128;
  const int col0 = blockIdx.x * 128;
  const int ar = t >> 2, ac = (t & 3) * 4;
  const int bk = t >> 5, bc = (t & 31) * 4;
  const bool a4 = (Kd & 3) == 0;

  float acc[8][8];
#pragma unroll
  for (int i = 0; i < 8; ++i)
#pragma unroll
    for (int j = 0; j < 8; ++j) acc[i][j] = 0.f;

  for (int k0 = 0; k0 < Kd; k0 += 16) {
    const bool fullA = (k0 + 16 <= Kd) && a4;
    {
      const float* ap = A + (size_t)(row0 + ar) * Kd + k0 + ac;
      if (fullA) {
        float4 v0 = *(const float4*)ap;
        float4 v1 = *(const float4*)(ap + (size_t)64 * Kd);
        As[ac + 0][ar] = v0.x; As[ac + 1][ar] = v0.y;
        As[ac + 2][ar] = v0.z; As[ac + 3][ar] = v0.w;
        As[ac + 0][ar + 64] = v1.x; As[ac + 1][ar + 64] = v1.y;
        As[ac + 2][ar + 64] = v1.z; As[ac + 3][ar + 64] = v1.w;
      } else {
#pragma unroll
        for (int e = 0; e < 4; ++e) {
          const int k = k0 + ac + e;
          float v0 = 0.f, v1 = 0.f;
          if (k < Kd) { v0 = ap[e]; v1 = ap[e + (size_t)64 * Kd]; }
          As[ac + e][ar] = v0; As[ac + e][ar + 64] = v1;
        }
      }
    }
    {
      const float* bp = Bm + (size_t)(k0 + bk) * N + col0 + bc;
      if (k0 + 16 <= Kd) {
        *(float4*)&Bs[bk][bc]     = *(const float4*)bp;
        *(float4*)&Bs[bk + 8][bc] = *(const float4*)(bp + (size_t)8 * N);
      } else {
        float4 z; z.x = z.y = z.z = z.w = 0.f;
        *(float4*)&Bs[bk][bc]     = (k0 + bk     < Kd) ? *(const float4*)bp : z;
        *(float4*)&Bs[bk + 8][bc] = (k0 + bk + 8 < Kd) ? *(const float4*)(bp + (size_t)8 * N) : z;
      }
    }
    __syncthreads();
#pragma unroll
    for (int kk = 0; kk < 16; ++kk) {
      float a[8], b[8];
      *(float4*)&a[0] = *(const float4*)&As[kk][ty * 4];
      *(float4*)&a[4] = *(const float4*)&As[kk][64 + ty * 4];
      *(float4*)&b[0] = *(const float4*)&Bs[kk][tx * 4];
      *(float4*)&b[4] = *(const float4*)&Bs[kk][64 + tx * 4];
#pragma unroll
      for (int i = 0; i < 8; ++i)
#pragma unroll
        for (int j = 0; j < 8; ++j)
          acc[i][j] = fmaf(a[i], b[j], acc[i][j]);
    }
    __syncthreads();
  }

  float bv[8];
#pragma unroll
  for (int j = 0; j < 8; ++j) bv[j] = 0.f;
  if (BIAS) {
    *(float4*)&bv[0] = *(const float4*)&bias[col0 + tx * 4];
    *(float4*)&bv[4] = *(const float4*)&bias[col0 + 64 + tx * 4];
  }
#pragma unroll
  for (int i = 0; i < 8; ++i) {
    const int r = row0 + ((i < 4) ? (ty * 4 + i) : (64 + ty * 4 + i - 4));
    float o[8];
#pragma unroll
    for (int j = 0; j < 8; ++j) {
      o[j] = acc[i][j] + bv[j];
      if (RELU) o[j] = fmaxf(o[j], 0.f);
    }
    *(float4*)&C[(size_t)r * N + col0 + tx * 4]      = *(float4*)&o[0];
    *(float4*)&C[(size_t)r * N + col0 + 64 + tx * 4] = *(float4*)&o[4];
  }
}

// =====================================================================
// Dual-part fp32 GEMM+ReLU+bias. Optional fp32 out (C) and bf16 hi/lo
// split outputs (Ch/Cl) — either may be null.
// =====================================================================
struct GPart {
  const float* A; const float* Bm; const float* bias;
  float* C; ushort_t* Ch; ushort_t* Cl;
  int N; int Kd; int nbx;
};

__global__ __launch_bounds__(256)
void gemm128_dual(GPart g0, GPart g1)
{
  __shared__ float As[16][132];
  __shared__ float Bs[16][132];
  const int t  = threadIdx.x;
  const int tx = t & 15, ty = t >> 4;
  const bool p0 = (int)blockIdx.x < g0.nbx;
  GPart g = p0 ? g0 : g1;
  const int bx = p0 ? blockIdx.x : (blockIdx.x - g0.nbx);
  const int row0 = blockIdx.y * 128;
  const int col0 = bx * 128;
  const int Kd = g.Kd, N = g.N;
  const int ar = t >> 2, ac = (t & 3) * 4;
  const int bk = t >> 5, bc = (t & 31) * 4;
  const bool a4 = (Kd & 3) == 0;

  float acc[8][8];
#pragma unroll
  for (int i = 0; i < 8; ++i)
#pragma unroll
    for (int j = 0; j < 8; ++j) acc[i][j] = 0.f;

  for (int k0 = 0; k0 < Kd; k0 += 16) {
    const bool fullA = (k0 + 16 <= Kd) && a4;
    {
      const float* ap = g.A + (size_t)(row0 + ar) * Kd + k0 + ac;
      if (fullA) {
        float4 v0 = *(const float4*)ap;
        float4 v1 = *(const float4*)(ap + (size_t)64 * Kd);
        As[ac + 0][ar] = v0.x; As[ac + 1][ar] = v0.y;
        As[ac + 2][ar] = v0.z; As[ac + 3][ar] = v0.w;
        As[ac + 0][ar + 64] = v1.x; As[ac + 1][ar + 64] = v1.y;
        As[ac + 2][ar + 64] = v1.z; As[ac + 3][ar + 64] = v1.w;
      } else {
#pragma unroll
        for (int e = 0; e < 4; ++e) {
          const int k = k0 + ac + e;
          float v0 = 0.f, v1 = 0.f;
          if (k < Kd) { v0 = ap[e]; v1 = ap[e + (size_t)64 * Kd]; }
          As[ac + e][ar] = v0; As[ac + e][ar + 64] = v1;
        }
      }
    }
    {
      const float* bp = g.Bm + (size_t)(k0 + bk) * N + col0 + bc;
      if (k0 + 16 <= Kd) {
        *(float4*)&Bs[bk][bc]     = *(const float4*)bp;
        *(float4*)&Bs[bk + 8][bc] = *(const float4*)(bp + (size_t)8 * N);
      } else {
        float4 z; z.x = z.y = z.z = z.w = 0.f;
        *(float4*)&Bs[bk][bc]     = (k0 + bk     < Kd) ? *(const float4*)bp : z;
        *(float4*)&Bs[bk + 8][bc] = (k0 + bk + 8 < Kd) ? *(const float4*)(bp + (size_t)8 * N) : z;
      }
    }
    __syncthreads();
#pragma unroll
    for (int kk = 0; kk < 16; ++kk) {
      float a[8], b[8];
      *(float4*)&a[0] = *(const float4*)&As[kk][ty * 4];
      *(float4*)&a[4] = *(const float4*)&As[kk][64 + ty * 4];
      *(float4*)&b[0] = *(const float4*)&Bs[kk][tx * 4];
      *(float4*)&b[4] = *(const float4*)&Bs[kk][64 + tx * 4];
#pragma unroll
      for (int i = 0; i < 8; ++i)
#pragma unroll
        for (int j = 0; j < 8; ++j)
          acc[i][j] = fmaf(a[i], b[j], acc[i][j]);
    }
    __syncthreads();
  }

  float bv[8];
  *(float4*)&bv[0] = *(const float4*)&g.bias[col0 + tx * 4];
  *(float4*)&bv[4] = *(const float4*)&g.bias[col0 + 64 + tx * 4];
#pragma unroll
  for (int i = 0; i < 8; ++i) {
    const int r = row0 + ((i < 4) ? (ty * 4 + i) : (64 + ty * 4 + i - 4));
    float o[8];
#pragma unroll
    for (int j = 0; j < 8; ++j) o[j] = fmaxf(acc[i][j] + bv[j], 0.f);
    const size_t i0 = (size_t)r * N + col0 + tx * 4;
    const size_t i1 = i0 + 64;
    if (g.C) {
      *(float4*)&g.C[i0] = *(float4*)&o[0];
      *(float4*)&g.C[i1] = *(float4*)&o[4];
    }
    if (g.Ch) {
      ushort4 h0, l0, h1, l1;
      h0.x = f2bf(o[0]); l0.x = f2bf(o[0] - bf2f(h0.x));
      h0.y = f2bf(o[1]); l0.y = f2bf(o[1] - bf2f(h0.y));
      h0.z = f2bf(o[2]); l0.z = f2bf(o[2] - bf2f(h0.z));
      h0.w = f2bf(o[3]); l0.w = f2bf(o[3] - bf2f(h0.w));
      h1.x = f2bf(o[4]); l1.x = f2bf(o[4] - bf2f(h1.x));
      h1.y = f2bf(o[5]); l1.y = f2bf(o[5] - bf2f(h1.y));
      h1.z = f2bf(o[6]); l1.z = f2bf(o[6] - bf2f(h1.z));
      h1.w = f2bf(o[7]); l1.w = f2bf(o[7] - bf2f(h1.w));
      *(ushort4*)&g.Ch[i0] = h0; *(ushort4*)&g.Cl[i0] = l0;
      *(ushort4*)&g.Ch[i1] = h1; *(ushort4*)&g.Cl[i1] = l1;
    }
  }
}

// =====================================================================
// bf16 MFMA screen GEMM, 256x256 tile, 8 waves (2Mx4N), BK=64, 8-phase.
// CONSOLIDATION (r4 schedule + r5 race fix): the placement sweep
// r4(after,unpinned)=221µs / r5(before,pinned)=266 / r6(mid,pinned)=241
// shows the compiler interleaves UNPINNED post-cluster reads into the
// MFMA cluster better than any manual pin (m141 lesson re-confirmed).
// Loop body = r4's: full 16-MFMA cluster, then reads, no sched pins
// except the mandatory rule-18 fence after lgkmcnt(0).
// Prologue = r5's race-fixed form: vmcnt(8) -> BARRIER -> first reads
// (own vmcnt says nothing about other waves' DMAs).
// =====================================================================
__global__ __launch_bounds__(512, 2)
void screen256(const ushort_t* __restrict__ A, const ushort_t* __restrict__ B,
               ushort_t* __restrict__ Cout, int N, int Kd)
{
  __shared__ ushort_t AL[2 * 256 * 64];   // 64 KB
  __shared__ ushort_t BL[2 * 256 * 64];   // 64 KB
  const int t = threadIdx.x;
  const int lane = t & 63;
  const int wid = t >> 6;
  const int wr = wid >> 2;        // 0..1  M half of tile
  const int wc = wid & 3;         // 0..3  N quarter of tile
  const int mr = lane & 15, qd = lane >> 4;
  const int row0 = (int)blockIdx.y << 8;
  const int col0 = (int)blockIdx.x << 8;
  const int NT = Kd >> 6;         // 48 K-tiles

  // staging: per-lane inverse-swizzled global source, wave-uniform LDS dest
  const int l8 = lane >> 3;             // row within 8-row region
  const int c8 = (lane & 7) ^ l8;       // source 16B chunk (involution)
  const ushort_t* pA = A + (size_t)(row0 + wr * 128 + wc * 16 + l8) * Kd + c8 * 8;
  const ushort_t* pB = B + (size_t)(col0 + (wid >> 1) * 64 + (wid & 1) * 16 + l8) * Kd + c8 * 8;
  ushort_t* aWp = &AL[wr * 8192 + wc * 1024];
  ushort_t* bWp = &BL[(wid >> 1) * 4096 + (wid & 1) * 1024];

  // fragment reads: same XOR on the read side
  const int swz = (mr & 7) << 4;                  // byte XOR
  const int aRow = (wr * 128 + mr) * 64;
  const int bRow = (wc * 64 + mr) * 64;
  const int cu0 = ((qd * 16) ^ swz) >> 1;         // ksub 0 (ushort units)
  const int cu1 = ((64 + qd * 16) ^ swz) >> 1;    // ksub 1

  floatx4 acc[8][4];
#pragma unroll
  for (int i = 0; i < 8; ++i)
#pragma unroll
    for (int j = 0; j < 4; ++j) acc[i][j] = (floatx4){0.f, 0.f, 0.f, 0.f};

  // double-buffered fragment registers (one-phase-ahead pipeline)
  short8 A0r[4][2], A1r[4][2], B0r[2][2], B1r[2][2];

#define STA(db, h, tile) do {                                            \
    const int kt_ = ((tile) < NT ? (tile) : 0) << 6;                     \
    gload16(pA + (size_t)((h) * 64) * Kd + kt_,                          \
            aWp + (db) * 16384 + (h) * 4096);                            \
    gload16(pA + (size_t)((h) * 64 + 8) * Kd + kt_,                      \
            aWp + (db) * 16384 + (h) * 4096 + 512);                      \
  } while (0)
#define STB(db, g, tile) do {                                            \
    const int kt_ = ((tile) < NT ? (tile) : 0) << 6;                     \
    gload16(pB + (size_t)((g) * 32) * Kd + kt_,                          \
            bWp + (db) * 16384 + (g) * 2048);                            \
    gload16(pB + (size_t)((g) * 32 + 8) * Kd + kt_,                      \
            bWp + (db) * 16384 + (g) * 2048 + 512);                      \
  } while (0)
#define LDAm(dst, db, half)                                              \
  _Pragma("unroll")                                                      \
  for (int i_ = 0; i_ < 4; ++i_) {                                       \
    const int b_ = (db) * 16384 + aRow + ((half) * 4 + i_) * 1024;       \
    dst[i_][0] = *(const short8*)&AL[b_ + cu0];                          \
    dst[i_][1] = *(const short8*)&AL[b_ + cu1];                          \
  }
#define LDBm(dst, db, jh)                                                \
  _Pragma("unroll")                                                      \
  for (int j_ = 0; j_ < 2; ++j_) {                                       \
    const int b_ = (db) * 16384 + bRow + ((jh) * 2 + j_) * 1024;         \
    dst[j_][0] = *(const short8*)&BL[b_ + cu0];                          \
    dst[j_][1] = *(const short8*)&BL[b_ + cu1];                          \
  }
// 16 MFMAs: 8 independent ksub0, then 8 ksub1 accumulating on top
#define MMq(ih, jh, As_, Bs_)                                            \
  _Pragma("unroll")                                                      \
  for (int s_ = 0; s_ < 2; ++s_)                                         \
    _Pragma("unroll")                                                    \
    for (int i_ = 0; i_ < 4; ++i_)                                       \
      _Pragma("unroll")                                                  \
      for (int j_ = 0; j_ < 2; ++j_)                                     \
        acc[(ih)*4+i_][(jh)*2+j_] = __builtin_amdgcn_mfma_f32_16x16x32_bf16( \
            As_[i_][s_], Bs_[j_][s_], acc[(ih)*4+i_][(jh)*2+j_], 0, 0, 0);
#define BARM() do { __builtin_amdgcn_s_barrier();                        \
                    asm volatile("" ::: "memory"); } while (0)
#define WLG()  do { asm volatile("s_waitcnt lgkmcnt(0)" ::: "memory");   \
                    __builtin_amdgcn_sched_barrier(0); } while (0)
#define WVM(n) asm volatile("s_waitcnt vmcnt(" #n ")" ::: "memory")
#define PRIO1() __builtin_amdgcn_s_setprio(1)
#define PRIO0() __builtin_amdgcn_s_setprio(0)
// phase body (r4 form): full MFMA cluster, then UNPINNED reads
#define PHASE(ih, jh, As_, Bs_, READS)                                   \
  do {                                                                   \
    __builtin_amdgcn_s_barrier(); WLG();                                 \
    PRIO1(); MMq(ih, jh, As_, Bs_); PRIO0();                             \
    READS;                                                               \
    BARM();                                                              \
  } while (0)

  // prologue (race-fixed): stage tile0 -> buf0 (8 DMAs), tile1 -> buf1
  // (8 DMAs); own-vmcnt(8) -> BARRIER (all waves' buf0 landed, visible)
  // -> issue p1's fragment reads.
  STA(0, 0, 0); STB(0, 0, 0); STB(0, 1, 0); STA(0, 1, 0);
  STA(1, 0, 1); STB(1, 0, 1); STB(1, 1, 1); STA(1, 1, 1);
  WVM(8);
  BARM();
  LDAm(A0r, 0, 0); LDBm(B0r, 0, 0);

  for (int it = 0; it < NT / 2; ++it) {
    const int tp = it * 2;
    // p1: MM(0,0) buf0; read B1r <- B1(buf0)
    PHASE(0, 0, A0r, B0r, LDBm(B1r, 0, 1));
    // p2: stage buf0{A0,B0} <- tp+2; MM(0,1); read A1r <- A1(buf0)
    STA(0, 0, tp + 2); STB(0, 0, tp + 2);
    PHASE(0, 1, A0r, B1r, LDAm(A1r, 0, 1));
    // p3: stage buf0{B1}; vmcnt(6) -> tile tp+1 (buf1) landed;
    //     MM(1,1); read A0r <- A0(buf1)
    STB(0, 1, tp + 2);
    WVM(6);
    PHASE(1, 1, A1r, B1r, LDAm(A0r, 1, 0));
    // p4: stage buf0{A1}; MM(1,0); read B1r <- B0(buf1)
    STA(0, 1, tp + 2);
    PHASE(1, 0, A1r, B0r, LDBm(B1r, 1, 0));
    // p5: MM(0,0) buf1; read B0r <- B1(buf1)
    PHASE(0, 0, A0r, B1r, LDBm(B0r, 1, 1));
    // p6: stage buf1{A0,B0} <- tp+3; MM(0,1); read A1r <- A1(buf1)
    STA(1, 0, tp + 3); STB(1, 0, tp + 3);
    PHASE(0, 1, A0r, B0r, LDAm(A1r, 1, 1));
    // p7: stage buf1{B1}; vmcnt(6) -> tile tp+2 (buf0) landed;
    //     MM(1,1); read A0r <- A0(buf0, next)
    STB(1, 1, tp + 3);
    WVM(6);
    PHASE(1, 1, A1r, B0r, LDAm(A0r, 0, 0));
    // p8: stage buf1{A1}; MM(1,0); read B0r <- B0(buf0, next)
    STA(1, 1, tp + 3);
    PHASE(1, 0, A1r, B1r, LDBm(B0r, 0, 0));
  }

  // epilogue drain: never exit with LDS-DMA in flight
  asm volatile("s_waitcnt vmcnt(0) lgkmcnt(0)" ::: "memory");
  __syncthreads();

#undef STA
#undef STB
#undef LDAm
#undef LDBm
#undef MMq
#undef PHASE
#undef BARM
#undef WLG
#undef WVM
#undef PRIO1
#undef PRIO0

  // epilogue: C/D layout col=lane&15, row=(lane>>4)*4+reg
#pragma unroll
  for (int i = 0; i < 8; ++i) {
#pragma unroll
    for (int j = 0; j < 4; ++j) {
      const int col = col0 + wc * 64 + j * 16 + mr;
#pragma unroll
      for (int r = 0; r < 4; ++r) {
        const int row = row0 + wr * 128 + i * 16 + qd * 4 + r;
        Cout[(size_t)row * N + col] = f2key(acc[i][j][r]);
      }
    }
  }
}

// =====================================================================
// bf16x3 split-precision MFMA GEMM (fp32-accurate): A@B^T + bias
// EPI=0: fp32 out (se_w3). EPI=1: relu then bf16 hi/lo split out (se_w2).
// =====================================================================
template<int EPI>
__global__ __launch_bounds__(256)
void mfma3_bt(const ushort_t* __restrict__ Ah, const ushort_t* __restrict__ Alo,
              const ushort_t* __restrict__ Bh, const ushort_t* __restrict__ Blo,
              const float* __restrict__ bias, float* __restrict__ Cout,
              ushort_t* __restrict__ Ch, ushort_t* __restrict__ Cl,
              int N, int Kd)
{
  __shared__ ushort_t AhL[128 * 32];
  __shared__ ushort_t AlL[128 * 32];
  __shared__ ushort_t BhL[128 * 32];
  __shared__ ushort_t BlL[128 * 32];
  const int t = threadIdx.x;
  const int wid = t >> 6, lane = t & 63;
  const int wr = wid >> 1, wc = wid & 1;
  const int row0 = blockIdx.y * 128;
  const int col0 = blockIdx.x * 128;
  const int srow = lane >> 2;
  const int scol = (lane & 3) * 8;

  const size_t aoff0 = (size_t)(row0 + wid * 16 + srow) * Kd + scol;
  const size_t aoff1 = (size_t)(row0 + (wid + 4) * 16 + srow) * Kd + scol;
  const size_t boff0 = (size_t)(col0 + wid * 16 + srow) * Kd + scol;
  const size_t boff1 = (size_t)(col0 + (wid + 4) * 16 + srow) * Kd + scol;
  const int l0 = (wid * 16) * 32;
  const int l1 = ((wid + 4) * 16) * 32;

  const int mr = lane & 15, qd = lane >> 4;

  floatx4 acc[4][4];
#pragma unroll
  for (int i = 0; i < 4; ++i)
#pragma unroll
    for (int j = 0; j < 4; ++j) acc[i][j] = (floatx4){0.f, 0.f, 0.f, 0.f};

  for (int kb = 0; kb < Kd; kb += 32) {
    gload16(Ah + aoff0 + kb, &AhL[l0]);
    gload16(Ah + aoff1 + kb, &AhL[l1]);
    gload16(Alo + aoff0 + kb, &AlL[l0]);
    gload16(Alo + aoff1 + kb, &AlL[l1]);
    gload16(Bh + boff0 + kb, &BhL[l0]);
    gload16(Bh + boff1 + kb, &BhL[l1]);
    gload16(Blo + boff0 + kb, &BlL[l0]);
    gload16(Blo + boff1 + kb, &BlL[l1]);
    __syncthreads();
    short8 ahF[4], alF[4], bhF[4], blF[4];
#pragma unroll
    for (int i = 0; i < 4; ++i) {
      const int o = (wr * 64 + i * 16 + mr) * 32 + qd * 8;
      ahF[i] = *(const short8*)&AhL[o];
      alF[i] = *(const short8*)&AlL[o];
    }
#pragma unroll
    for (int j = 0; j < 4; ++j) {
      const int o = (wc * 64 + j * 16 + mr) * 32 + qd * 8;
      bhF[j] = *(const short8*)&BhL[o];
      blF[j] = *(const short8*)&BlL[o];
    }
#pragma unroll
    for (int i = 0; i < 4; ++i)
#pragma unroll
      for (int j = 0; j < 4; ++j) {
        acc[i][j] = __builtin_amdgcn_mfma_f32_16x16x32_bf16(alF[i], bhF[j], acc[i][j], 0, 0, 0);
        acc[i][j] = __builtin_amdgcn_mfma_f32_16x16x32_bf16(ahF[i], blF[j], acc[i][j], 0, 0, 0);
        acc[i][j] = __builtin_amdgcn_mfma_f32_16x16x32_bf16(ahF[i], bhF[j], acc[i][j], 0, 0, 0);
      }
    __syncthreads();
  }

#pragma unroll
  for (int i = 0; i < 4; ++i) {
#pragma unroll
    for (int j = 0; j < 4; ++j) {
      const int col = col0 + wc * 64 + j * 16 + mr;
#pragma unroll
      for (int r = 0; r < 4; ++r) {
        const int row = row0 + wr * 64 + i * 16 + qd * 4 + r;
        const float v = acc[i][j][r] + bias[col];
        if (EPI == 0) {
          Cout[(size_t)row * N + col] = v;
        } else {
          const float y = fmaxf(v, 0.f);
          const ushort_t h = f2bf(y);
          Ch[(size_t)row * N + col] = h;
          Cl[(size_t)row * N + col] = f2bf(y - bf2f(h));
        }
      }
    }
  }
}

// =====================================================================
// bf16 MFMA GEMM, 64x128 tile (for cc_w1's small-M grid).
// A(M x K) bf16, B(N x K)^T bf16, out fp32 = relu(acc + bias). BK=64.
// =====================================================================
__global__ __launch_bounds__(256)
void mfma_bt64(const ushort_t* __restrict__ A, const ushort_t* __restrict__ B,
               const float* __restrict__ bias, float* __restrict__ Cout,
               int N, int Kd)
{
  __shared__ ushort_t Al[2 * 64 * 32];    // [sub][row][col]
  __shared__ ushort_t Bl[2 * 128 * 32];
  const int t = threadIdx.x;
  const int wid = t >> 6, lane = t & 63;
  const int row0 = blockIdx.y << 6;
  const int col0 = blockIdx.x << 7;
  const int srow = lane >> 2;
  const int scol = (lane & 3) * 8;
  const int mr = lane & 15, qd = lane >> 4;

  const ushort_t* gsrc[6];
  ushort_t* ldst[6];
#pragma unroll
  for (int m = 0; m < 6; ++m) {
    const int c = wid * 6 + m;
    if (c < 8) {        // A chunks: sub = c>>2, grp = c&3
      const int sub = c >> 2, grp = c & 3;
      gsrc[m] = A + (size_t)(row0 + grp * 16 + srow) * Kd + sub * 32 + scol;
      ldst[m] = &Al[sub * 2048 + (grp * 16 + srow) * 32];
    } else {            // B chunks: b = c-8, sub = b>>3, grp = b&7
      const int b = c - 8, sub = b >> 3, grp = b & 7;
      gsrc[m] = B + (size_t)(col0 + grp * 16 + srow) * Kd + sub * 32 + scol;
      ldst[m] = &Bl[sub * 4096 + (grp * 16 + srow) * 32];
    }
  }

  floatx4 acc[4][2];
#pragma unroll
  for (int i = 0; i < 4; ++i)
#pragma unroll
    for (int j = 0; j < 2; ++j) acc[i][j] = (floatx4){0.f, 0.f, 0.f, 0.f};

  for (int kb = 0; kb < Kd; kb += 64) {
#pragma unroll
    for (int m = 0; m < 6; ++m) gload16(gsrc[m] + kb, ldst[m]);
    __syncthreads();
#pragma unroll
    for (int sub = 0; sub < 2; ++sub) {
      short8 aF[4], bF[2];
#pragma unroll
      for (int i = 0; i < 4; ++i)
        aF[i] = *(const short8*)&Al[sub * 2048 + (i * 16 + mr) * 32 + qd * 8];
#pragma unroll
      for (int j = 0; j < 2; ++j)
        bF[j] = *(const short8*)&Bl[sub * 4096 + (wid * 32 + j * 16 + mr) * 32 + qd * 8];
#pragma unroll
      for (int i = 0; i < 4; ++i)
#pragma unroll
        for (int j = 0; j < 2; ++j)
          acc[i][j] = __builtin_amdgcn_mfma_f32_16x16x32_bf16(aF[i], bF[j], acc[i][j], 0, 0, 0);
    }
    __syncthreads();
  }

#pragma unroll
  for (int i = 0; i < 4; ++i) {
#pragma unroll
    for (int j = 0; j < 2; ++j) {
      const int col = col0 + wid * 32 + j * 16 + mr;
#pragma unroll
      for (int r = 0; r < 4; ++r) {
        const int row = row0 + i * 16 + qd * 4 + r;
        Cout[(size_t)row * N + col] = fmaxf(acc[i][j][r] + bias[col], 0.f);
      }
    }
  }
}

// =====================================================================
// fp32 scores GEMM (fallback path only) -> u16 score keys
// =====================================================================
__global__ __launch_bounds__(256)
void gemm_scores(const float* __restrict__ A, const float* __restrict__ Bm,
                 const float* __restrict__ rk, ushort_t* __restrict__ S)
{
  __shared__ float As[16][132];
  __shared__ float Bs[16][132];
  const int t  = threadIdx.x;
  const int tx = t & 15, ty = t >> 4;
  const int row0 = blockIdx.y * 128;
  const int col0 = blockIdx.x * 128;
  const int ar = t >> 2, ac = (t & 3) * 4;
  const int Kd = Ez;

  float acc[8][8];
#pragma unroll
  for (int i = 0; i < 8; ++i)
#pragma unroll
    for (int j = 0; j < 8; ++j) acc[i][j] = 0.f;

  for (int k0 = 0; k0 < Kd; k0 += 16) {
    {
      const float* ap = A + (size_t)(row0 + ar) * Kd + k0 + ac;
      float4 v0 = *(const float4*)ap;
      float4 v1 = *(const float4*)(ap + (size_t)64 * Kd);
      As[ac + 0][ar] = v0.x; As[ac + 1][ar] = v0.y;
      As[ac + 2][ar] = v0.z; As[ac + 3][ar] = v0.w;
      As[ac + 0][ar + 64] = v1.x; As[ac + 1][ar + 64] = v1.y;
      As[ac + 2][ar + 64] = v1.z; As[ac + 3][ar + 64] = v1.w;
    }
    {
      const float* bp = Bm + (size_t)(col0 + ar) * Kd + k0 + ac;
      float4 v0 = *(const float4*)bp;
      float4 v1 = *(const float4*)(bp + (size_t)64 * Kd);
      Bs[ac + 0][ar] = v0.x; Bs[ac + 1][ar] = v0.y;
      Bs[ac + 2][ar] = v0.z; Bs[ac + 3][ar] = v0.w;
      Bs[ac + 0][ar + 64] = v1.x; Bs[ac + 1][ar + 64] = v1.y;
      Bs[ac + 2][ar + 64] = v1.z; Bs[ac + 3][ar + 64] = v1.w;
    }
    __syncthreads();
#pragma unroll
    for (int kk = 0; kk < 16; ++kk) {
      float a[8], b[8];
      *(float4*)&a[0] = *(const float4*)&As[kk][ty * 4];
      *(float4*)&a[4] = *(const float4*)&As[kk][64 + ty * 4];
      *(float4*)&b[0] = *(const float4*)&Bs[kk][tx * 4];
      *(float4*)&b[4] = *(const float4*)&Bs[kk][64 + tx * 4];
#pragma unroll
      for (int i = 0; i < 8; ++i)
#pragma unroll
        for (int j = 0; j < 8; ++j)
          acc[i][j] = fmaf(a[i], b[j], acc[i][j]);
    }
    __syncthreads();
  }

  float rk0[8];
  *(float4*)&rk0[0] = *(const float4*)&rk[col0 + tx * 4];
  *(float4*)&rk0[4] = *(const float4*)&rk[col0 + 64 + tx * 4];
#pragma unroll
  for (int i = 0; i < 8; ++i) {
    const int r = row0 + ((i < 4) ? (ty * 4 + i) : (64 + ty * 4 + i - 4));
    ushort4 h0, h1;
    h0.x = f2key(acc[i][0] * rk0[0]); h0.y = f2key(acc[i][1] * rk0[1]);
    h0.z = f2key(acc[i][2] * rk0[2]); h0.w = f2key(acc[i][3] * rk0[3]);
    h1.x = f2key(acc[i][4] * rk0[4]); h1.y = f2key(acc[i][5] * rk0[5]);
    h1.z = f2key(acc[i][6] * rk0[6]); h1.w = f2key(acc[i][7] * rk0[7]);
    *(ushort4*)&S[(size_t)r * NEz + col0 + tx * 4]      = h0;
    *(ushort4*)&S[(size_t)r * NEz + col0 + 64 + tx * 4] = h1;
  }
}

// =====================================================================
// Batched (4-actor) fused GEMM(N=128) + LayerNorm (+ReLU).
// =====================================================================
struct LN4 {
  const float* W[4]; const float* b[4]; const float* g[4]; const float* be[4];
  int eoff[4]; int elen[4];
};

template<bool RELU, bool HASEXT>
__global__ __launch_bounds__(256)
void gemm_ln4(const float* __restrict__ A1base, size_t a1stride, int K1,
              const float* __restrict__ A2, LN4 p,
              float* __restrict__ outbase, size_t ostride)
{
  __shared__ float As[32][68];
  __shared__ float Bs[32][132];
  __shared__ float rsum[64][17];
  __shared__ float rsq[64][17];
  __shared__ float stm[64], str[64];
  const int a = blockIdx.y;
  const float* A1 = A1base + (size_t)a * a1stride;
  float* out = outbase + (size_t)a * ostride;
  const float* W = p.W[a];
  const float* bias = p.b[a];
  const float* g = p.g[a];
  const float* be = p.be[a];
  const int eoff = HASEXT ? p.eoff[a] : 0;
  const int K2 = HASEXT ? p.elen[a] : 0;

  const int t = threadIdx.x;
  const int tx = t & 15, ty = t >> 4;
  const int row0 = blockIdx.x * 64;
  const int Kt = K1 + K2;
  const int ar = t >> 2, ac = (t & 3) * 8;
  const int bk = t >> 3, bc = (t & 7) * 16;

  float acc[4][8];
#pragma unroll
  for (int i = 0; i < 4; ++i)
#pragma unroll
    for (int j = 0; j < 8; ++j) acc[i][j] = 0.f;

  for (int k0 = 0; k0 < Kt; k0 += 32) {
    const int grow = row0 + ar;
#pragma unroll
    for (int e = 0; e < 8; ++e) {
      const int k = k0 + ac + e;
      float v = 0.f;
      if (k < K1)      v = A1[(size_t)grow * K1 + k];
      else if (k < Kt) v = A2[(size_t)grow * 115 + eoff + (k - K1)];
      As[ac + e][ar] = v;
    }
    {
      const int k = k0 + bk;
#pragma unroll
      for (int qd = 0; qd < 4; ++qd) {
        float4 z; z.x = z.y = z.z = z.w = 0.f;
        *(float4*)&Bs[bk][bc + 4 * qd] =
            (k < Kt) ? *(const float4*)&W[(size_t)k * 128 + bc + 4 * qd] : z;
      }
    }
    __syncthreads();
#pragma unroll
    for (int kk = 0; kk < 32; ++kk) {
      float av[4], bv2[8];
      *(float4*)&av[0]  = *(const float4*)&As[kk][ty * 4];
      *(float4*)&bv2[0] = *(const float4*)&Bs[kk][tx * 4];
      *(float4*)&bv2[4] = *(const float4*)&Bs[kk][64 + tx * 4];
#pragma unroll
      for (int i = 0; i < 4; ++i)
#pragma unroll
        for (int j = 0; j < 8; ++j)
          acc[i][j] = fmaf(av[i], bv2[j], acc[i][j]);
    }
    __syncthreads();
  }

  float bv[8];
  *(float4*)&bv[0] = *(const float4*)&bias[tx * 4];
  *(float4*)&bv[4] = *(const float4*)&bias[64 + tx * 4];
#pragma unroll
  for (int i = 0; i < 4; ++i) {
    float s = 0.f, q = 0.f;
#pragma unroll
    for (int j = 0; j < 8; ++j) {
      acc[i][j] += bv[j];
      s += acc[i][j];
      q += acc[i][j] * acc[i][j];
    }
    rsum[ty * 4 + i][tx] = s;
    rsq[ty * 4 + i][tx]  = q;
  }
  __syncthreads();
  if (t < 64) {
    float s = 0.f, q = 0.f;
#pragma unroll
    for (int x = 0; x < 16; ++x) { s += rsum[t][x]; q += rsq[t][x]; }
    const float m = s * (1.f / 128.f);
    const float v = q * (1.f / 128.f) - m * m;
    stm[t] = m;
    str[t] = rsqrtf(v + 1e-5f);
  }
  __syncthreads();
#pragma unroll
  for (int i = 0; i < 4; ++i) {
    const int r = ty * 4 + i;
    const float m = stm[r], rs = str[r];
    float o[8];
#pragma unroll
    for (int j = 0; j < 8; ++j) {
      const int col = (j < 4) ? (tx * 4 + j) : (64 + tx * 4 + (j - 4));
      float y = (acc[i][j] - m) * rs * g[col] + be[col];
      if (RELU) y = fmaxf(y, 0.f);
      o[j] = y;
    }
    *(float4*)&out[(size_t)(row0 + r) * 128 + tx * 4]      = *(float4*)&o[0];
    *(float4*)&out[(size_t)(row0 + r) * 128 + 64 + tx * 4] = *(float4*)&o[4];
  }
}

// =====================================================================
// Block-wide (256 threads) sum helper
// =====================================================================
__device__ __forceinline__ float blockSum256(float v, float* sh)
{
#pragma unroll
  for (int d = 32; d; d >>= 1) v += __shfl_down(v, d, 64);
  __syncthreads();
  if ((threadIdx.x & 63) == 0) sh[threadIdx.x >> 6] = v;
  __syncthreads();
  return sh[0] + sh[1] + sh[2] + sh[3];
}

// =====================================================================
// Fused normalize+convert launch (fast path):
// blocks [0,Bz):        q row LN + L2 + bf16 out
// blocks [Bz, Bz+NEz):  key row norm + bf16(keys*rk) + rk
// =====================================================================
__global__ __launch_bounds__(256)
void norm_cvt_fused(float* __restrict__ q, const float* __restrict__ g,
                    const float* __restrict__ be, ushort_t* __restrict__ qb,
                    const float* __restrict__ keys, float* __restrict__ rk,
                    ushort_t* __restrict__ knb)
{
  __shared__ float sh[4];
  const int b = blockIdx.x, t = threadIdx.x;
  if (b < Bz) {
    const int row = b;
    float* qr = q + (size_t)row * Ez;
    float x[12];
#pragma unroll
    for (int i = 0; i < 12; ++i) x[i] = qr[t + (i << 8)];
    float s = 0.f;
#pragma unroll
    for (int i = 0; i < 12; ++i) s += x[i];
    const float m = blockSum256(s, sh) * (1.f / (float)Ez);
    float vs = 0.f;
#pragma unroll
    for (int i = 0; i < 12; ++i) { const float d = x[i] - m; vs += d * d; }
    const float v = blockSum256(vs, sh) * (1.f / (float)Ez);
    const float rs = rsqrtf(v + 1e-5f);
    float y[12]; float qs = 0.f;
#pragma unroll
    for (int i = 0; i < 12; ++i) {
      const int c = t + (i << 8);
      const float yy = (x[i] - m) * rs * g[c] + be[c];
      y[i] = yy; qs += yy * yy;
    }
    const float tot = blockSum256(qs, sh);
    const float s2 = rsqrtf(tot + 1e-12f);
#pragma unroll
    for (int i = 0; i < 12; ++i) {
      const int c = t + (i << 8);
      const float yn = y[i] * s2;
      qr[c] = yn;
      qb[(size_t)row * Ez + c] = f2bf(yn);
    }
  } else {
    const int row = b - Bz;
    const float* xr = keys + (size_t)row * Ez;
    float x[12]; float qs = 0.f;
#pragma unroll
    for (int i = 0; i < 12; ++i) { x[i] = xr[t + (i << 8)]; qs += x[i] * x[i]; }
    const float tot = blockSum256(qs, sh);
    const float s = rsqrtf(tot + 1e-12f);
    if (t == 0) rk[row] = s;
#pragma unroll
    for (int i = 0; i < 12; ++i)
      knb[(size_t)row * Ez + t + (i << 8)] = f2bf(x[i] * s);
  }
}

// Row LN (width 3072) + L2 normalize, in place (fallback)
__global__ __launch_bounds__(256)
void ln_l2_q(float* __restrict__ q, const float* __restrict__ g,
             const float* __restrict__ be)
{
  __shared__ float sh[4];
  const int row = blockIdx.x, t = threadIdx.x;
  float* qr = q + (size_t)row * Ez;
  float x[12];
#pragma unroll
  for (int i = 0; i < 12; ++i) x[i] = qr[t + (i << 8)];
  float s = 0.f;
#pragma unroll
  for (int i = 0; i < 12; ++i) s += x[i];
  const float m = blockSum256(s, sh) * (1.f / (float)Ez);
  float vs = 0.f;
#pragma unroll
  for (int i = 0; i < 12; ++i) { const float d = x[i] - m; vs += d * d; }
  const float v = blockSum256(vs, sh) * (1.f / (float)Ez);
  const float rs = rsqrtf(v + 1e-5f);
  float y[12]; float qs = 0.f;
#pragma unroll
  for (int i = 0; i < 12; ++i) {
    const int c = t + (i << 8);
    const float yy = (x[i] - m) * rs * g[c] + be[c];
    y[i] = yy; qs += yy * yy;
  }
  const float tot = blockSum256(qs, sh);
  const float s2 = rsqrtf(tot + 1e-12f);
#pragma unroll
  for (int i = 0; i < 12; ++i) qr[t + (i << 8)] = y[i] * s2;
}

// rk[n] only (fallback)
__global__ __launch_bounds__(256)
void keynorm(const float* __restrict__ keys, float* __restrict__ rk)
{
  __shared__ float sh[4];
  const int row = blockIdx.x, t = threadIdx.x;
  const float* xr = keys + (size_t)row * Ez;
  float qs = 0.f;
#pragma unroll
  for (int i = 0; i < 12; ++i) { const float x = xr[t + (i << 8)]; qs += x * x; }
  const float tot = blockSum256(qs, sh);
  if (t == 0) rk[row] = rsqrtf(tot + 1e-12f);
}

// Combined weight transpose+split: blockIdx.y<8 -> se_w2 (C=512),
// else se_w3 (C=3072). W is (512 x C), outputs (C x 512) hi/lo bf16.
__global__ __launch_bounds__(256)
void wt_split2(const float* __restrict__ w2, ushort_t* __restrict__ h2,
               ushort_t* __restrict__ l2v,
               const float* __restrict__ w3, ushort_t* __restrict__ h3,
               ushort_t* __restrict__ l3v)
{
  __shared__ float tile[64][65];
  const float* w; ushort_t* hT; ushort_t* lT; int C; int n0;
  if ((int)blockIdx.y < 8) { w = w2; hT = h2; lT = l2v; C = 512;  n0 = blockIdx.y * 64; }
  else                     { w = w3; hT = h3; lT = l3v; C = 3072; n0 = (blockIdx.y - 8) * 64; }
  const int k0 = blockIdx.x * 64;
  const int t = threadIdx.x;
  const int c = t & 63, r4 = t >> 6;
#pragma unroll
  for (int rr = 0; rr < 16; ++rr) {
    const int r = rr * 4 + r4;
    tile[r][c] = w[(size_t)(k0 + r) * C + n0 + c];
  }
  __syncthreads();
#pragma unroll
  for (int rr = 0; rr < 16; ++rr) {
    const int n = rr * 4 + r4;
    const float a = tile[c][n];
    const ushort_t h = f2bf(a);
    hT[(size_t)(n0 + n) * 512 + k0 + c] = h;
    lT[(size_t)(n0 + n) * 512 + k0 + c] = f2bf(a - bf2f(h));
  }
}

// cc_w1 (3072 x 512 fp32) -> transposed bf16 (512 x 3072), coalesced
__global__ __launch_bounds__(256)
void cvt_w1t_t(const float* __restrict__ w, ushort_t* __restrict__ out)
{
  __shared__ float tile[64][65];
  const int k0 = blockIdx.x * 64;   // 48 blocks
  const int n0 = blockIdx.y * 64;   // 8 blocks
  const int t = threadIdx.x;
  const int c = t & 63, r4 = t >> 6;
#pragma unroll
  for (int rr = 0; rr < 16; ++rr) {
    const int r = rr * 4 + r4;
    tile[r][c] = w[(size_t)(k0 + r) * 512 + n0 + c];
  }
  __syncthreads();
#pragma unroll
  for (int rr = 0; rr < 16; ++rr) {
    const int n = rr * 4 + r4;
    out[(size_t)(n0 + n) * Ez + k0 + c] = f2bf(tile[c][n]);
  }
}

// =====================================================================
// Top-16 per row of the 8192 x 4096 u16-key score matrix.
// =====================================================================
__global__ __launch_bounds__(256)
void topk16(const ushort_t* __restrict__ S, int* __restrict__ outIdx)
{
  __shared__ uint_t cand[64];
  const int row = blockIdx.x, t = threadIdx.x;
  const int w = t >> 6, lane = t & 63;
  const int base = (w << 10) + (lane << 4);
  const ushort_t* sr = S + (size_t)row * NEz + base;
  uint4 v0 = *(const uint4*)sr;
  uint4 v1 = *(const uint4*)(sr + 8);
  const uint_t cb = (uint_t)(4095 - base);
  uint_t p[16];
  p[0]  = ((v0.x & 0xFFFFu) << 12) | (cb - 0);
  p[1]  = ((v0.x >> 16)     << 12) | (cb - 1);
  p[2]  = ((v0.y & 0xFFFFu) << 12) | (cb - 2);
  p[3]  = ((v0.y >> 16)     << 12) | (cb - 3);
  p[4]  = ((v0.z & 0xFFFFu) << 12) | (cb - 4);
  p[5]  = ((v0.z >> 16)     << 12) | (cb - 5);
  p[6]  = ((v0.w & 0xFFFFu) << 12) | (cb - 6);
  p[7]  = ((v0.w >> 16)     << 12) | (cb - 7);
  p[8]  = ((v1.x & 0xFFFFu) << 12) | (cb - 8);
  p[9]  = ((v1.x >> 16)     << 12) | (cb - 9);
  p[10] = ((v1.y & 0xFFFFu) << 12) | (cb - 10);
  p[11] = ((v1.y >> 16)     << 12) | (cb - 11);
  p[12] = ((v1.z & 0xFFFFu) << 12) | (cb - 12);
  p[13] = ((v1.z >> 16)     << 12) | (cb - 13);
  p[14] = ((v1.w & 0xFFFFu) << 12) | (cb - 14);
  p[15] = ((v1.w >> 16)     << 12) | (cb - 15);

  for (int it = 0; it < 16; ++it) {
    uint_t m = p[0];
#pragma unroll
    for (int j = 1; j < 16; ++j) m = umax_(m, p[j]);
#pragma unroll
    for (int d = 1; d < 64; d <<= 1)
      m = umax_(m, (uint_t)__shfl_xor((int)m, d, 64));
    if (lane == it) cand[(w << 4) + it] = m;
#pragma unroll
    for (int j = 0; j < 16; ++j) p[j] = (p[j] == m) ? 0u : p[j];
  }
  __syncthreads();
  if (t < 64) {
    uint_t mine = cand[t];
    for (int it = 0; it < 16; ++it) {
      uint_t m = mine;
#pragma unroll
      for (int d = 1; d < 64; d <<= 1)
        m = umax_(m, (uint_t)__shfl_xor((int)m, d, 64));
      if (t == it) outIdx[(size_t)row * 16 + it] = 4095 - (int)(m & 0xFFFu);
      mine = (mine == m) ? 0u : mine;
    }
  }
}

// =====================================================================
// Fused rescore + gather: one block per batch row (16 candidates).
// ctxOut must NOT alias qn (fast path uses separate region).
// =====================================================================
template<bool BFOUT>
__global__ __launch_bounds__(256)
void rescore_gather(const float* __restrict__ qn, const float* __restrict__ keys,
                    const float* __restrict__ rk, const int* __restrict__ cand,
                    void* __restrict__ ctxOut)
{
  __shared__ float qs[Ez];
  __shared__ double sv[16];
  __shared__ int si[16];
  __shared__ int sel10[10];
  const int row = blockIdx.x, t = threadIdx.x;
  const int w = t >> 6, lane = t & 63;

  {
    const float* qr = qn + (size_t)row * Ez;
#pragma unroll
    for (int i = 0; i < 3; ++i) {
      const int c = (t << 2) + (i << 10);
      *(float4*)&qs[c] = *(const float4*)&qr[c];
    }
  }
  __syncthreads();

#pragma unroll
  for (int cc = 0; cc < 4; ++cc) {
    const int slot = w * 4 + cc;
    const int id = cand[(size_t)row * 16 + slot];
    const float* kr = keys + (size_t)id * Ez;
    double s = 0.0;
#pragma unroll
    for (int it = 0; it < 12; ++it) {
      const int c = (lane << 2) + (it << 8);
      float4 k4 = *(const float4*)&kr[c];
      float4 q4 = *(const float4*)&qs[c];
      s += (double)q4.x * (double)k4.x;
      s += (double)q4.y * (double)k4.y;
      s += (double)q4.z * (double)k4.z;
      s += (double)q4.w * (double)k4.w;
    }
#pragma unroll
    for (int d = 32; d; d >>= 1) s += __shfl_down(s, d, 64);
    if (lane == 0) { sv[slot] = s * (double)rk[id]; si[slot] = id; }
  }
  __syncthreads();

  if (t == 0) {
    for (int it = 0; it < 10; ++it) {
      int bj = 0; double bvv = sv[0]; int bi = si[0];
      for (int j = 1; j < 16; ++j) {
        const double v = sv[j]; const int i2 = si[j];
        if (v > bvv || (v == bvv && i2 < bi)) { bj = j; bvv = v; bi = i2; }
      }
      sel10[it] = bi;
      sv[bj] = -1e300;
    }
  }
  __syncthreads();

  int id[10];
#pragma unroll
  for (int j = 0; j < 10; ++j) id[j] = sel10[j];

#pragma unroll
  for (int i = 0; i < 3; ++i) {
    const int c = (t << 2) + (i << 10);
    float4 a = {0.f, 0.f, 0.f, 0.f};
#pragma unroll
    for (int j = 0; j < 10; ++j) {
      float4 v = *(const float4*)&keys[(size_t)id[j] * Ez + c];
      a.x += v.x; a.y += v.y; a.z += v.z; a.w += v.w;
    }
    if (BFOUT) {
      ushort4 o;
      o.x = f2bf(a.x * 0.1f); o.y = f2bf(a.y * 0.1f);
      o.z = f2bf(a.z * 0.1f); o.w = f2bf(a.w * 0.1f);
      *(ushort4*)&((ushort_t*)ctxOut)[(size_t)row * Ez + c] = o;
    } else {
      float4 o;
      o.x = a.x * 0.1f; o.y = a.y * 0.1f; o.z = a.z * 0.1f; o.w = a.w * 0.1f;
      *(float4*)&((float*)ctxOut)[(size_t)row * Ez + c] = o;
    }
  }
}

// =====================================================================
// Router: 115 -> 64 -> 64 -> 4, clip, + gumbel, softmax, straight-through
// =====================================================================
__global__ __launch_bounds__(256)
void router_kernel(const float* __restrict__ state, const float* __restrict__ gn,
                   const float* __restrict__ w1, const float* __restrict__ b1,
                   const float* __restrict__ w2, const float* __restrict__ b2,
                   const float* __restrict__ w3, const float* __restrict__ b3,
                   float* __restrict__ outAlpha)
{
  const int row = blockIdx.x * 256 + threadIdx.x;
  const float* sr = state + (size_t)row * Sz;
  float h1[64];
#pragma unroll
  for (int j = 0; j < 64; ++j) h1[j] = b1[j];
  for (int k = 0; k < Sz; ++k) {
    const float a = sr[k];
    const float* wr = w1 + (size_t)k * 64;
#pragma unroll
    for (int j = 0; j < 64; ++j) h1[j] = fmaf(a, wr[j], h1[j]);
  }
#pragma unroll
  for (int j = 0; j < 64; ++j) h1[j] = fmaxf(h1[j], 0.f);
  float h2[64];
#pragma unroll
  for (int j = 0; j < 64; ++j) h2[j] = b2[j];
#pragma unroll
  for (int k = 0; k < 64; ++k) {
    const float a = h1[k];
    const float* wr = w2 + (size_t)k * 64;
#pragma unroll
    for (int j = 0; j < 64; ++j) h2[j] = fmaf(a, wr[j], h2[j]);
  }
#pragma unroll
  for (int j = 0; j < 64; ++j) h2[j] = fmaxf(h2[j], 0.f);
  float z[4];
#pragma unroll
  for (int a = 0; a < 4; ++a) {
    float s = b3[a];
#pragma unroll
    for (int k = 0; k < 64; ++k) s = fmaf(h2[k], w3[k * 4 + a], s);
    s = fminf(fmaxf(s, -20.f), 20.f);
    z[a] = s + gn[(size_t)row * 4 + a];   // TAU = 1
  }
  float mz = z[0];
#pragma unroll
  for (int a = 1; a < 4; ++a) mz = fmaxf(mz, z[a]);
  float e[4]; float se = 0.f;
#pragma unroll
  for (int a = 0; a < 4; ++a) { e[a] = expf(z[a] - mz); se += e[a]; }
  const float inv = 1.f / se;
  float y[4];
#pragma unroll
  for (int a = 0; a < 4; ++a) y[a] = e[a] * inv;
  int am = 0;
#pragma unroll
  for (int a = 1; a < 4; ++a) if (y[a] > y[am]) am = a;
#pragma unroll
  for (int a = 0; a < 4; ++a) {
    const float hard = (a == am) ? 1.f : 0.f;
    outAlpha[(size_t)row * 4 + a] = y[a] + (hard - y[a]);
  }
}

// critic head, coalesced: 128 blocks, wave handles 16 rows, lane = 4 cols
__global__ __launch_bounds__(256)
void critic_head(const float* __restrict__ c2, const float* __restrict__ w3,
                 const float* __restrict__ b3, float* __restrict__ outv)
{
  const int t = threadIdx.x;
  const int w = t >> 6, lane = t & 63;
  const int row0 = blockIdx.x * 64 + w * 16;
  float wv[4];
  *(float4*)&wv[0] = *(const float4*)&w3[lane * 4];
  const float b0 = b3[0];
#pragma unroll
  for (int rr = 0; rr < 16; ++rr) {
    const int row = row0 + rr;
    float4 x = *(const float4*)&c2[(size_t)row * 256 + lane * 4];
    float s = x.x * wv[0] + x.y * wv[1] + x.z * wv[2] + x.w * wv[3];
#pragma unroll
    for (int d = 32; d; d >>= 1) s += __shfl_down(s, d, 64);
    if (lane == 0) outv[row] = s + b0;
  }
}

// all-4 actor heads fused; 32 rows/block (256 blocks = full GPU)
struct HeadP { const float* w3[4]; const float* b3[4]; };

__global__ __launch_bounds__(256)
void actor_head4(const float* __restrict__ x2g, HeadP p,
                 const float* __restrict__ alpha, float* __restrict__ outL)
{
  __shared__ float wsm[4][128 * 23];
  __shared__ float bs[4][23];
  const int t = threadIdx.x;
#pragma unroll
  for (int a = 0; a < 4; ++a) {
    for (int i = t; i < 128 * 23; i += 256) wsm[a][i] = p.w3[a][i];
    if (t < 23) bs[a][t] = p.b3[a][t];
  }
  __syncthreads();
  const int row = blockIdx.x * 32 + (t >> 3);
  const int cg = t & 7;
  float sum[3] = {0.f, 0.f, 0.f};
#pragma unroll
  for (int a = 0; a < 4; ++a) {
    const float al = alpha[(size_t)row * 4 + a];
    const float* xr = x2g + (size_t)a * Bz * 128 + (size_t)row * 128;
    float acc[3] = {0.f, 0.f, 0.f};
    for (int kk = 0; kk < 128; ++kk) {
      const float xa = xr[kk];
#pragma unroll
      for (int j = 0; j < 3; ++j) {
        const int col = cg + 8 * j;
        if (col < 23) acc[j] = fmaf(xa, wsm[a][kk * 23 + col], acc[j]);
      }
    }
#pragma unroll
    for (int j = 0; j < 3; ++j) {
      const int col = cg + 8 * j;
      if (col < 23) sum[j] += al * (acc[j] + bs[a][col]);
    }
  }
#pragma unroll
  for (int j = 0; j < 3; ++j) {
    const int col = cg + 8 * j;
    if (col < 23) outL[(size_t)row * 23 + col] = sum[j];
  }
}

// =====================================================================
extern "C" void kernel_launch(void* const* d_in, const int* in_sizes, int n_in,
                              void* d_out, int out_size, void* d_ws, size_t ws_size,
                              hipStream_t stream)
{
  const float* state  = (const float*)d_in[0];
  const float* gumbel = (const float*)d_in[1];
  const float* keys   = (const float*)d_in[2];
  const float* se_w1 = (const float*)d_in[3];
  const float* se_b1 = (const float*)d_in[4];
  const float* se_w2 = (const float*)d_in[5];
  const float* se_b2 = (const float*)d_in[6];
  const float* se_w3 = (const float*)d_in[7];
  const float* se_b3 = (const float*)d_in[8];
  const float* se_g  = (const float*)d_in[9];
  const float* se_be = (const float*)d_in[10];
  const float* cc_w1 = (const float*)d_in[11];
  const float* cc_b1 = (const float*)d_in[12];
  const float* cc_w2 = (const float*)d_in[13];
  const float* cc_b2 = (const float*)d_in[14];
  const float* cc_g  = (const float*)d_in[15];
  const float* cc_be = (const float*)d_in[16];
  const float* r_w1 = (const float*)d_in[57];
  const float* r_b1 = (const float*)d_in[58];
  const float* r_w2 = (const float*)d_in[59];
  const float* r_b2 = (const float*)d_in[60];
  const float* r_w3 = (const float*)d_in[61];
  const float* r_b3 = (const float*)d_in[62];
  const float* c_w1 = (const float*)d_in[63];
  const float* c_b1 = (const float*)d_in[64];
  const float* c_w2 = (const float*)d_in[65];
  const float* c_b2 = (const float*)d_in[66];
  const float* c_w3 = (const float*)d_in[67];
  const float* c_b3 = (const float*)d_in[68];

  // ---- workspace layout ----
  float* wsf = (float*)d_ws;
  const size_t qF = (size_t)Bz * Ez;          // 25,165,824 floats
  const size_t uF = (size_t)16777216;         // union region, floats
  float* q = wsf;
  float* U = wsf + qF;
  // U internal (time-multiplexed), float offsets:
  ushort_t* sAh  = (ushort_t*)(U + 0);          // 8192x512 halves
  ushort_t* sAl  = (ushort_t*)(U + 2097152);
  ushort_t* sBh  = (ushort_t*)(U + 4194304);
  ushort_t* sBl  = (ushort_t*)(U + 6291456);
  ushort_t* w3hT = (ushort_t*)(U + 8388608);    // 3072x512 halves
  ushort_t* w3lT = (ushort_t*)(U + 9175040);
  ushort_t* w2hT = (ushort_t*)(U + 9961472);    // 512x512 halves
  ushort_t* w2lT = (ushort_t*)(U + 10092544);
  // fallback path fp32 buffers (same region, stream-ordered):
  float* sA = U;                                 // 8192x512 fp32 (fallback)
  float* sB = U + 4194304;                       // 8192x512 fp32 (fallback)
  ushort_t* scoresU = (ushort_t*)U;              // 8192x4096 u16 (whole U)
  ushort_t* ctxb = (ushort_t*)U;                 // bf16 ctx (8192x3072 halves),
                                                 // overlays dead scores post-topk
  float* cch = U + 12582912;                     // 8192x512 fp32
  float* shr = U;                                // 8192x128 (post-ctx phase)
  float* x1g = U + 1 * 1048576;                  // 4 x 8192x128
  float* x2g = U + 5 * 1048576;                  // 4 x 8192x128
  // critic temporaries in the (not yet written) q region:
  float* cr1 = q;                                // 8192x256
  float* cr2 = q + 2097152;                      // 8192x256
  // fast-path bf16 buffers after U:
  ushort_t* qbf  = (ushort_t*)(wsf + qF + uF);   // 8192x3072
  ushort_t* knbf = qbf + qF;                     // 4096x3072
  ushort_t* w1T  = knbf + (size_t)NEz * Ez;      // 512x3072
  const size_t bfHalves = qF + (size_t)NEz * Ez + (size_t)512 * Ez;
  const size_t baseBytes = (qF + uF) * sizeof(float);
  const size_t tailBytes = 4096 * 4 + (size_t)Bz * 16 * 4;
  const bool fast = ws_size >= baseBytes + bfHalves * 2 + tailBytes;
  float* tailF = (float*)((char*)d_ws + (fast ? baseBytes + bfHalves * 2 : baseBytes));
  float* rk  = tailF;
  int* cand  = (int*)(tailF + 4096);

  float* outL = (float*)d_out;                 // 8192*23
  float* outA = outL + (size_t)Bz * 23;        // 8192*4
  float* outV = outA + (size_t)Bz * 4;         // 8192*1

  const dim3 blk(256);

  // --- encoder L1 (hi/lo split out on fast path) + critic L1 ---
  {
    GPart e0 = {state, se_w1, se_b1, fast ? nullptr : sA,
                fast ? sAh : nullptr, fast ? sAl : nullptr, 512, 115, 4};
    GPart e1 = {state, c_w1, c_b1, cr1, nullptr, nullptr, 256, 115, 2};
    gemm128_dual<<<dim3(6, 64), blk, 0, stream>>>(e0, e1);
  }
  // --- critic L2 (fp32) ---
  gemm128<true, true><<<dim3(2, 64), blk, 0, stream>>>(cr1, c_w2, c_b2, cr2, 256, 256);

  if (fast) {
    // combined weight transpose+split (se_w2 + se_w3)
    wt_split2<<<dim3(8, 56), blk, 0, stream>>>(se_w2, w2hT, w2lT, se_w3, w3hT, w3lT);
    // encoder L2 via bf16x3 MFMA: relu + hi/lo split out
    mfma3_bt<1><<<dim3(4, 64), blk, 0, stream>>>(sAh, sAl, w2hT, w2lT, se_b2,
                                                 nullptr, sBh, sBl, 512, 512);
  } else {
    gemm128<true, true><<<dim3(4, 64), blk, 0, stream>>>(sA, se_w2, se_b2, sB, 512, 512);
  }

  // critic head + router (cr1/cr2 die before q is written)
  critic_head<<<dim3(128), blk, 0, stream>>>(cr2, c_w3, c_b3, outV);
  router_kernel<<<dim3(32), blk, 0, stream>>>(state, gumbel, r_w1, r_b1, r_w2, r_b2,
                                              r_w3, r_b3, outA);

  if (fast) {
    // encoder L3 (se_w3) via bf16x3 MFMA -> q fp32
    mfma3_bt<0><<<dim3(24, 64), blk, 0, stream>>>(sBh, sBl, w3hT, w3lT, se_b3,
                                                  q, nullptr, nullptr, 3072, 512);
    // fused: q LN+L2+bf16 and keys norm+bf16 in one launch
    norm_cvt_fused<<<dim3(Bz + NEz), blk, 0, stream>>>(q, se_g, se_be, qbf,
                                                       keys, rk, knbf);
    cvt_w1t_t<<<dim3(48, 8), blk, 0, stream>>>(cc_w1, w1T);
    // screen: 256x256-tile 8-phase pipelined MFMA (r4 schedule + race fix)
    screen256<<<dim3(16, 32), dim3(512), 0, stream>>>(qbf, knbf, scoresU, NEz, Ez);
  } else {
    gemm128<false, true><<<dim3(24, 64), blk, 0, stream>>>(sB, se_w3, se_b3, q, 3072, 512);
    ln_l2_q<<<dim3(Bz), blk, 0, stream>>>(q, se_g, se_be);
    keynorm<<<dim3(NEz), blk, 0, stream>>>(keys, rk);
    gemm_scores<<<dim3(32, 64), blk, 0, stream>>>(q, keys, rk, scoresU);
  }

  // --- top-16 screen, fused fp64 rescore + top-10 set + context gather ---
  topk16<<<dim3(Bz), blk, 0, stream>>>(scoresU, cand);

  // --- context + compressor ---
  if (fast) {
    // ctx -> ctxb in U (scores dead after topk; NO aliasing with q)
    rescore_gather<true><<<dim3(Bz), blk, 0, stream>>>(q, keys, rk, cand, ctxb);
    mfma_bt64<<<dim3(4, 128), blk, 0, stream>>>(ctxb, w1T, cc_b1, cch, 512, Ez);
  } else {
    // fallback: ctx fp32 overlays q row-for-row (self-row only: safe)
    rescore_gather<false><<<dim3(Bz), blk, 0, stream>>>(q, keys, rk, cand, q);
    gemm128<true, true><<<dim3(4, 64), blk, 0, stream>>>(q, cc_w1, cc_b1, cch, 512, Ez);
  }
  {
    LN4 pcc = {};
    pcc.W[0] = cc_w2; pcc.b[0] = cc_b2; pcc.g[0] = cc_g; pcc.be[0] = cc_be;
    gemm_ln4<false, false><<<dim3(128, 1), blk, 0, stream>>>(cch, 0, 512, nullptr, pcc,
                                                             shr, 0);
  }

  // --- actors (batched over blockIdx.y) ---
  {
    LN4 p1 = {}, p2 = {};
    HeadP ph = {};
    const int eoffs[4] = {0, 20, 40, 45};
    const int elens[4] = {50, 20, 10, 15};
    for (int a = 0; a < 4; ++a) {
      const int base = 17 + 10 * a;
      p1.W[a]  = (const float*)d_in[base + 0];
      p1.b[a]  = (const float*)d_in[base + 1];
      p1.g[a]  = (const float*)d_in[base + 2];
      p1.be[a] = (const float*)d_in[base + 3];
      p1.eoff[a] = eoffs[a]; p1.elen[a] = elens[a];
      p2.W[a]  = (const float*)d_in[base + 4];
      p2.b[a]  = (const float*)d_in[base + 5];
      p2.g[a]  = (const float*)d_in[base + 6];
      p2.be[a] = (const float*)d_in[base + 7];
      ph.w3[a] = (const float*)d_in[base + 8];
      ph.b3[a] = (const float*)d_in[base + 9];
    }
    gemm_ln4<true, true ><<<dim3(128, 4), blk, 0, stream>>>(shr, 0, 128, state, p1,
                                                            x1g, (size_t)Bz * 128);
    gemm_ln4<true, false><<<dim3(128, 4), blk, 0, stream>>>(x1g, (size_t)Bz * 128, 128,
                                                            nullptr, p2,
                                                            x2g, (size_t)Bz * 128);
    actor_head4<<<dim3(256), blk, 0, stream>>>(x2g, ph, outA, outL);
  }
}

// Round 9
// 1227.259 us; speedup vs baseline: 1.0298x; 1.0298x over previous
//
#include <hip/hip_runtime.h>

// Problem constants (match reference)
constexpr int Bz = 8192;   // batch
constexpr int Sz = 115;    // state dim
constexpr int Ez = 3072;   // embedding dim
constexpr int NEz = 4096;  // num keys
// C=128, A=23, K=10, TAU=1, EPS=1e-5

typedef __attribute__((ext_vector_type(8))) short short8;
typedef __attribute__((ext_vector_type(4))) float floatx4;
typedef unsigned short ushort_t;
typedef unsigned int uint_t;

__device__ __forceinline__ ushort_t f2bf(float f) {
  uint_t u = __float_as_uint(f);
  uint_t r = (u + 0x7FFFu + ((u >> 16) & 1u)) >> 16;   // RNE
  return (ushort_t)r;
}
__device__ __forceinline__ float bf2f(ushort_t b) {
  uint_t u = ((uint_t)b) << 16;
  return __uint_as_float(u);
}
// fp32 -> fp16 -> order-preserving u16 key (monotone total order)
__device__ __forceinline__ ushort_t f2key(float v) {
  _Float16 h = (_Float16)v;
  ushort_t b = __builtin_bit_cast(ushort_t, h);
  return b ^ ((b & 0x8000u) ? 0xFFFFu : 0x8000u);
}
__device__ __forceinline__ uint_t umax_(uint_t a, uint_t b) { return a > b ? a : b; }

// async global->LDS, 16 B per lane; lds dest = wave-uniform base + lane*16
__device__ __forceinline__ void gload16(const ushort_t* g, ushort_t* l) {
  __builtin_amdgcn_global_load_lds(
      (__attribute__((address_space(1))) const void*)g,
      (__attribute__((address_space(3))) void*)l, 16, 0, 0);
}

// =====================================================================
// Generic fp32 tiled GEMM: C = act(A@B + bias). Used for critic L2 + fallback.
// =====================================================================
template<bool RELU, bool BIAS>
__global__ __launch_bounds__(256)
void gemm128(const float* __restrict__ A, const float* __restrict__ Bm,
             const float* __restrict__ bias, float* __restrict__ C,
             int N, int Kd)
{
  __shared__ float As[16][132];
  __shared__ float Bs[16][132];
  const int t  = threadIdx.x;
  const int tx = t & 15, ty = t >> 4;
  const int row0 = blockIdx.y * 128;
  const int col0 = blockIdx.x * 128;
  const int ar = t >> 2, ac = (t & 3) * 4;
  const int bk = t >> 5, bc = (t & 31) * 4;
  const bool a4 = (Kd & 3) == 0;

  float acc[8][8];
#pragma unroll
  for (int i = 0; i < 8; ++i)
#pragma unroll
    for (int j = 0; j < 8; ++j) acc[i][j] = 0.f;

  for (int k0 = 0; k0 < Kd; k0 += 16) {
    const bool fullA = (k0 + 16 <= Kd) && a4;
    {
      const float* ap = A + (size_t)(row0 + ar) * Kd + k0 + ac;
      if (fullA) {
        float4 v0 = *(const float4*)ap;
        float4 v1 = *(const float4*)(ap + (size_t)64 * Kd);
        As[ac + 0][ar] = v0.x; As[ac + 1][ar] = v0.y;
        As[ac + 2][ar] = v0.z; As[ac + 3][ar] = v0.w;
        As[ac + 0][ar + 64] = v1.x; As[ac + 1][ar + 64] = v1.y;
        As[ac + 2][ar + 64] = v1.z; As[ac + 3][ar + 64] = v1.w;
      } else {
#pragma unroll
        for (int e = 0; e < 4; ++e) {
          const int k = k0 + ac + e;
          float v0 = 0.f, v1 = 0.f;
          if (k < Kd) { v0 = ap[e]; v1 = ap[e + (size_t)64 * Kd]; }
          As[ac + e][ar] = v0; As[ac + e][ar + 64] = v1;
        }
      }
    }
    {
      const float* bp = Bm + (size_t)(k0 + bk) * N + col0 + bc;
      if (k0 + 16 <= Kd) {
        *(float4*)&Bs[bk][bc]     = *(const float4*)bp;
        *(float4*)&Bs[bk + 8][bc] = *(const float4*)(bp + (size_t)8 * N);
      } else {
        float4 z; z.x = z.y = z.z = z.w = 0.f;
        *(float4*)&Bs[bk][bc]     = (k0 + bk     < Kd) ? *(const float4*)bp : z;
        *(float4*)&Bs[bk + 8][bc] = (k0 + bk + 8 < Kd) ? *(const float4*)(bp + (size_t)8 * N) : z;
      }
    }
    __syncthreads();
#pragma unroll
    for (int kk = 0; kk < 16; ++kk) {
      float a[8], b[8];
      *(float4*)&a[0] = *(const float4*)&As[kk][ty * 4];
      *(float4*)&a[4] = *(const float4*)&As[kk][64 + ty * 4];
      *(float4*)&b[0] = *(const float4*)&Bs[kk][tx * 4];
      *(float4*)&b[4] = *(const float4*)&Bs[kk][64 + tx * 4];
#pragma unroll
      for (int i = 0; i < 8; ++i)
#pragma unroll
        for (int j = 0; j < 8; ++j)
          acc[i][j] = fmaf(a[i], b[j], acc[i][j]);
    }
    __syncthreads();
  }

  float bv[8];
#pragma unroll
  for (int j = 0; j < 8; ++j) bv[j] = 0.f;
  if (BIAS) {
    *(float4*)&bv[0] = *(const float4*)&bias[col0 + tx * 4];
    *(float4*)&bv[4] = *(const float4*)&bias[col0 + 64 + tx * 4];
  }
#pragma unroll
  for (int i = 0; i < 8; ++i) {
    const int r = row0 + ((i < 4) ? (ty * 4 + i) : (64 + ty * 4 + i - 4));
    float o[8];
#pragma unroll
    for (int j = 0; j < 8; ++j) {
      o[j] = acc[i][j] + bv[j];
      if (RELU) o[j] = fmaxf(o[j], 0.f);
    }
    *(float4*)&C[(size_t)r * N + col0 + tx * 4]      = *(float4*)&o[0];
    *(float4*)&C[(size_t)r * N + col0 + 64 + tx * 4] = *(float4*)&o[4];
  }
}

// =====================================================================
// Dual-part fp32 GEMM+ReLU+bias. Optional fp32 out (C) and bf16 hi/lo
// split outputs (Ch/Cl) — either may be null.
// =====================================================================
struct GPart {
  const float* A; const float* Bm; const float* bias;
  float* C; ushort_t* Ch; ushort_t* Cl;
  int N; int Kd; int nbx;
};

__global__ __launch_bounds__(256)
void gemm128_dual(GPart g0, GPart g1)
{
  __shared__ float As[16][132];
  __shared__ float Bs[16][132];
  const int t  = threadIdx.x;
  const int tx = t & 15, ty = t >> 4;
  const bool p0 = (int)blockIdx.x < g0.nbx;
  GPart g = p0 ? g0 : g1;
  const int bx = p0 ? blockIdx.x : (blockIdx.x - g0.nbx);
  const int row0 = blockIdx.y * 128;
  const int col0 = bx * 128;
  const int Kd = g.Kd, N = g.N;
  const int ar = t >> 2, ac = (t & 3) * 4;
  const int bk = t >> 5, bc = (t & 31) * 4;
  const bool a4 = (Kd & 3) == 0;

  float acc[8][8];
#pragma unroll
  for (int i = 0; i < 8; ++i)
#pragma unroll
    for (int j = 0; j < 8; ++j) acc[i][j] = 0.f;

  for (int k0 = 0; k0 < Kd; k0 += 16) {
    const bool fullA = (k0 + 16 <= Kd) && a4;
    {
      const float* ap = g.A + (size_t)(row0 + ar) * Kd + k0 + ac;
      if (fullA) {
        float4 v0 = *(const float4*)ap;
        float4 v1 = *(const float4*)(ap + (size_t)64 * Kd);
        As[ac + 0][ar] = v0.x; As[ac + 1][ar] = v0.y;
        As[ac + 2][ar] = v0.z; As[ac + 3][ar] = v0.w;
        As[ac + 0][ar + 64] = v1.x; As[ac + 1][ar + 64] = v1.y;
        As[ac + 2][ar + 64] = v1.z; As[ac + 3][ar + 64] = v1.w;
      } else {
#pragma unroll
        for (int e = 0; e < 4; ++e) {
          const int k = k0 + ac + e;
          float v0 = 0.f, v1 = 0.f;
          if (k < Kd) { v0 = ap[e]; v1 = ap[e + (size_t)64 * Kd]; }
          As[ac + e][ar] = v0; As[ac + e][ar + 64] = v1;
        }
      }
    }
    {
      const float* bp = g.Bm + (size_t)(k0 + bk) * N + col0 + bc;
      if (k0 + 16 <= Kd) {
        *(float4*)&Bs[bk][bc]     = *(const float4*)bp;
        *(float4*)&Bs[bk + 8][bc] = *(const float4*)(bp + (size_t)8 * N);
      } else {
        float4 z; z.x = z.y = z.z = z.w = 0.f;
        *(float4*)&Bs[bk][bc]     = (k0 + bk     < Kd) ? *(const float4*)bp : z;
        *(float4*)&Bs[bk + 8][bc] = (k0 + bk + 8 < Kd) ? *(const float4*)(bp + (size_t)8 * N) : z;
      }
    }
    __syncthreads();
#pragma unroll
    for (int kk = 0; kk < 16; ++kk) {
      float a[8], b[8];
      *(float4*)&a[0] = *(const float4*)&As[kk][ty * 4];
      *(float4*)&a[4] = *(const float4*)&As[kk][64 + ty * 4];
      *(float4*)&b[0] = *(const float4*)&Bs[kk][tx * 4];
      *(float4*)&b[4] = *(const float4*)&Bs[kk][64 + tx * 4];
#pragma unroll
      for (int i = 0; i < 8; ++i)
#pragma unroll
        for (int j = 0; j < 8; ++j)
          acc[i][j] = fmaf(a[i], b[j], acc[i][j]);
    }
    __syncthreads();
  }

  float bv[8];
  *(float4*)&bv[0] = *(const float4*)&g.bias[col0 + tx * 4];
  *(float4*)&bv[4] = *(const float4*)&g.bias[col0 + 64 + tx * 4];
#pragma unroll
  for (int i = 0; i < 8; ++i) {
    const int r = row0 + ((i < 4) ? (ty * 4 + i) : (64 + ty * 4 + i - 4));
    float o[8];
#pragma unroll
    for (int j = 0; j < 8; ++j) o[j] = fmaxf(acc[i][j] + bv[j], 0.f);
    const size_t i0 = (size_t)r * N + col0 + tx * 4;
    const size_t i1 = i0 + 64;
    if (g.C) {
      *(float4*)&g.C[i0] = *(float4*)&o[0];
      *(float4*)&g.C[i1] = *(float4*)&o[4];
    }
    if (g.Ch) {
      ushort4 h0, l0, h1, l1;
      h0.x = f2bf(o[0]); l0.x = f2bf(o[0] - bf2f(h0.x));
      h0.y = f2bf(o[1]); l0.y = f2bf(o[1] - bf2f(h0.y));
      h0.z = f2bf(o[2]); l0.z = f2bf(o[2] - bf2f(h0.z));
      h0.w = f2bf(o[3]); l0.w = f2bf(o[3] - bf2f(h0.w));
      h1.x = f2bf(o[4]); l1.x = f2bf(o[4] - bf2f(h1.x));
      h1.y = f2bf(o[5]); l1.y = f2bf(o[5] - bf2f(h1.y));
      h1.z = f2bf(o[6]); l1.z = f2bf(o[6] - bf2f(h1.z));
      h1.w = f2bf(o[7]); l1.w = f2bf(o[7] - bf2f(h1.w));
      *(ushort4*)&g.Ch[i0] = h0; *(ushort4*)&g.Cl[i0] = l0;
      *(ushort4*)&g.Ch[i1] = h1; *(ushort4*)&g.Cl[i1] = l1;
    }
  }
}

// =====================================================================
// bf16 MFMA screen GEMM, 256x256 tile, 8 waves (2Mx4N), BK=64.
// 4-PHASE schedule (vs r7's verified 8-phase at 225us/39% MfmaUtil):
// halves barrier count (8 vs 16 per 2-K-tile group) — sync overhead
// dominates (MFMA ~155 cyc/CU/phase, LDS ~380-510, measured ~1400).
// Each phase = 32 MFMAs (one A-half x both B-halves), verified r4
// pattern: cluster then UNPINNED reads. Stage schedule
// {P1: buf1-A1<-tp+1(2), P2: buf0-ABB<-tp+2(6), P3: buf0-A1<-tp+2(2),
// P4: buf1-ABB<-tp+3(6)}; uniform vmcnt(8) at every phase entry
// (leaves the two newest phases' stages in flight; 2-phase-old stage
// landed before first read — verified per-phase + prologue boundary).
// Race-fixed prologue (vmcnt->barrier->reads); epilogue drain kept.
// r8 fix: READS passed as statement sequence (semicolons), not a
// comma expression — LDAm/LDBm are _Pragma statements.
// =====================================================================
__global__ __launch_bounds__(512, 2)
void screen256(const ushort_t* __restrict__ A, const ushort_t* __restrict__ B,
               ushort_t* __restrict__ Cout, int N, int Kd)
{
  __shared__ ushort_t AL[2 * 256 * 64];   // 64 KB
  __shared__ ushort_t BL[2 * 256 * 64];   // 64 KB
  const int t = threadIdx.x;
  const int lane = t & 63;
  const int wid = t >> 6;
  const int wr = wid >> 2;        // 0..1  M half of tile
  const int wc = wid & 3;         // 0..3  N quarter of tile
  const int mr = lane & 15, qd = lane >> 4;
  const int row0 = (int)blockIdx.y << 8;
  const int col0 = (int)blockIdx.x << 8;
  const int NT = Kd >> 6;         // 48 K-tiles

  // staging: per-lane inverse-swizzled global source, wave-uniform LDS dest
  const int l8 = lane >> 3;             // row within 8-row region
  const int c8 = (lane & 7) ^ l8;       // source 16B chunk (involution)
  const ushort_t* pA = A + (size_t)(row0 + wr * 128 + wc * 16 + l8) * Kd + c8 * 8;
  const ushort_t* pB = B + (size_t)(col0 + (wid >> 1) * 64 + (wid & 1) * 16 + l8) * Kd + c8 * 8;
  ushort_t* aWp = &AL[wr * 8192 + wc * 1024];
  ushort_t* bWp = &BL[(wid >> 1) * 4096 + (wid & 1) * 1024];

  // fragment reads: same XOR on the read side
  const int swz = (mr & 7) << 4;                  // byte XOR
  const int aRow = (wr * 128 + mr) * 64;
  const int bRow = (wc * 64 + mr) * 64;
  const int cu0 = ((qd * 16) ^ swz) >> 1;         // ksub 0 (ushort units)
  const int cu1 = ((64 + qd * 16) ^ swz) >> 1;    // ksub 1

  floatx4 acc[8][4];
#pragma unroll
  for (int i = 0; i < 8; ++i)
#pragma unroll
    for (int j = 0; j < 4; ++j) acc[i][j] = (floatx4){0.f, 0.f, 0.f, 0.f};

  // fragment registers: A-halves double-buffered across phases;
  // B-halves live across the two phases of each K-tile.
  short8 A0r[4][2], A1r[4][2], B0r[2][2], B1r[2][2];

#define STA(db, h, tile) do {                                            \
    const int kt_ = ((tile) < NT ? (tile) : 0) << 6;                     \
    gload16(pA + (size_t)((h) * 64) * Kd + kt_,                          \
            aWp + (db) * 16384 + (h) * 4096);                            \
    gload16(pA + (size_t)((h) * 64 + 8) * Kd + kt_,                      \
            aWp + (db) * 16384 + (h) * 4096 + 512);                      \
  } while (0)
#define STB(db, g, tile) do {                                            \
    const int kt_ = ((tile) < NT ? (tile) : 0) << 6;                     \
    gload16(pB + (size_t)((g) * 32) * Kd + kt_,                          \
            bWp + (db) * 16384 + (g) * 2048);                            \
    gload16(pB + (size_t)((g) * 32 + 8) * Kd + kt_,                      \
            bWp + (db) * 16384 + (g) * 2048 + 512);                      \
  } while (0)
#define LDAm(dst, db, half)                                              \
  _Pragma("unroll")                                                      \
  for (int i_ = 0; i_ < 4; ++i_) {                                       \
    const int b_ = (db) * 16384 + aRow + ((half) * 4 + i_) * 1024;       \
    dst[i_][0] = *(const short8*)&AL[b_ + cu0];                          \
    dst[i_][1] = *(const short8*)&AL[b_ + cu1];                          \
  }
#define LDBm(dst, db, jh)                                                \
  _Pragma("unroll")                                                      \
  for (int j_ = 0; j_ < 2; ++j_) {                                       \
    const int b_ = (db) * 16384 + bRow + ((jh) * 2 + j_) * 1024;         \
    dst[j_][0] = *(const short8*)&BL[b_ + cu0];                          \
    dst[j_][1] = *(const short8*)&BL[b_ + cu1];                          \
  }
// 16 MFMAs for one (ih,jh) quadrant: 8 independent ksub0, then 8 ksub1
#define MMq(ih, jh, As_, Bs_)                                            \
  _Pragma("unroll")                                                      \
  for (int s_ = 0; s_ < 2; ++s_)                                         \
    _Pragma("unroll")                                                    \
    for (int i_ = 0; i_ < 4; ++i_)                                       \
      _Pragma("unroll")                                                  \
      for (int j_ = 0; j_ < 2; ++j_)                                     \
        acc[(ih)*4+i_][(jh)*2+j_] = __builtin_amdgcn_mfma_f32_16x16x32_bf16( \
            As_[i_][s_], Bs_[j_][s_], acc[(ih)*4+i_][(jh)*2+j_], 0, 0, 0);
#define BARM() do { __builtin_amdgcn_s_barrier();                        \
                    asm volatile("" ::: "memory"); } while (0)
#define WLG()  do { asm volatile("s_waitcnt lgkmcnt(0)" ::: "memory");   \
                    __builtin_amdgcn_sched_barrier(0); } while (0)
#define WVM(n) asm volatile("s_waitcnt vmcnt(" #n ")" ::: "memory")
#define PRIO1() __builtin_amdgcn_s_setprio(1)
#define PRIO0() __builtin_amdgcn_s_setprio(0)
// phase: 32-MFMA cluster (one A-half x both B-halves), then unpinned
// reads. READS is a statement sequence (semicolon-separated).
#define PHASE2(ih, READS)                                                \
  do {                                                                   \
    WVM(8);                                                              \
    __builtin_amdgcn_s_barrier(); WLG();                                 \
    PRIO1(); MMq(ih, 0, (ih ? A1r : A0r), B0r);                          \
             MMq(ih, 1, (ih ? A1r : A0r), B1r); PRIO0();                 \
    READS;                                                               \
    BARM();                                                              \
  } while (0)

  // prologue (race-fixed): buf0 <- tile0 (8 DMAs), buf1-ABB <- tile1 (6);
  // own-vmcnt(6) [buf0 landed] -> BARRIER [all waves visible] -> initial
  // reads of buf0 {A0,B0,B1} (the steady-state "P4-end" reads).
  STA(0, 0, 0); STB(0, 0, 0); STB(0, 1, 0); STA(0, 1, 0);
  STA(1, 0, 1); STB(1, 0, 1); STB(1, 1, 1);
  WVM(6);
  BARM();
  LDAm(A0r, 0, 0); LDBm(B0r, 0, 0); LDBm(B1r, 0, 1);

  for (int it = 0; it < NT / 2; ++it) {
    const int tp = it * 2;
    // P1: stage buf1-A1 <- tp+1 (2); MFMA A-lo(buf0) x B; read A1r <- buf0-A1
    STA(1, 1, tp + 1);
    PHASE2(0, LDAm(A1r, 0, 1));
    // P2: stage buf0-{A0,B0,B1} <- tp+2 (6); MFMA A-hi(buf0) x B;
    //     reads A0r,B0r,B1r <- buf1 (tile tp+1)
    STA(0, 0, tp + 2); STB(0, 0, tp + 2); STB(0, 1, tp + 2);
    PHASE2(1, LDAm(A0r, 1, 0); LDBm(B0r, 1, 0); LDBm(B1r, 1, 1));
    // P3: stage buf0-A1 <- tp+2 (2); MFMA A-lo(buf1) x B; read A1r <- buf1-A1
    STA(0, 1, tp + 2);
    PHASE2(0, LDAm(A1r, 1, 1));
    // P4: stage buf1-{A0,B0,B1} <- tp+3 (6); MFMA A-hi(buf1) x B;
    //     reads A0r,B0r,B1r <- buf0 (tile tp+2, next group)
    STA(1, 0, tp + 3); STB(1, 0, tp + 3); STB(1, 1, tp + 3);
    PHASE2(1, LDAm(A0r, 0, 0); LDBm(B0r, 0, 0); LDBm(B1r, 0, 1));
  }

  // epilogue drain: never exit with LDS-DMA in flight
  asm volatile("s_waitcnt vmcnt(0) lgkmcnt(0)" ::: "memory");
  __syncthreads();

#undef STA
#undef STB
#undef LDAm
#undef LDBm
#undef MMq
#undef PHASE2
#undef BARM
#undef WLG
#undef WVM
#undef PRIO1
#undef PRIO0

  // epilogue: C/D layout col=lane&15, row=(lane>>4)*4+reg
#pragma unroll
  for (int i = 0; i < 8; ++i) {
#pragma unroll
    for (int j = 0; j < 4; ++j) {
      const int col = col0 + wc * 64 + j * 16 + mr;
#pragma unroll
      for (int r = 0; r < 4; ++r) {
        const int row = row0 + wr * 128 + i * 16 + qd * 4 + r;
        Cout[(size_t)row * N + col] = f2key(acc[i][j][r]);
      }
    }
  }
}

// =====================================================================
// bf16x3 split-precision MFMA GEMM (fp32-accurate): A@B^T + bias
// EPI=0: fp32 out (se_w3). EPI=1: relu then bf16 hi/lo split out (se_w2).
// =====================================================================
template<int EPI>
__global__ __launch_bounds__(256)
void mfma3_bt(const ushort_t* __restrict__ Ah, const ushort_t* __restrict__ Alo,
              const ushort_t* __restrict__ Bh, const ushort_t* __restrict__ Blo,
              const float* __restrict__ bias, float* __restrict__ Cout,
              ushort_t* __restrict__ Ch, ushort_t* __restrict__ Cl,
              int N, int Kd)
{
  __shared__ ushort_t AhL[128 * 32];
  __shared__ ushort_t AlL[128 * 32];
  __shared__ ushort_t BhL[128 * 32];
  __shared__ ushort_t BlL[128 * 32];
  const int t = threadIdx.x;
  const int wid = t >> 6, lane = t & 63;
  const int wr = wid >> 1, wc = wid & 1;
  const int row0 = blockIdx.y * 128;
  const int col0 = blockIdx.x * 128;
  const int srow = lane >> 2;
  const int scol = (lane & 3) * 8;

  const size_t aoff0 = (size_t)(row0 + wid * 16 + srow) * Kd + scol;
  const size_t aoff1 = (size_t)(row0 + (wid + 4) * 16 + srow) * Kd + scol;
  const size_t boff0 = (size_t)(col0 + wid * 16 + srow) * Kd + scol;
  const size_t boff1 = (size_t)(col0 + (wid + 4) * 16 + srow) * Kd + scol;
  const int l0 = (wid * 16) * 32;
  const int l1 = ((wid + 4) * 16) * 32;

  const int mr = lane & 15, qd = lane >> 4;

  floatx4 acc[4][4];
#pragma unroll
  for (int i = 0; i < 4; ++i)
#pragma unroll
    for (int j = 0; j < 4; ++j) acc[i][j] = (floatx4){0.f, 0.f, 0.f, 0.f};

  for (int kb = 0; kb < Kd; kb += 32) {
    gload16(Ah + aoff0 + kb, &AhL[l0]);
    gload16(Ah + aoff1 + kb, &AhL[l1]);
    gload16(Alo + aoff0 + kb, &AlL[l0]);
    gload16(Alo + aoff1 + kb, &AlL[l1]);
    gload16(Bh + boff0 + kb, &BhL[l0]);
    gload16(Bh + boff1 + kb, &BhL[l1]);
    gload16(Blo + boff0 + kb, &BlL[l0]);
    gload16(Blo + boff1 + kb, &BlL[l1]);
    __syncthreads();
    short8 ahF[4], alF[4], bhF[4], blF[4];
#pragma unroll
    for (int i = 0; i < 4; ++i) {
      const int o = (wr * 64 + i * 16 + mr) * 32 + qd * 8;
      ahF[i] = *(const short8*)&AhL[o];
      alF[i] = *(const short8*)&AlL[o];
    }
#pragma unroll
    for (int j = 0; j < 4; ++j) {
      const int o = (wc * 64 + j * 16 + mr) * 32 + qd * 8;
      bhF[j] = *(const short8*)&BhL[o];
      blF[j] = *(const short8*)&BlL[o];
    }
#pragma unroll
    for (int i = 0; i < 4; ++i)
#pragma unroll
      for (int j = 0; j < 4; ++j) {
        acc[i][j] = __builtin_amdgcn_mfma_f32_16x16x32_bf16(alF[i], bhF[j], acc[i][j], 0, 0, 0);
        acc[i][j] = __builtin_amdgcn_mfma_f32_16x16x32_bf16(ahF[i], blF[j], acc[i][j], 0, 0, 0);
        acc[i][j] = __builtin_amdgcn_mfma_f32_16x16x32_bf16(ahF[i], bhF[j], acc[i][j], 0, 0, 0);
      }
    __syncthreads();
  }

#pragma unroll
  for (int i = 0; i < 4; ++i) {
#pragma unroll
    for (int j = 0; j < 4; ++j) {
      const int col = col0 + wc * 64 + j * 16 + mr;
#pragma unroll
      for (int r = 0; r < 4; ++r) {
        const int row = row0 + wr * 64 + i * 16 + qd * 4 + r;
        const float v = acc[i][j][r] + bias[col];
        if (EPI == 0) {
          Cout[(size_t)row * N + col] = v;
        } else {
          const float y = fmaxf(v, 0.f);
          const ushort_t h = f2bf(y);
          Ch[(size_t)row * N + col] = h;
          Cl[(size_t)row * N + col] = f2bf(y - bf2f(h));
        }
      }
    }
  }
}

// =====================================================================
// bf16 MFMA GEMM, 64x128 tile (for cc_w1's small-M grid).
// A(M x K) bf16, B(N x K)^T bf16, out fp32 = relu(acc + bias). BK=64.
// =====================================================================
__global__ __launch_bounds__(256)
void mfma_bt64(const ushort_t* __restrict__ A, const ushort_t* __restrict__ B,
               const float* __restrict__ bias, float* __restrict__ Cout,
               int N, int Kd)
{
  __shared__ ushort_t Al[2 * 64 * 32];    // [sub][row][col]
  __shared__ ushort_t Bl[2 * 128 * 32];
  const int t = threadIdx.x;
  const int wid = t >> 6, lane = t & 63;
  const int row0 = blockIdx.y << 6;
  const int col0 = blockIdx.x << 7;
  const int srow = lane >> 2;
  const int scol = (lane & 3) * 8;
  const int mr = lane & 15, qd = lane >> 4;

  const ushort_t* gsrc[6];
  ushort_t* ldst[6];
#pragma unroll
  for (int m = 0; m < 6; ++m) {
    const int c = wid * 6 + m;
    if (c < 8) {        // A chunks: sub = c>>2, grp = c&3
      const int sub = c >> 2, grp = c & 3;
      gsrc[m] = A + (size_t)(row0 + grp * 16 + srow) * Kd + sub * 32 + scol;
      ldst[m] = &Al[sub * 2048 + (grp * 16 + srow) * 32];
    } else {            // B chunks: b = c-8, sub = b>>3, grp = b&7
      const int b = c - 8, sub = b >> 3, grp = b & 7;
      gsrc[m] = B + (size_t)(col0 + grp * 16 + srow) * Kd + sub * 32 + scol;
      ldst[m] = &Bl[sub * 4096 + (grp * 16 + srow) * 32];
    }
  }

  floatx4 acc[4][2];
#pragma unroll
  for (int i = 0; i < 4; ++i)
#pragma unroll
    for (int j = 0; j < 2; ++j) acc[i][j] = (floatx4){0.f, 0.f, 0.f, 0.f};

  for (int kb = 0; kb < Kd; kb += 64) {
#pragma unroll
    for (int m = 0; m < 6; ++m) gload16(gsrc[m] + kb, ldst[m]);
    __syncthreads();
#pragma unroll
    for (int sub = 0; sub < 2; ++sub) {
      short8 aF[4], bF[2];
#pragma unroll
      for (int i = 0; i < 4; ++i)
        aF[i] = *(const short8*)&Al[sub * 2048 + (i * 16 + mr) * 32 + qd * 8];
#pragma unroll
      for (int j = 0; j < 2; ++j)
        bF[j] = *(const short8*)&Bl[sub * 4096 + (wid * 32 + j * 16 + mr) * 32 + qd * 8];
#pragma unroll
      for (int i = 0; i < 4; ++i)
#pragma unroll
        for (int j = 0; j < 2; ++j)
          acc[i][j] = __builtin_amdgcn_mfma_f32_16x16x32_bf16(aF[i], bF[j], acc[i][j], 0, 0, 0);
    }
    __syncthreads();
  }

#pragma unroll
  for (int i = 0; i < 4; ++i) {
#pragma unroll
    for (int j = 0; j < 2; ++j) {
      const int col = col0 + wid * 32 + j * 16 + mr;
#pragma unroll
      for (int r = 0; r < 4; ++r) {
        const int row = row0 + i * 16 + qd * 4 + r;
        Cout[(size_t)row * N + col] = fmaxf(acc[i][j][r] + bias[col], 0.f);
      }
    }
  }
}

// =====================================================================
// fp32 scores GEMM (fallback path only) -> u16 score keys
// =====================================================================
__global__ __launch_bounds__(256)
void gemm_scores(const float* __restrict__ A, const float* __restrict__ Bm,
                 const float* __restrict__ rk, ushort_t* __restrict__ S)
{
  __shared__ float As[16][132];
  __shared__ float Bs[16][132];
  const int t  = threadIdx.x;
  const int tx = t & 15, ty = t >> 4;
  const int row0 = blockIdx.y * 128;
  const int col0 = blockIdx.x * 128;
  const int ar = t >> 2, ac = (t & 3) * 4;
  const int Kd = Ez;

  float acc[8][8];
#pragma unroll
  for (int i = 0; i < 8; ++i)
#pragma unroll
    for (int j = 0; j < 8; ++j) acc[i][j] = 0.f;

  for (int k0 = 0; k0 < Kd; k0 += 16) {
    {
      const float* ap = A + (size_t)(row0 + ar) * Kd + k0 + ac;
      float4 v0 = *(const float4*)ap;
      float4 v1 = *(const float4*)(ap + (size_t)64 * Kd);
      As[ac + 0][ar] = v0.x; As[ac + 1][ar] = v0.y;
      As[ac + 2][ar] = v0.z; As[ac + 3][ar] = v0.w;
      As[ac + 0][ar + 64] = v1.x; As[ac + 1][ar + 64] = v1.y;
      As[ac + 2][ar + 64] = v1.z; As[ac + 3][ar + 64] = v1.w;
    }
    {
      const float* bp = Bm + (size_t)(col0 + ar) * Kd + k0 + ac;
      float4 v0 = *(const float4*)bp;
      float4 v1 = *(const float4*)(bp + (size_t)64 * Kd);
      Bs[ac + 0][ar] = v0.x; Bs[ac + 1][ar] = v0.y;
      Bs[ac + 2][ar] = v0.z; Bs[ac + 3][ar] = v0.w;
      Bs[ac + 0][ar + 64] = v1.x; Bs[ac + 1][ar + 64] = v1.y;
      Bs[ac + 2][ar + 64] = v1.z; Bs[ac + 3][ar + 64] = v1.w;
    }
    __syncthreads();
#pragma unroll
    for (int kk = 0; kk < 16; ++kk) {
      float a[8], b[8];
      *(float4*)&a[0] = *(const float4*)&As[kk][ty * 4];
      *(float4*)&a[4] = *(const float4*)&As[kk][64 + ty * 4];
      *(float4*)&b[0] = *(const float4*)&Bs[kk][tx * 4];
      *(float4*)&b[4] = *(const float4*)&Bs[kk][64 + tx * 4];
#pragma unroll
      for (int i = 0; i < 8; ++i)
#pragma unroll
        for (int j = 0; j < 8; ++j)
          acc[i][j] = fmaf(a[i], b[j], acc[i][j]);
    }
    __syncthreads();
  }

  float rk0[8];
  *(float4*)&rk0[0] = *(const float4*)&rk[col0 + tx * 4];
  *(float4*)&rk0[4] = *(const float4*)&rk[col0 + 64 + tx * 4];
#pragma unroll
  for (int i = 0; i < 8; ++i) {
    const int r = row0 + ((i < 4) ? (ty * 4 + i) : (64 + ty * 4 + i - 4));
    ushort4 h0, h1;
    h0.x = f2key(acc[i][0] * rk0[0]); h0.y = f2key(acc[i][1] * rk0[1]);
    h0.z = f2key(acc[i][2] * rk0[2]); h0.w = f2key(acc[i][3] * rk0[3]);
    h1.x = f2key(acc[i][4] * rk0[4]); h1.y = f2key(acc[i][5] * rk0[5]);
    h1.z = f2key(acc[i][6] * rk0[6]); h1.w = f2key(acc[i][7] * rk0[7]);
    *(ushort4*)&S[(size_t)r * NEz + col0 + tx * 4]      = h0;
    *(ushort4*)&S[(size_t)r * NEz + col0 + 64 + tx * 4] = h1;
  }
}

// =====================================================================
// Batched (4-actor) fused GEMM(N=128) + LayerNorm (+ReLU).
// =====================================================================
struct LN4 {
  const float* W[4]; const float* b[4]; const float* g[4]; const float* be[4];
  int eoff[4]; int elen[4];
};

template<bool RELU, bool HASEXT>
__global__ __launch_bounds__(256)
void gemm_ln4(const float* __restrict__ A1base, size_t a1stride, int K1,
              const float* __restrict__ A2, LN4 p,
              float* __restrict__ outbase, size_t ostride)
{
  __shared__ float As[32][68];
  __shared__ float Bs[32][132];
  __shared__ float rsum[64][17];
  __shared__ float rsq[64][17];
  __shared__ float stm[64], str[64];
  const int a = blockIdx.y;
  const float* A1 = A1base + (size_t)a * a1stride;
  float* out = outbase + (size_t)a * ostride;
  const float* W = p.W[a];
  const float* bias = p.b[a];
  const float* g = p.g[a];
  const float* be = p.be[a];
  const int eoff = HASEXT ? p.eoff[a] : 0;
  const int K2 = HASEXT ? p.elen[a] : 0;

  const int t = threadIdx.x;
  const int tx = t & 15, ty = t >> 4;
  const int row0 = blockIdx.x * 64;
  const int Kt = K1 + K2;
  const int ar = t >> 2, ac = (t & 3) * 8;
  const int bk = t >> 3, bc = (t & 7) * 16;

  float acc[4][8];
#pragma unroll
  for (int i = 0; i < 4; ++i)
#pragma unroll
    for (int j = 0; j < 8; ++j) acc[i][j] = 0.f;

  for (int k0 = 0; k0 < Kt; k0 += 32) {
    const int grow = row0 + ar;
#pragma unroll
    for (int e = 0; e < 8; ++e) {
      const int k = k0 + ac + e;
      float v = 0.f;
      if (k < K1)      v = A1[(size_t)grow * K1 + k];
      else if (k < Kt) v = A2[(size_t)grow * 115 + eoff + (k - K1)];
      As[ac + e][ar] = v;
    }
    {
      const int k = k0 + bk;
#pragma unroll
      for (int qd = 0; qd < 4; ++qd) {
        float4 z; z.x = z.y = z.z = z.w = 0.f;
        *(float4*)&Bs[bk][bc + 4 * qd] =
            (k < Kt) ? *(const float4*)&W[(size_t)k * 128 + bc + 4 * qd] : z;
      }
    }
    __syncthreads();
#pragma unroll
    for (int kk = 0; kk < 32; ++kk) {
      float av[4], bv2[8];
      *(float4*)&av[0]  = *(const float4*)&As[kk][ty * 4];
      *(float4*)&bv2[0] = *(const float4*)&Bs[kk][tx * 4];
      *(float4*)&bv2[4] = *(const float4*)&Bs[kk][64 + tx * 4];
#pragma unroll
      for (int i = 0; i < 4; ++i)
#pragma unroll
        for (int j = 0; j < 8; ++j)
          acc[i][j] = fmaf(av[i], bv2[j], acc[i][j]);
    }
    __syncthreads();
  }

  float bv[8];
  *(float4*)&bv[0] = *(const float4*)&bias[tx * 4];
  *(float4*)&bv[4] = *(const float4*)&bias[64 + tx * 4];
#pragma unroll
  for (int i = 0; i < 4; ++i) {
    float s = 0.f, q = 0.f;
#pragma unroll
    for (int j = 0; j < 8; ++j) {
      acc[i][j] += bv[j];
      s += acc[i][j];
      q += acc[i][j] * acc[i][j];
    }
    rsum[ty * 4 + i][tx] = s;
    rsq[ty * 4 + i][tx]  = q;
  }
  __syncthreads();
  if (t < 64) {
    float s = 0.f, q = 0.f;
#pragma unroll
    for (int x = 0; x < 16; ++x) { s += rsum[t][x]; q += rsq[t][x]; }
    const float m = s * (1.f / 128.f);
    const float v = q * (1.f / 128.f) - m * m;
    stm[t] = m;
    str[t] = rsqrtf(v + 1e-5f);
  }
  __syncthreads();
#pragma unroll
  for (int i = 0; i < 4; ++i) {
    const int r = ty * 4 + i;
    const float m = stm[r], rs = str[r];
    float o[8];
#pragma unroll
    for (int j = 0; j < 8; ++j) {
      const int col = (j < 4) ? (tx * 4 + j) : (64 + tx * 4 + (j - 4));
      float y = (acc[i][j] - m) * rs * g[col] + be[col];
      if (RELU) y = fmaxf(y, 0.f);
      o[j] = y;
    }
    *(float4*)&out[(size_t)(row0 + r) * 128 + tx * 4]      = *(float4*)&o[0];
    *(float4*)&out[(size_t)(row0 + r) * 128 + 64 + tx * 4] = *(float4*)&o[4];
  }
}

// =====================================================================
// Block-wide (256 threads) sum helper
// =====================================================================
__device__ __forceinline__ float blockSum256(float v, float* sh)
{
#pragma unroll
  for (int d = 32; d; d >>= 1) v += __shfl_down(v, d, 64);
  __syncthreads();
  if ((threadIdx.x & 63) == 0) sh[threadIdx.x >> 6] = v;
  __syncthreads();
  return sh[0] + sh[1] + sh[2] + sh[3];
}

// =====================================================================
// Fused normalize+convert launch (fast path):
// blocks [0,Bz):        q row LN + L2 + bf16 out
// blocks [Bz, Bz+NEz):  key row norm + bf16(keys*rk) + rk
// =====================================================================
__global__ __launch_bounds__(256)
void norm_cvt_fused(float* __restrict__ q, const float* __restrict__ g,
                    const float* __restrict__ be, ushort_t* __restrict__ qb,
                    const float* __restrict__ keys, float* __restrict__ rk,
                    ushort_t* __restrict__ knb)
{
  __shared__ float sh[4];
  const int b = blockIdx.x, t = threadIdx.x;
  if (b < Bz) {
    const int row = b;
    float* qr = q + (size_t)row * Ez;
    float x[12];
#pragma unroll
    for (int i = 0; i < 12; ++i) x[i] = qr[t + (i << 8)];
    float s = 0.f;
#pragma unroll
    for (int i = 0; i < 12; ++i) s += x[i];
    const float m = blockSum256(s, sh) * (1.f / (float)Ez);
    float vs = 0.f;
#pragma unroll
    for (int i = 0; i < 12; ++i) { const float d = x[i] - m; vs += d * d; }
    const float v = blockSum256(vs, sh) * (1.f / (float)Ez);
    const float rs = rsqrtf(v + 1e-5f);
    float y[12]; float qs = 0.f;
#pragma unroll
    for (int i = 0; i < 12; ++i) {
      const int c = t + (i << 8);
      const float yy = (x[i] - m) * rs * g[c] + be[c];
      y[i] = yy; qs += yy * yy;
    }
    const float tot = blockSum256(qs, sh);
    const float s2 = rsqrtf(tot + 1e-12f);
#pragma unroll
    for (int i = 0; i < 12; ++i) {
      const int c = t + (i << 8);
      const float yn = y[i] * s2;
      qr[c] = yn;
      qb[(size_t)row * Ez + c] = f2bf(yn);
    }
  } else {
    const int row = b - Bz;
    const float* xr = keys + (size_t)row * Ez;
    float x[12]; float qs = 0.f;
#pragma unroll
    for (int i = 0; i < 12; ++i) { x[i] = xr[t + (i << 8)]; qs += x[i] * x[i]; }
    const float tot = blockSum256(qs, sh);
    const float s = rsqrtf(tot + 1e-12f);
    if (t == 0) rk[row] = s;
#pragma unroll
    for (int i = 0; i < 12; ++i)
      knb[(size_t)row * Ez + t + (i << 8)] = f2bf(x[i] * s);
  }
}

// Row LN (width 3072) + L2 normalize, in place (fallback)
__global__ __launch_bounds__(256)
void ln_l2_q(float* __restrict__ q, const float* __restrict__ g,
             const float* __restrict__ be)
{
  __shared__ float sh[4];
  const int row = blockIdx.x, t = threadIdx.x;
  float* qr = q + (size_t)row * Ez;
  float x[12];
#pragma unroll
  for (int i = 0; i < 12; ++i) x[i] = qr[t + (i << 8)];
  float s = 0.f;
#pragma unroll
  for (int i = 0; i < 12; ++i) s += x[i];
  const float m = blockSum256(s, sh) * (1.f / (float)Ez);
  float vs = 0.f;
#pragma unroll
  for (int i = 0; i < 12; ++i) { const float d = x[i] - m; vs += d * d; }
  const float v = blockSum256(vs, sh) * (1.f / (float)Ez);
  const float rs = rsqrtf(v + 1e-5f);
  float y[12]; float qs = 0.f;
#pragma unroll
  for (int i = 0; i < 12; ++i) {
    const int c = t + (i << 8);
    const float yy = (x[i] - m) * rs * g[c] + be[c];
    y[i] = yy; qs += yy * yy;
  }
  const float tot = blockSum256(qs, sh);
  const float s2 = rsqrtf(tot + 1e-12f);
#pragma unroll
  for (int i = 0; i < 12; ++i) qr[t + (i << 8)] = y[i] * s2;
}

// rk[n] only (fallback)
__global__ __launch_bounds__(256)
void keynorm(const float* __restrict__ keys, float* __restrict__ rk)
{
  __shared__ float sh[4];
  const int row = blockIdx.x, t = threadIdx.x;
  const float* xr = keys + (size_t)row * Ez;
  float qs = 0.f;
#pragma unroll
  for (int i = 0; i < 12; ++i) { const float x = xr[t + (i << 8)]; qs += x * x; }
  const float tot = blockSum256(qs, sh);
  if (t == 0) rk[row] = rsqrtf(tot + 1e-12f);
}

// Combined weight transpose+split: blockIdx.y<8 -> se_w2 (C=512),
// else se_w3 (C=3072). W is (512 x C), outputs (C x 512) hi/lo bf16.
__global__ __launch_bounds__(256)
void wt_split2(const float* __restrict__ w2, ushort_t* __restrict__ h2,
               ushort_t* __restrict__ l2v,
               const float* __restrict__ w3, ushort_t* __restrict__ h3,
               ushort_t* __restrict__ l3v)
{
  __shared__ float tile[64][65];
  const float* w; ushort_t* hT; ushort_t* lT; int C; int n0;
  if ((int)blockIdx.y < 8) { w = w2; hT = h2; lT = l2v; C = 512;  n0 = blockIdx.y * 64; }
  else                     { w = w3; hT = h3; lT = l3v; C = 3072; n0 = (blockIdx.y - 8) * 64; }
  const int k0 = blockIdx.x * 64;
  const int t = threadIdx.x;
  const int c = t & 63, r4 = t >> 6;
#pragma unroll
  for (int rr = 0; rr < 16; ++rr) {
    const int r = rr * 4 + r4;
    tile[r][c] = w[(size_t)(k0 + r) * C + n0 + c];
  }
  __syncthreads();
#pragma unroll
  for (int rr = 0; rr < 16; ++rr) {
    const int n = rr * 4 + r4;
    const float a = tile[c][n];
    const ushort_t h = f2bf(a);
    hT[(size_t)(n0 + n) * 512 + k0 + c] = h;
    lT[(size_t)(n0 + n) * 512 + k0 + c] = f2bf(a - bf2f(h));
  }
}

// cc_w1 (3072 x 512 fp32) -> transposed bf16 (512 x 3072), coalesced
__global__ __launch_bounds__(256)
void cvt_w1t_t(const float* __restrict__ w, ushort_t* __restrict__ out)
{
  __shared__ float tile[64][65];
  const int k0 = blockIdx.x * 64;   // 48 blocks
  const int n0 = blockIdx.y * 64;   // 8 blocks
  const int t = threadIdx.x;
  const int c = t & 63, r4 = t >> 6;
#pragma unroll
  for (int rr = 0; rr < 16; ++rr) {
    const int r = rr * 4 + r4;
    tile[r][c] = w[(size_t)(k0 + r) * 512 + n0 + c];
  }
  __syncthreads();
#pragma unroll
  for (int rr = 0; rr < 16; ++rr) {
    const int n = rr * 4 + r4;
    out[(size_t)(n0 + n) * Ez + k0 + c] = f2bf(tile[c][n]);
  }
}

// =====================================================================
// Top-16 per row of the 8192 x 4096 u16-key score matrix.
// =====================================================================
__global__ __launch_bounds__(256)
void topk16(const ushort_t* __restrict__ S, int* __restrict__ outIdx)
{
  __shared__ uint_t cand[64];
  const int row = blockIdx.x, t = threadIdx.x;
  const int w = t >> 6, lane = t & 63;
  const int base = (w << 10) + (lane << 4);
  const ushort_t* sr = S + (size_t)row * NEz + base;
  uint4 v0 = *(const uint4*)sr;
  uint4 v1 = *(const uint4*)(sr + 8);
  const uint_t cb = (uint_t)(4095 - base);
  uint_t p[16];
  p[0]  = ((v0.x & 0xFFFFu) << 12) | (cb - 0);
  p[1]  = ((v0.x >> 16)     << 12) | (cb - 1);
  p[2]  = ((v0.y & 0xFFFFu) << 12) | (cb - 2);
  p[3]  = ((v0.y >> 16)     << 12) | (cb - 3);
  p[4]  = ((v0.z & 0xFFFFu) << 12) | (cb - 4);
  p[5]  = ((v0.z >> 16)     << 12) | (cb - 5);
  p[6]  = ((v0.w & 0xFFFFu) << 12) | (cb - 6);
  p[7]  = ((v0.w >> 16)     << 12) | (cb - 7);
  p[8]  = ((v1.x & 0xFFFFu) << 12) | (cb - 8);
  p[9]  = ((v1.x >> 16)     << 12) | (cb - 9);
  p[10] = ((v1.y & 0xFFFFu) << 12) | (cb - 10);
  p[11] = ((v1.y >> 16)     << 12) | (cb - 11);
  p[12] = ((v1.z & 0xFFFFu) << 12) | (cb - 12);
  p[13] = ((v1.z >> 16)     << 12) | (cb - 13);
  p[14] = ((v1.w & 0xFFFFu) << 12) | (cb - 14);
  p[15] = ((v1.w >> 16)     << 12) | (cb - 15);

  for (int it = 0; it < 16; ++it) {
    uint_t m = p[0];
#pragma unroll
    for (int j = 1; j < 16; ++j) m = umax_(m, p[j]);
#pragma unroll
    for (int d = 1; d < 64; d <<= 1)
      m = umax_(m, (uint_t)__shfl_xor((int)m, d, 64));
    if (lane == it) cand[(w << 4) + it] = m;
#pragma unroll
    for (int j = 0; j < 16; ++j) p[j] = (p[j] == m) ? 0u : p[j];
  }
  __syncthreads();
  if (t < 64) {
    uint_t mine = cand[t];
    for (int it = 0; it < 16; ++it) {
      uint_t m = mine;
#pragma unroll
      for (int d = 1; d < 64; d <<= 1)
        m = umax_(m, (uint_t)__shfl_xor((int)m, d, 64));
      if (t == it) outIdx[(size_t)row * 16 + it] = 4095 - (int)(m & 0xFFFu);
      mine = (mine == m) ? 0u : mine;
    }
  }
}

// =====================================================================
// Fused rescore + gather: one block per batch row (16 candidates).
// ctxOut must NOT alias qn (fast path uses separate region).
// =====================================================================
template<bool BFOUT>
__global__ __launch_bounds__(256)
void rescore_gather(const float* __restrict__ qn, const float* __restrict__ keys,
                    const float* __restrict__ rk, const int* __restrict__ cand,
                    void* __restrict__ ctxOut)
{
  __shared__ float qs[Ez];
  __shared__ double sv[16];
  __shared__ int si[16];
  __shared__ int sel10[10];
  const int row = blockIdx.x, t = threadIdx.x;
  const int w = t >> 6, lane = t & 63;

  {
    const float* qr = qn + (size_t)row * Ez;
#pragma unroll
    for (int i = 0; i < 3; ++i) {
      const int c = (t << 2) + (i << 10);
      *(float4*)&qs[c] = *(const float4*)&qr[c];
    }
  }
  __syncthreads();

#pragma unroll
  for (int cc = 0; cc < 4; ++cc) {
    const int slot = w * 4 + cc;
    const int id = cand[(size_t)row * 16 + slot];
    const float* kr = keys + (size_t)id * Ez;
    double s = 0.0;
#pragma unroll
    for (int it = 0; it < 12; ++it) {
      const int c = (lane << 2) + (it << 8);
      float4 k4 = *(const float4*)&kr[c];
      float4 q4 = *(const float4*)&qs[c];
      s += (double)q4.x * (double)k4.x;
      s += (double)q4.y * (double)k4.y;
      s += (double)q4.z * (double)k4.z;
      s += (double)q4.w * (double)k4.w;
    }
#pragma unroll
    for (int d = 32; d; d >>= 1) s += __shfl_down(s, d, 64);
    if (lane == 0) { sv[slot] = s * (double)rk[id]; si[slot] = id; }
  }
  __syncthreads();

  if (t == 0) {
    for (int it = 0; it < 10; ++it) {
      int bj = 0; double bvv = sv[0]; int bi = si[0];
      for (int j = 1; j < 16; ++j) {
        const double v = sv[j]; const int i2 = si[j];
        if (v > bvv || (v == bvv && i2 < bi)) { bj = j; bvv = v; bi = i2; }
      }
      sel10[it] = bi;
      sv[bj] = -1e300;
    }
  }
  __syncthreads();

  int id[10];
#pragma unroll
  for (int j = 0; j < 10; ++j) id[j] = sel10[j];

#pragma unroll
  for (int i = 0; i < 3; ++i) {
    const int c = (t << 2) + (i << 10);
    float4 a = {0.f, 0.f, 0.f, 0.f};
#pragma unroll
    for (int j = 0; j < 10; ++j) {
      float4 v = *(const float4*)&keys[(size_t)id[j] * Ez + c];
      a.x += v.x; a.y += v.y; a.z += v.z; a.w += v.w;
    }
    if (BFOUT) {
      ushort4 o;
      o.x = f2bf(a.x * 0.1f); o.y = f2bf(a.y * 0.1f);
      o.z = f2bf(a.z * 0.1f); o.w = f2bf(a.w * 0.1f);
      *(ushort4*)&((ushort_t*)ctxOut)[(size_t)row * Ez + c] = o;
    } else {
      float4 o;
      o.x = a.x * 0.1f; o.y = a.y * 0.1f; o.z = a.z * 0.1f; o.w = a.w * 0.1f;
      *(float4*)&((float*)ctxOut)[(size_t)row * Ez + c] = o;
    }
  }
}

// =====================================================================
// Router: 115 -> 64 -> 64 -> 4, clip, + gumbel, softmax, straight-through
// =====================================================================
__global__ __launch_bounds__(256)
void router_kernel(const float* __restrict__ state, const float* __restrict__ gn,
                   const float* __restrict__ w1, const float* __restrict__ b1,
                   const float* __restrict__ w2, const float* __restrict__ b2,
                   const float* __restrict__ w3, const float* __restrict__ b3,
                   float* __restrict__ outAlpha)
{
  const int row = blockIdx.x * 256 + threadIdx.x;
  const float* sr = state + (size_t)row * Sz;
  float h1[64];
#pragma unroll
  for (int j = 0; j < 64; ++j) h1[j] = b1[j];
  for (int k = 0; k < Sz; ++k) {
    const float a = sr[k];
    const float* wr = w1 + (size_t)k * 64;
#pragma unroll
    for (int j = 0; j < 64; ++j) h1[j] = fmaf(a, wr[j], h1[j]);
  }
#pragma unroll
  for (int j = 0; j < 64; ++j) h1[j] = fmaxf(h1[j], 0.f);
  float h2[64];
#pragma unroll
  for (int j = 0; j < 64; ++j) h2[j] = b2[j];
#pragma unroll
  for (int k = 0; k < 64; ++k) {
    const float a = h1[k];
    const float* wr = w2 + (size_t)k * 64;
#pragma unroll
    for (int j = 0; j < 64; ++j) h2[j] = fmaf(a, wr[j], h2[j]);
  }
#pragma unroll
  for (int j = 0; j < 64; ++j) h2[j] = fmaxf(h2[j], 0.f);
  float z[4];
#pragma unroll
  for (int a = 0; a < 4; ++a) {
    float s = b3[a];
#pragma unroll
    for (int k = 0; k < 64; ++k) s = fmaf(h2[k], w3[k * 4 + a], s);
    s = fminf(fmaxf(s, -20.f), 20.f);
    z[a] = s + gn[(size_t)row * 4 + a];   // TAU = 1
  }
  float mz = z[0];
#pragma unroll
  for (int a = 1; a < 4; ++a) mz = fmaxf(mz, z[a]);
  float e[4]; float se = 0.f;
#pragma unroll
  for (int a = 0; a < 4; ++a) { e[a] = expf(z[a] - mz); se += e[a]; }
  const float inv = 1.f / se;
  float y[4];
#pragma unroll
  for (int a = 0; a < 4; ++a) y[a] = e[a] * inv;
  int am = 0;
#pragma unroll
  for (int a = 1; a < 4; ++a) if (y[a] > y[am]) am = a;
#pragma unroll
  for (int a = 0; a < 4; ++a) {
    const float hard = (a == am) ? 1.f : 0.f;
    outAlpha[(size_t)row * 4 + a] = y[a] + (hard - y[a]);
  }
}

// critic head, coalesced: 128 blocks, wave handles 16 rows, lane = 4 cols
__global__ __launch_bounds__(256)
void critic_head(const float* __restrict__ c2, const float* __restrict__ w3,
                 const float* __restrict__ b3, float* __restrict__ outv)
{
  const int t = threadIdx.x;
  const int w = t >> 6, lane = t & 63;
  const int row0 = blockIdx.x * 64 + w * 16;
  float wv[4];
  *(float4*)&wv[0] = *(const float4*)&w3[lane * 4];
  const float b0 = b3[0];
#pragma unroll
  for (int rr = 0; rr < 16; ++rr) {
    const int row = row0 + rr;
    float4 x = *(const float4*)&c2[(size_t)row * 256 + lane * 4];
    float s = x.x * wv[0] + x.y * wv[1] + x.z * wv[2] + x.w * wv[3];
#pragma unroll
    for (int d = 32; d; d >>= 1) s += __shfl_down(s, d, 64);
    if (lane == 0) outv[row] = s + b0;
  }
}

// all-4 actor heads fused; 32 rows/block (256 blocks = full GPU)
struct HeadP { const float* w3[4]; const float* b3[4]; };

__global__ __launch_bounds__(256)
void actor_head4(const float* __restrict__ x2g, HeadP p,
                 const float* __restrict__ alpha, float* __restrict__ outL)
{
  __shared__ float wsm[4][128 * 23];
  __shared__ float bs[4][23];
  const int t = threadIdx.x;
#pragma unroll
  for (int a = 0; a < 4; ++a) {
    for (int i = t; i < 128 * 23; i += 256) wsm[a][i] = p.w3[a][i];
    if (t < 23) bs[a][t] = p.b3[a][t];
  }
  __syncthreads();
  const int row = blockIdx.x * 32 + (t >> 3);
  const int cg = t & 7;
  float sum[3] = {0.f, 0.f, 0.f};
#pragma unroll
  for (int a = 0; a < 4; ++a) {
    const float al = alpha[(size_t)row * 4 + a];
    const float* xr = x2g + (size_t)a * Bz * 128 + (size_t)row * 128;
    float acc[3] = {0.f, 0.f, 0.f};
    for (int kk = 0; kk < 128; ++kk) {
      const float xa = xr[kk];
#pragma unroll
      for (int j = 0; j < 3; ++j) {
        const int col = cg + 8 * j;
        if (col < 23) acc[j] = fmaf(xa, wsm[a][kk * 23 + col], acc[j]);
      }
    }
#pragma unroll
    for (int j = 0; j < 3; ++j) {
      const int col = cg + 8 * j;
      if (col < 23) sum[j] += al * (acc[j] + bs[a][col]);
    }
  }
#pragma unroll
  for (int j = 0; j < 3; ++j) {
    const int col = cg + 8 * j;
    if (col < 23) outL[(size_t)row * 23 + col] = sum[j];
  }
}

// =====================================================================
extern "C" void kernel_launch(void* const* d_in, const int* in_sizes, int n_in,
                              void* d_out, int out_size, void* d_ws, size_t ws_size,
                              hipStream_t stream)
{
  const float* state  = (const float*)d_in[0];
  const float* gumbel = (const float*)d_in[1];
  const float* keys   = (const float*)d_in[2];
  const float* se_w1 = (const float*)d_in[3];
  const float* se_b1 = (const float*)d_in[4];
  const float* se_w2 = (const float*)d_in[5];
  const float* se_b2 = (const float*)d_in[6];
  const float* se_w3 = (const float*)d_in[7];
  const float* se_b3 = (const float*)d_in[8];
  const float* se_g  = (const float*)d_in[9];
  const float* se_be = (const float*)d_in[10];
  const float* cc_w1 = (const float*)d_in[11];
  const float* cc_b1 = (const float*)d_in[12];
  const float* cc_w2 = (const float*)d_in[13];
  const float* cc_b2 = (const float*)d_in[14];
  const float* cc_g  = (const float*)d_in[15];
  const float* cc_be = (const float*)d_in[16];
  const float* r_w1 = (const float*)d_in[57];
  const float* r_b1 = (const float*)d_in[58];
  const float* r_w2 = (const float*)d_in[59];
  const float* r_b2 = (const float*)d_in[60];
  const float* r_w3 = (const float*)d_in[61];
  const float* r_b3 = (const float*)d_in[62];
  const float* c_w1 = (const float*)d_in[63];
  const float* c_b1 = (const float*)d_in[64];
  const float* c_w2 = (const float*)d_in[65];
  const float* c_b2 = (const float*)d_in[66];
  const float* c_w3 = (const float*)d_in[67];
  const float* c_b3 = (const float*)d_in[68];

  // ---- workspace layout ----
  float* wsf = (float*)d_ws;
  const size_t qF = (size_t)Bz * Ez;          // 25,165,824 floats
  const size_t uF = (size_t)16777216;         // union region, floats
  float* q = wsf;
  float* U = wsf + qF;
  // U internal (time-multiplexed), float offsets:
  ushort_t* sAh  = (ushort_t*)(U + 0);          // 8192x512 halves
  ushort_t* sAl  = (ushort_t*)(U + 2097152);
  ushort_t* sBh  = (ushort_t*)(U + 4194304);
  ushort_t* sBl  = (ushort_t*)(U + 6291456);
  ushort_t* w3hT = (ushort_t*)(U + 8388608);    // 3072x512 halves
  ushort_t* w3lT = (ushort_t*)(U + 9175040);
  ushort_t* w2hT = (ushort_t*)(U + 9961472);    // 512x512 halves
  ushort_t* w2lT = (ushort_t*)(U + 10092544);
  // fallback path fp32 buffers (same region, stream-ordered):
  float* sA = U;                                 // 8192x512 fp32 (fallback)
  float* sB = U + 4194304;                       // 8192x512 fp32 (fallback)
  ushort_t* scoresU = (ushort_t*)U;              // 8192x4096 u16 (whole U)
  ushort_t* ctxb = (ushort_t*)U;                 // bf16 ctx (8192x3072 halves),
                                                 // overlays dead scores post-topk
  float* cch = U + 12582912;                     // 8192x512 fp32
  float* shr = U;                                // 8192x128 (post-ctx phase)
  float* x1g = U + 1 * 1048576;                  // 4 x 8192x128
  float* x2g = U + 5 * 1048576;                  // 4 x 8192x128
  // critic temporaries in the (not yet written) q region:
  float* cr1 = q;                                // 8192x256
  float* cr2 = q + 2097152;                      // 8192x256
  // fast-path bf16 buffers after U:
  ushort_t* qbf  = (ushort_t*)(wsf + qF + uF);   // 8192x3072
  ushort_t* knbf = qbf + qF;                     // 4096x3072
  ushort_t* w1T  = knbf + (size_t)NEz * Ez;      // 512x3072
  const size_t bfHalves = qF + (size_t)NEz * Ez + (size_t)512 * Ez;
  const size_t baseBytes = (qF + uF) * sizeof(float);
  const size_t tailBytes = 4096 * 4 + (size_t)Bz * 16 * 4;
  const bool fast = ws_size >= baseBytes + bfHalves * 2 + tailBytes;
  float* tailF = (float*)((char*)d_ws + (fast ? baseBytes + bfHalves * 2 : baseBytes));
  float* rk  = tailF;
  int* cand  = (int*)(tailF + 4096);

  float* outL = (float*)d_out;                 // 8192*23
  float* outA = outL + (size_t)Bz * 23;        // 8192*4
  float* outV = outA + (size_t)Bz * 4;         // 8192*1

  const dim3 blk(256);

  // --- encoder L1 (hi/lo split out on fast path) + critic L1 ---
  {
    GPart e0 = {state, se_w1, se_b1, fast ? nullptr : sA,
                fast ? sAh : nullptr, fast ? sAl : nullptr, 512, 115, 4};
    GPart e1 = {state, c_w1, c_b1, cr1, nullptr, nullptr, 256, 115, 2};
    gemm128_dual<<<dim3(6, 64), blk, 0, stream>>>(e0, e1);
  }
  // --- critic L2 (fp32) ---
  gemm128<true, true><<<dim3(2, 64), blk, 0, stream>>>(cr1, c_w2, c_b2, cr2, 256, 256);

  if (fast) {
    // combined weight transpose+split (se_w2 + se_w3)
    wt_split2<<<dim3(8, 56), blk, 0, stream>>>(se_w2, w2hT, w2lT, se_w3, w3hT, w3lT);
    // encoder L2 via bf16x3 MFMA: relu + hi/lo split out
    mfma3_bt<1><<<dim3(4, 64), blk, 0, stream>>>(sAh, sAl, w2hT, w2lT, se_b2,
                                                 nullptr, sBh, sBl, 512, 512);
  } else {
    gemm128<true, true><<<dim3(4, 64), blk, 0, stream>>>(sA, se_w2, se_b2, sB, 512, 512);
  }

  // critic head + router (cr1/cr2 die before q is written)
  critic_head<<<dim3(128), blk, 0, stream>>>(cr2, c_w3, c_b3, outV);
  router_kernel<<<dim3(32), blk, 0, stream>>>(state, gumbel, r_w1, r_b1, r_w2, r_b2,
                                              r_w3, r_b3, outA);

  if (fast) {
    // encoder L3 (se_w3) via bf16x3 MFMA -> q fp32
    mfma3_bt<0><<<dim3(24, 64), blk, 0, stream>>>(sBh, sBl, w3hT, w3lT, se_b3,
                                                  q, nullptr, nullptr, 3072, 512);
    // fused: q LN+L2+bf16 and keys norm+bf16 in one launch
    norm_cvt_fused<<<dim3(Bz + NEz), blk, 0, stream>>>(q, se_g, se_be, qbf,
                                                       keys, rk, knbf);
    cvt_w1t_t<<<dim3(48, 8), blk, 0, stream>>>(cc_w1, w1T);
    // screen: 256x256-tile 4-phase pipelined MFMA (halved barrier count)
    screen256<<<dim3(16, 32), dim3(512), 0, stream>>>(qbf, knbf, scoresU, NEz, Ez);
  } else {
    gemm128<false, true><<<dim3(24, 64), blk, 0, stream>>>(sB, se_w3, se_b3, q, 3072, 512);
    ln_l2_q<<<dim3(Bz), blk, 0, stream>>>(q, se_g, se_be);
    keynorm<<<dim3(NEz), blk, 0, stream>>>(keys, rk);
    gemm_scores<<<dim3(32, 64), blk, 0, stream>>>(q, keys, rk, scoresU);
  }

  // --- top-16 screen, fused fp64 rescore + top-10 set + context gather ---
  topk16<<<dim3(Bz), blk, 0, stream>>>(scoresU, cand);

  // --- context + compressor ---
  if (fast) {
    // ctx -> ctxb in U (scores dead after topk; NO aliasing with q)
    rescore_gather<true><<<dim3(Bz), blk, 0, stream>>>(q, keys, rk, cand, ctxb);
    mfma_bt64<<<dim3(4, 128), blk, 0, stream>>>(ctxb, w1T, cc_b1, cch, 512, Ez);
  } else {
    // fallback: ctx fp32 overlays q row-for-row (self-row only: safe)
    rescore_gather<false><<<dim3(Bz), blk, 0, stream>>>(q, keys, rk, cand, q);
    gemm128<true, true><<<dim3(4, 64), blk, 0, stream>>>(q, cc_w1, cc_b1, cch, 512, Ez);
  }
  {
    LN4 pcc = {};
    pcc.W[0] = cc_w2; pcc.b[0] = cc_b2; pcc.g[0] = cc_g; pcc.be[0] = cc_be;
    gemm_ln4<false, false><<<dim3(128, 1), blk, 0, stream>>>(cch, 0, 512, nullptr, pcc,
                                                             shr, 0);
  }

  // --- actors (batched over blockIdx.y) ---
  {
    LN4 p1 = {}, p2 = {};
    HeadP ph = {};
    const int eoffs[4] = {0, 20, 40, 45};
    const int elens[4] = {50, 20, 10, 15};
    for (int a = 0; a < 4; ++a) {
      const int base = 17 + 10 * a;
      p1.W[a]  = (const float*)d_in[base + 0];
      p1.b[a]  = (const float*)d_in[base + 1];
      p1.g[a]  = (const float*)d_in[base + 2];
      p1.be[a] = (const float*)d_in[base + 3];
      p1.eoff[a] = eoffs[a]; p1.elen[a] = elens[a];
      p2.W[a]  = (const float*)d_in[base + 4];
      p2.b[a]  = (const float*)d_in[base + 5];
      p2.g[a]  = (const float*)d_in[base + 6];
      p2.be[a] = (const float*)d_in[base + 7];
      ph.w3[a] = (const float*)d_in[base + 8];
      ph.b3[a] = (const float*)d_in[base + 9];
    }
    gemm_ln4<true, true ><<<dim3(128, 4), blk, 0, stream>>>(shr, 0, 128, state, p1,
                                                            x1g, (size_t)Bz * 128);
    gemm_ln4<true, false><<<dim3(128, 4), blk, 0, stream>>>(x1g, (size_t)Bz * 128, 128,
                                                            nullptr, p2,
                                                            x2g, (size_t)Bz * 128);
    actor_head4<<<dim3(256), blk, 0, stream>>>(x2g, ph, outA, outL);
  }
}

// Round 10
// 1226.896 us; speedup vs baseline: 1.0301x; 1.0003x over previous
//
#include <hip/hip_runtime.h>

// Problem constants (match reference)
constexpr int Bz = 8192;   // batch
constexpr int Sz = 115;    // state dim
constexpr int Ez = 3072;   // embedding dim
constexpr int NEz = 4096;  // num keys
// C=128, A=23, K=10, TAU=1, EPS=1e-5

typedef __attribute__((ext_vector_type(8))) short short8;
typedef __attribute__((ext_vector_type(4))) float floatx4;
typedef unsigned short ushort_t;
typedef unsigned int uint_t;

__device__ __forceinline__ ushort_t f2bf(float f) {
  uint_t u = __float_as_uint(f);
  uint_t r = (u + 0x7FFFu + ((u >> 16) & 1u)) >> 16;   // RNE
  return (ushort_t)r;
}
__device__ __forceinline__ float bf2f(ushort_t b) {
  uint_t u = ((uint_t)b) << 16;
  return __uint_as_float(u);
}
// fp32 -> fp16 -> order-preserving u16 key (monotone total order)
__device__ __forceinline__ ushort_t f2key(float v) {
  _Float16 h = (_Float16)v;
  ushort_t b = __builtin_bit_cast(ushort_t, h);
  return b ^ ((b & 0x8000u) ? 0xFFFFu : 0x8000u);
}
__device__ __forceinline__ uint_t umax_(uint_t a, uint_t b) { return a > b ? a : b; }

// async global->LDS, 16 B per lane; lds dest = wave-uniform base + lane*16
__device__ __forceinline__ void gload16(const ushort_t* g, ushort_t* l) {
  __builtin_amdgcn_global_load_lds(
      (__attribute__((address_space(1))) const void*)g,
      (__attribute__((address_space(3))) void*)l, 16, 0, 0);
}

// =====================================================================
// Generic fp32 tiled GEMM: C = act(A@B + bias). Used for critic L2 + fallback.
// =====================================================================
template<bool RELU, bool BIAS>
__global__ __launch_bounds__(256)
void gemm128(const float* __restrict__ A, const float* __restrict__ Bm,
             const float* __restrict__ bias, float* __restrict__ C,
             int N, int Kd)
{
  __shared__ float As[16][132];
  __shared__ float Bs[16][132];
  const int t  = threadIdx.x;
  const int tx = t & 15, ty = t >> 4;
  const int row0 = blockIdx.y * 128;
  const int col0 = blockIdx.x * 128;
  const int ar = t >> 2, ac = (t & 3) * 4;
  const int bk = t >> 5, bc = (t & 31) * 4;
  const bool a4 = (Kd & 3) == 0;

  float acc[8][8];
#pragma unroll
  for (int i = 0; i < 8; ++i)
#pragma unroll
    for (int j = 0; j < 8; ++j) acc[i][j] = 0.f;

  for (int k0 = 0; k0 < Kd; k0 += 16) {
    const bool fullA = (k0 + 16 <= Kd) && a4;
    {
      const float* ap = A + (size_t)(row0 + ar) * Kd + k0 + ac;
      if (fullA) {
        float4 v0 = *(const float4*)ap;
        float4 v1 = *(const float4*)(ap + (size_t)64 * Kd);
        As[ac + 0][ar] = v0.x; As[ac + 1][ar] = v0.y;
        As[ac + 2][ar] = v0.z; As[ac + 3][ar] = v0.w;
        As[ac + 0][ar + 64] = v1.x; As[ac + 1][ar + 64] = v1.y;
        As[ac + 2][ar + 64] = v1.z; As[ac + 3][ar + 64] = v1.w;
      } else {
#pragma unroll
        for (int e = 0; e < 4; ++e) {
          const int k = k0 + ac + e;
          float v0 = 0.f, v1 = 0.f;
          if (k < Kd) { v0 = ap[e]; v1 = ap[e + (size_t)64 * Kd]; }
          As[ac + e][ar] = v0; As[ac + e][ar + 64] = v1;
        }
      }
    }
    {
      const float* bp = Bm + (size_t)(k0 + bk) * N + col0 + bc;
      if (k0 + 16 <= Kd) {
        *(float4*)&Bs[bk][bc]     = *(const float4*)bp;
        *(float4*)&Bs[bk + 8][bc] = *(const float4*)(bp + (size_t)8 * N);
      } else {
        float4 z; z.x = z.y = z.z = z.w = 0.f;
        *(float4*)&Bs[bk][bc]     = (k0 + bk     < Kd) ? *(const float4*)bp : z;
        *(float4*)&Bs[bk + 8][bc] = (k0 + bk + 8 < Kd) ? *(const float4*)(bp + (size_t)8 * N) : z;
      }
    }
    __syncthreads();
#pragma unroll
    for (int kk = 0; kk < 16; ++kk) {
      float a[8], b[8];
      *(float4*)&a[0] = *(const float4*)&As[kk][ty * 4];
      *(float4*)&a[4] = *(const float4*)&As[kk][64 + ty * 4];
      *(float4*)&b[0] = *(const float4*)&Bs[kk][tx * 4];
      *(float4*)&b[4] = *(const float4*)&Bs[kk][64 + tx * 4];
#pragma unroll
      for (int i = 0; i < 8; ++i)
#pragma unroll
        for (int j = 0; j < 8; ++j)
          acc[i][j] = fmaf(a[i], b[j], acc[i][j]);
    }
    __syncthreads();
  }

  float bv[8];
#pragma unroll
  for (int j = 0; j < 8; ++j) bv[j] = 0.f;
  if (BIAS) {
    *(float4*)&bv[0] = *(const float4*)&bias[col0 + tx * 4];
    *(float4*)&bv[4] = *(const float4*)&bias[col0 + 64 + tx * 4];
  }
#pragma unroll
  for (int i = 0; i < 8; ++i) {
    const int r = row0 + ((i < 4) ? (ty * 4 + i) : (64 + ty * 4 + i - 4));
    float o[8];
#pragma unroll
    for (int j = 0; j < 8; ++j) {
      o[j] = acc[i][j] + bv[j];
      if (RELU) o[j] = fmaxf(o[j], 0.f);
    }
    *(float4*)&C[(size_t)r * N + col0 + tx * 4]      = *(float4*)&o[0];
    *(float4*)&C[(size_t)r * N + col0 + 64 + tx * 4] = *(float4*)&o[4];
  }
}

// =====================================================================
// Dual-part fp32 GEMM+ReLU+bias. Optional fp32 out (C) and bf16 hi/lo
// split outputs (Ch/Cl) — either may be null.
// =====================================================================
struct GPart {
  const float* A; const float* Bm; const float* bias;
  float* C; ushort_t* Ch; ushort_t* Cl;
  int N; int Kd; int nbx;
};

__global__ __launch_bounds__(256)
void gemm128_dual(GPart g0, GPart g1)
{
  __shared__ float As[16][132];
  __shared__ float Bs[16][132];
  const int t  = threadIdx.x;
  const int tx = t & 15, ty = t >> 4;
  const bool p0 = (int)blockIdx.x < g0.nbx;
  GPart g = p0 ? g0 : g1;
  const int bx = p0 ? blockIdx.x : (blockIdx.x - g0.nbx);
  const int row0 = blockIdx.y * 128;
  const int col0 = bx * 128;
  const int Kd = g.Kd, N = g.N;
  const int ar = t >> 2, ac = (t & 3) * 4;
  const int bk = t >> 5, bc = (t & 31) * 4;
  const bool a4 = (Kd & 3) == 0;

  float acc[8][8];
#pragma unroll
  for (int i = 0; i < 8; ++i)
#pragma unroll
    for (int j = 0; j < 8; ++j) acc[i][j] = 0.f;

  for (int k0 = 0; k0 < Kd; k0 += 16) {
    const bool fullA = (k0 + 16 <= Kd) && a4;
    {
      const float* ap = g.A + (size_t)(row0 + ar) * Kd + k0 + ac;
      if (fullA) {
        float4 v0 = *(const float4*)ap;
        float4 v1 = *(const float4*)(ap + (size_t)64 * Kd);
        As[ac + 0][ar] = v0.x; As[ac + 1][ar] = v0.y;
        As[ac + 2][ar] = v0.z; As[ac + 3][ar] = v0.w;
        As[ac + 0][ar + 64] = v1.x; As[ac + 1][ar + 64] = v1.y;
        As[ac + 2][ar + 64] = v1.z; As[ac + 3][ar + 64] = v1.w;
      } else {
#pragma unroll
        for (int e = 0; e < 4; ++e) {
          const int k = k0 + ac + e;
          float v0 = 0.f, v1 = 0.f;
          if (k < Kd) { v0 = ap[e]; v1 = ap[e + (size_t)64 * Kd]; }
          As[ac + e][ar] = v0; As[ac + e][ar + 64] = v1;
        }
      }
    }
    {
      const float* bp = g.Bm + (size_t)(k0 + bk) * N + col0 + bc;
      if (k0 + 16 <= Kd) {
        *(float4*)&Bs[bk][bc]     = *(const float4*)bp;
        *(float4*)&Bs[bk + 8][bc] = *(const float4*)(bp + (size_t)8 * N);
      } else {
        float4 z; z.x = z.y = z.z = z.w = 0.f;
        *(float4*)&Bs[bk][bc]     = (k0 + bk     < Kd) ? *(const float4*)bp : z;
        *(float4*)&Bs[bk + 8][bc] = (k0 + bk + 8 < Kd) ? *(const float4*)(bp + (size_t)8 * N) : z;
      }
    }
    __syncthreads();
#pragma unroll
    for (int kk = 0; kk < 16; ++kk) {
      float a[8], b[8];
      *(float4*)&a[0] = *(const float4*)&As[kk][ty * 4];
      *(float4*)&a[4] = *(const float4*)&As[kk][64 + ty * 4];
      *(float4*)&b[0] = *(const float4*)&Bs[kk][tx * 4];
      *(float4*)&b[4] = *(const float4*)&Bs[kk][64 + tx * 4];
#pragma unroll
      for (int i = 0; i < 8; ++i)
#pragma unroll
        for (int j = 0; j < 8; ++j)
          acc[i][j] = fmaf(a[i], b[j], acc[i][j]);
    }
    __syncthreads();
  }

  float bv[8];
  *(float4*)&bv[0] = *(const float4*)&g.bias[col0 + tx * 4];
  *(float4*)&bv[4] = *(const float4*)&g.bias[col0 + 64 + tx * 4];
#pragma unroll
  for (int i = 0; i < 8; ++i) {
    const int r = row0 + ((i < 4) ? (ty * 4 + i) : (64 + ty * 4 + i - 4));
    float o[8];
#pragma unroll
    for (int j = 0; j < 8; ++j) o[j] = fmaxf(acc[i][j] + bv[j], 0.f);
    const size_t i0 = (size_t)r * N + col0 + tx * 4;
    const size_t i1 = i0 + 64;
    if (g.C) {
      *(float4*)&g.C[i0] = *(float4*)&o[0];
      *(float4*)&g.C[i1] = *(float4*)&o[4];
    }
    if (g.Ch) {
      ushort4 h0, l0, h1, l1;
      h0.x = f2bf(o[0]); l0.x = f2bf(o[0] - bf2f(h0.x));
      h0.y = f2bf(o[1]); l0.y = f2bf(o[1] - bf2f(h0.y));
      h0.z = f2bf(o[2]); l0.z = f2bf(o[2] - bf2f(h0.z));
      h0.w = f2bf(o[3]); l0.w = f2bf(o[3] - bf2f(h0.w));
      h1.x = f2bf(o[4]); l1.x = f2bf(o[4] - bf2f(h1.x));
      h1.y = f2bf(o[5]); l1.y = f2bf(o[5] - bf2f(h1.y));
      h1.z = f2bf(o[6]); l1.z = f2bf(o[6] - bf2f(h1.z));
      h1.w = f2bf(o[7]); l1.w = f2bf(o[7] - bf2f(h1.w));
      *(ushort4*)&g.Ch[i0] = h0; *(ushort4*)&g.Cl[i0] = l0;
      *(ushort4*)&g.Ch[i1] = h1; *(ushort4*)&g.Cl[i1] = l1;
    }
  }
}

// =====================================================================
// bf16 MFMA screen GEMM, 256x256 tile, 8 waves (2Mx4N), BK=64.
// 4-phase, SINGLE barrier per phase (vs r9's two):
// phase = { WVM(n); barrier; STA; WLG; MFMA; reads }.
// Formal safety: barrier(Q) requires all waves completed phase Q-1's
// body, which contains their WLG (lgkmcnt(0)) -> all reads issued in
// Q-2 are COMPLETE at barrier(Q); every stage targets a region last
// read exactly 2 phases earlier -> stage-after-barrier is safe.
// vmcnt tightened per-phase {P1:6, P2:2, P3:6, P4:2}: each leaves only
// the DMAs younger than the staging of the regions this phase's READS
// touch (in-order vmcnt completion -> formal guarantee, replacing r9's
// latency argument). Zero practical wait (waited-on DMAs >=1.2 phases
// ~3000cyc old >> 900cyc HBM latency).
// Race-fixed prologue (vmcnt->barrier->reads); epilogue drain kept.
// =====================================================================
__global__ __launch_bounds__(512, 2)
void screen256(const ushort_t* __restrict__ A, const ushort_t* __restrict__ B,
               ushort_t* __restrict__ Cout, int N, int Kd)
{
  __shared__ ushort_t AL[2 * 256 * 64];   // 64 KB
  __shared__ ushort_t BL[2 * 256 * 64];   // 64 KB
  const int t = threadIdx.x;
  const int lane = t & 63;
  const int wid = t >> 6;
  const int wr = wid >> 2;        // 0..1  M half of tile
  const int wc = wid & 3;         // 0..3  N quarter of tile
  const int mr = lane & 15, qd = lane >> 4;
  const int row0 = (int)blockIdx.y << 8;
  const int col0 = (int)blockIdx.x << 8;
  const int NT = Kd >> 6;         // 48 K-tiles

  // staging: per-lane inverse-swizzled global source, wave-uniform LDS dest
  const int l8 = lane >> 3;             // row within 8-row region
  const int c8 = (lane & 7) ^ l8;       // source 16B chunk (involution)
  const ushort_t* pA = A + (size_t)(row0 + wr * 128 + wc * 16 + l8) * Kd + c8 * 8;
  const ushort_t* pB = B + (size_t)(col0 + (wid >> 1) * 64 + (wid & 1) * 16 + l8) * Kd + c8 * 8;
  ushort_t* aWp = &AL[wr * 8192 + wc * 1024];
  ushort_t* bWp = &BL[(wid >> 1) * 4096 + (wid & 1) * 1024];

  // fragment reads: same XOR on the read side
  const int swz = (mr & 7) << 4;                  // byte XOR
  const int aRow = (wr * 128 + mr) * 64;
  const int bRow = (wc * 64 + mr) * 64;
  const int cu0 = ((qd * 16) ^ swz) >> 1;         // ksub 0 (ushort units)
  const int cu1 = ((64 + qd * 16) ^ swz) >> 1;    // ksub 1

  floatx4 acc[8][4];
#pragma unroll
  for (int i = 0; i < 8; ++i)
#pragma unroll
    for (int j = 0; j < 4; ++j) acc[i][j] = (floatx4){0.f, 0.f, 0.f, 0.f};

  // fragment registers: A-halves double-buffered across phases;
  // B-halves live across the two phases of each K-tile.
  short8 A0r[4][2], A1r[4][2], B0r[2][2], B1r[2][2];

#define STA(db, h, tile) do {                                            \
    const int kt_ = ((tile) < NT ? (tile) : 0) << 6;                     \
    gload16(pA + (size_t)((h) * 64) * Kd + kt_,                          \
            aWp + (db) * 16384 + (h) * 4096);                            \
    gload16(pA + (size_t)((h) * 64 + 8) * Kd + kt_,                      \
            aWp + (db) * 16384 + (h) * 4096 + 512);                      \
  } while (0)
#define STB(db, g, tile) do {                                            \
    const int kt_ = ((tile) < NT ? (tile) : 0) << 6;                     \
    gload16(pB + (size_t)((g) * 32) * Kd + kt_,                          \
            bWp + (db) * 16384 + (g) * 2048);                            \
    gload16(pB + (size_t)((g) * 32 + 8) * Kd + kt_,                      \
            bWp + (db) * 16384 + (g) * 2048 + 512);                      \
  } while (0)
#define LDAm(dst, db, half)                                              \
  _Pragma("unroll")                                                      \
  for (int i_ = 0; i_ < 4; ++i_) {                                       \
    const int b_ = (db) * 16384 + aRow + ((half) * 4 + i_) * 1024;       \
    dst[i_][0] = *(const short8*)&AL[b_ + cu0];                          \
    dst[i_][1] = *(const short8*)&AL[b_ + cu1];                          \
  }
#define LDBm(dst, db, jh)                                                \
  _Pragma("unroll")                                                      \
  for (int j_ = 0; j_ < 2; ++j_) {                                       \
    const int b_ = (db) * 16384 + bRow + ((jh) * 2 + j_) * 1024;         \
    dst[j_][0] = *(const short8*)&BL[b_ + cu0];                          \
    dst[j_][1] = *(const short8*)&BL[b_ + cu1];                          \
  }
// 16 MFMAs for one (ih,jh) quadrant: 8 independent ksub0, then 8 ksub1
#define MMq(ih, jh, As_, Bs_)                                            \
  _Pragma("unroll")                                                      \
  for (int s_ = 0; s_ < 2; ++s_)                                         \
    _Pragma("unroll")                                                    \
    for (int i_ = 0; i_ < 4; ++i_)                                       \
      _Pragma("unroll")                                                  \
      for (int j_ = 0; j_ < 2; ++j_)                                     \
        acc[(ih)*4+i_][(jh)*2+j_] = __builtin_amdgcn_mfma_f32_16x16x32_bf16( \
            As_[i_][s_], Bs_[j_][s_], acc[(ih)*4+i_][(jh)*2+j_], 0, 0, 0);
#define BARM() do { __builtin_amdgcn_s_barrier();                        \
                    asm volatile("" ::: "memory"); } while (0)
#define WLG()  do { asm volatile("s_waitcnt lgkmcnt(0)" ::: "memory");   \
                    __builtin_amdgcn_sched_barrier(0); } while (0)
#define WVM(n) asm volatile("s_waitcnt vmcnt(" #n ")" ::: "memory")
#define PRIO1() __builtin_amdgcn_s_setprio(1)
#define PRIO0() __builtin_amdgcn_s_setprio(0)
// single-barrier phase: WVM(n); barrier; stage; WLG; 32-MFMA; unpinned reads
#define PHASE1(n, ih, STAGES, READS)                                     \
  do {                                                                   \
    WVM(n);                                                              \
    BARM();                                                              \
    STAGES;                                                              \
    WLG();                                                               \
    PRIO1(); MMq(ih, 0, (ih ? A1r : A0r), B0r);                          \
             MMq(ih, 1, (ih ? A1r : A0r), B1r); PRIO0();                 \
    READS;                                                               \
  } while (0)

  // prologue (race-fixed): buf0 <- tile0 (8 DMAs), buf1-ABB <- tile1 (6);
  // own-vmcnt(6) [buf0 landed] -> BARRIER [all waves visible] -> initial
  // reads of buf0 {A0,B0,B1} (the steady-state "P4-end" reads).
  STA(0, 0, 0); STB(0, 0, 0); STB(0, 1, 0); STA(0, 1, 0);
  STA(1, 0, 1); STB(1, 0, 1); STB(1, 1, 1);
  WVM(6);
  BARM();
  LDAm(A0r, 0, 0); LDBm(B0r, 0, 0); LDBm(B1r, 0, 1);

  for (int it = 0; it < NT / 2; ++it) {
    const int tp = it * 2;
    // P1: vmcnt(6) [leaves P4' 6 -> P3''s buf0-A1 landed];
    //     stage buf1-A1 <- tp+1; MFMA A-lo(buf0) x B; read A1r <- buf0-A1
    PHASE1(6, 0, STA(1, 1, tp + 1), LDAm(A1r, 0, 1));
    // P2: vmcnt(2) [leaves P1's 2 -> P4''s buf1-ABB landed];
    //     stage buf0-{A0,B0,B1} <- tp+2; MFMA A-hi(buf0) x B;
    //     reads A0r,B0r,B1r <- buf1 (tile tp+1)
    PHASE1(2, 1, STA(0, 0, tp + 2); STB(0, 0, tp + 2); STB(0, 1, tp + 2),
           LDAm(A0r, 1, 0); LDBm(B0r, 1, 0); LDBm(B1r, 1, 1));
    // P3: vmcnt(6) [leaves P2's 6 -> P1's buf1-A1 landed];
    //     stage buf0-A1 <- tp+2; MFMA A-lo(buf1) x B; read A1r <- buf1-A1
    PHASE1(6, 0, STA(0, 1, tp + 2), LDAm(A1r, 1, 1));
    // P4: vmcnt(2) [leaves P3's 2 -> P2's buf0-ABB landed];
    //     stage buf1-{A0,B0,B1} <- tp+3; MFMA A-hi(buf1) x B;
    //     reads A0r,B0r,B1r <- buf0 (tile tp+2, next group)
    PHASE1(2, 1, STA(1, 0, tp + 3); STB(1, 0, tp + 3); STB(1, 1, tp + 3),
           LDAm(A0r, 0, 0); LDBm(B0r, 0, 0); LDBm(B1r, 0, 1));
  }

  // epilogue drain: never exit with LDS-DMA in flight
  asm volatile("s_waitcnt vmcnt(0) lgkmcnt(0)" ::: "memory");
  __syncthreads();

#undef STA
#undef STB
#undef LDAm
#undef LDBm
#undef MMq
#undef PHASE1
#undef BARM
#undef WLG
#undef WVM
#undef PRIO1
#undef PRIO0

  // epilogue: C/D layout col=lane&15, row=(lane>>4)*4+reg
#pragma unroll
  for (int i = 0; i < 8; ++i) {
#pragma unroll
    for (int j = 0; j < 4; ++j) {
      const int col = col0 + wc * 64 + j * 16 + mr;
#pragma unroll
      for (int r = 0; r < 4; ++r) {
        const int row = row0 + wr * 128 + i * 16 + qd * 4 + r;
        Cout[(size_t)row * N + col] = f2key(acc[i][j][r]);
      }
    }
  }
}

// =====================================================================
// bf16x3 split-precision MFMA GEMM (fp32-accurate): A@B^T + bias
// EPI=0: fp32 out (se_w3). EPI=1: relu then bf16 hi/lo split out (se_w2).
// =====================================================================
template<int EPI>
__global__ __launch_bounds__(256)
void mfma3_bt(const ushort_t* __restrict__ Ah, const ushort_t* __restrict__ Alo,
              const ushort_t* __restrict__ Bh, const ushort_t* __restrict__ Blo,
              const float* __restrict__ bias, float* __restrict__ Cout,
              ushort_t* __restrict__ Ch, ushort_t* __restrict__ Cl,
              int N, int Kd)
{
  __shared__ ushort_t AhL[128 * 32];
  __shared__ ushort_t AlL[128 * 32];
  __shared__ ushort_t BhL[128 * 32];
  __shared__ ushort_t BlL[128 * 32];
  const int t = threadIdx.x;
  const int wid = t >> 6, lane = t & 63;
  const int wr = wid >> 1, wc = wid & 1;
  const int row0 = blockIdx.y * 128;
  const int col0 = blockIdx.x * 128;
  const int srow = lane >> 2;
  const int scol = (lane & 3) * 8;

  const size_t aoff0 = (size_t)(row0 + wid * 16 + srow) * Kd + scol;
  const size_t aoff1 = (size_t)(row0 + (wid + 4) * 16 + srow) * Kd + scol;
  const size_t boff0 = (size_t)(col0 + wid * 16 + srow) * Kd + scol;
  const size_t boff1 = (size_t)(col0 + (wid + 4) * 16 + srow) * Kd + scol;
  const int l0 = (wid * 16) * 32;
  const int l1 = ((wid + 4) * 16) * 32;

  const int mr = lane & 15, qd = lane >> 4;

  floatx4 acc[4][4];
#pragma unroll
  for (int i = 0; i < 4; ++i)
#pragma unroll
    for (int j = 0; j < 4; ++j) acc[i][j] = (floatx4){0.f, 0.f, 0.f, 0.f};

  for (int kb = 0; kb < Kd; kb += 32) {
    gload16(Ah + aoff0 + kb, &AhL[l0]);
    gload16(Ah + aoff1 + kb, &AhL[l1]);
    gload16(Alo + aoff0 + kb, &AlL[l0]);
    gload16(Alo + aoff1 + kb, &AlL[l1]);
    gload16(Bh + boff0 + kb, &BhL[l0]);
    gload16(Bh + boff1 + kb, &BhL[l1]);
    gload16(Blo + boff0 + kb, &BlL[l0]);
    gload16(Blo + boff1 + kb, &BlL[l1]);
    __syncthreads();
    short8 ahF[4], alF[4], bhF[4], blF[4];
#pragma unroll
    for (int i = 0; i < 4; ++i) {
      const int o = (wr * 64 + i * 16 + mr) * 32 + qd * 8;
      ahF[i] = *(const short8*)&AhL[o];
      alF[i] = *(const short8*)&AlL[o];
    }
#pragma unroll
    for (int j = 0; j < 4; ++j) {
      const int o = (wc * 64 + j * 16 + mr) * 32 + qd * 8;
      bhF[j] = *(const short8*)&BhL[o];
      blF[j] = *(const short8*)&BlL[o];
    }
#pragma unroll
    for (int i = 0; i < 4; ++i)
#pragma unroll
      for (int j = 0; j < 4; ++j) {
        acc[i][j] = __builtin_amdgcn_mfma_f32_16x16x32_bf16(alF[i], bhF[j], acc[i][j], 0, 0, 0);
        acc[i][j] = __builtin_amdgcn_mfma_f32_16x16x32_bf16(ahF[i], blF[j], acc[i][j], 0, 0, 0);
        acc[i][j] = __builtin_amdgcn_mfma_f32_16x16x32_bf16(ahF[i], bhF[j], acc[i][j], 0, 0, 0);
      }
    __syncthreads();
  }

#pragma unroll
  for (int i = 0; i < 4; ++i) {
#pragma unroll
    for (int j = 0; j < 4; ++j) {
      const int col = col0 + wc * 64 + j * 16 + mr;
#pragma unroll
      for (int r = 0; r < 4; ++r) {
        const int row = row0 + wr * 64 + i * 16 + qd * 4 + r;
        const float v = acc[i][j][r] + bias[col];
        if (EPI == 0) {
          Cout[(size_t)row * N + col] = v;
        } else {
          const float y = fmaxf(v, 0.f);
          const ushort_t h = f2bf(y);
          Ch[(size_t)row * N + col] = h;
          Cl[(size_t)row * N + col] = f2bf(y - bf2f(h));
        }
      }
    }
  }
}

// =====================================================================
// bf16 MFMA GEMM, 64x128 tile (for cc_w1's small-M grid).
// A(M x K) bf16, B(N x K)^T bf16, out fp32 = relu(acc + bias). BK=64.
// =====================================================================
__global__ __launch_bounds__(256)
void mfma_bt64(const ushort_t* __restrict__ A, const ushort_t* __restrict__ B,
               const float* __restrict__ bias, float* __restrict__ Cout,
               int N, int Kd)
{
  __shared__ ushort_t Al[2 * 64 * 32];    // [sub][row][col]
  __shared__ ushort_t Bl[2 * 128 * 32];
  const int t = threadIdx.x;
  const int wid = t >> 6, lane = t & 63;
  const int row0 = blockIdx.y << 6;
  const int col0 = blockIdx.x << 7;
  const int srow = lane >> 2;
  const int scol = (lane & 3) * 8;
  const int mr = lane & 15, qd = lane >> 4;

  const ushort_t* gsrc[6];
  ushort_t* ldst[6];
#pragma unroll
  for (int m = 0; m < 6; ++m) {
    const int c = wid * 6 + m;
    if (c < 8) {        // A chunks: sub = c>>2, grp = c&3
      const int sub = c >> 2, grp = c & 3;
      gsrc[m] = A + (size_t)(row0 + grp * 16 + srow) * Kd + sub * 32 + scol;
      ldst[m] = &Al[sub * 2048 + (grp * 16 + srow) * 32];
    } else {            // B chunks: b = c-8, sub = b>>3, grp = b&7
      const int b = c - 8, sub = b >> 3, grp = b & 7;
      gsrc[m] = B + (size_t)(col0 + grp * 16 + srow) * Kd + sub * 32 + scol;
      ldst[m] = &Bl[sub * 4096 + (grp * 16 + srow) * 32];
    }
  }

  floatx4 acc[4][2];
#pragma unroll
  for (int i = 0; i < 4; ++i)
#pragma unroll
    for (int j = 0; j < 2; ++j) acc[i][j] = (floatx4){0.f, 0.f, 0.f, 0.f};

  for (int kb = 0; kb < Kd; kb += 64) {
#pragma unroll
    for (int m = 0; m < 6; ++m) gload16(gsrc[m] + kb, ldst[m]);
    __syncthreads();
#pragma unroll
    for (int sub = 0; sub < 2; ++sub) {
      short8 aF[4], bF[2];
#pragma unroll
      for (int i = 0; i < 4; ++i)
        aF[i] = *(const short8*)&Al[sub * 2048 + (i * 16 + mr) * 32 + qd * 8];
#pragma unroll
      for (int j = 0; j < 2; ++j)
        bF[j] = *(const short8*)&Bl[sub * 4096 + (wid * 32 + j * 16 + mr) * 32 + qd * 8];
#pragma unroll
      for (int i = 0; i < 4; ++i)
#pragma unroll
        for (int j = 0; j < 2; ++j)
          acc[i][j] = __builtin_amdgcn_mfma_f32_16x16x32_bf16(aF[i], bF[j], acc[i][j], 0, 0, 0);
    }
    __syncthreads();
  }

#pragma unroll
  for (int i = 0; i < 4; ++i) {
#pragma unroll
    for (int j = 0; j < 2; ++j) {
      const int col = col0 + wid * 32 + j * 16 + mr;
#pragma unroll
      for (int r = 0; r < 4; ++r) {
        const int row = row0 + i * 16 + qd * 4 + r;
        Cout[(size_t)row * N + col] = fmaxf(acc[i][j][r] + bias[col], 0.f);
      }
    }
  }
}

// =====================================================================
// fp32 scores GEMM (fallback path only) -> u16 score keys
// =====================================================================
__global__ __launch_bounds__(256)
void gemm_scores(const float* __restrict__ A, const float* __restrict__ Bm,
                 const float* __restrict__ rk, ushort_t* __restrict__ S)
{
  __shared__ float As[16][132];
  __shared__ float Bs[16][132];
  const int t  = threadIdx.x;
  const int tx = t & 15, ty = t >> 4;
  const int row0 = blockIdx.y * 128;
  const int col0 = blockIdx.x * 128;
  const int ar = t >> 2, ac = (t & 3) * 4;
  const int Kd = Ez;

  float acc[8][8];
#pragma unroll
  for (int i = 0; i < 8; ++i)
#pragma unroll
    for (int j = 0; j < 8; ++j) acc[i][j] = 0.f;

  for (int k0 = 0; k0 < Kd; k0 += 16) {
    {
      const float* ap = A + (size_t)(row0 + ar) * Kd + k0 + ac;
      float4 v0 = *(const float4*)ap;
      float4 v1 = *(const float4*)(ap + (size_t)64 * Kd);
      As[ac + 0][ar] = v0.x; As[ac + 1][ar] = v0.y;
      As[ac + 2][ar] = v0.z; As[ac + 3][ar] = v0.w;
      As[ac + 0][ar + 64] = v1.x; As[ac + 1][ar + 64] = v1.y;
      As[ac + 2][ar + 64] = v1.z; As[ac + 3][ar + 64] = v1.w;
    }
    {
      const float* bp = Bm + (size_t)(col0 + ar) * Kd + k0 + ac;
      float4 v0 = *(const float4*)bp;
      float4 v1 = *(const float4*)(bp + (size_t)64 * Kd);
      Bs[ac + 0][ar] = v0.x; Bs[ac + 1][ar] = v0.y;
      Bs[ac + 2][ar] = v0.z; Bs[ac + 3][ar] = v0.w;
      Bs[ac + 0][ar + 64] = v1.x; Bs[ac + 1][ar + 64] = v1.y;
      Bs[ac + 2][ar + 64] = v1.z; Bs[ac + 3][ar + 64] = v1.w;
    }
    __syncthreads();
#pragma unroll
    for (int kk = 0; kk < 16; ++kk) {
      float a[8], b[8];
      *(float4*)&a[0] = *(const float4*)&As[kk][ty * 4];
      *(float4*)&a[4] = *(const float4*)&As[kk][64 + ty * 4];
      *(float4*)&b[0] = *(const float4*)&Bs[kk][tx * 4];
      *(float4*)&b[4] = *(const float4*)&Bs[kk][64 + tx * 4];
#pragma unroll
      for (int i = 0; i < 8; ++i)
#pragma unroll
        for (int j = 0; j < 8; ++j)
          acc[i][j] = fmaf(a[i], b[j], acc[i][j]);
    }
    __syncthreads();
  }

  float rk0[8];
  *(float4*)&rk0[0] = *(const float4*)&rk[col0 + tx * 4];
  *(float4*)&rk0[4] = *(const float4*)&rk[col0 + 64 + tx * 4];
#pragma unroll
  for (int i = 0; i < 8; ++i) {
    const int r = row0 + ((i < 4) ? (ty * 4 + i) : (64 + ty * 4 + i - 4));
    ushort4 h0, h1;
    h0.x = f2key(acc[i][0] * rk0[0]); h0.y = f2key(acc[i][1] * rk0[1]);
    h0.z = f2key(acc[i][2] * rk0[2]); h0.w = f2key(acc[i][3] * rk0[3]);
    h1.x = f2key(acc[i][4] * rk0[4]); h1.y = f2key(acc[i][5] * rk0[5]);
    h1.z = f2key(acc[i][6] * rk0[6]); h1.w = f2key(acc[i][7] * rk0[7]);
    *(ushort4*)&S[(size_t)r * NEz + col0 + tx * 4]      = h0;
    *(ushort4*)&S[(size_t)r * NEz + col0 + 64 + tx * 4] = h1;
  }
}

// =====================================================================
// Batched (4-actor) fused GEMM(N=128) + LayerNorm (+ReLU).
// =====================================================================
struct LN4 {
  const float* W[4]; const float* b[4]; const float* g[4]; const float* be[4];
  int eoff[4]; int elen[4];
};

template<bool RELU, bool HASEXT>
__global__ __launch_bounds__(256)
void gemm_ln4(const float* __restrict__ A1base, size_t a1stride, int K1,
              const float* __restrict__ A2, LN4 p,
              float* __restrict__ outbase, size_t ostride)
{
  __shared__ float As[32][68];
  __shared__ float Bs[32][132];
  __shared__ float rsum[64][17];
  __shared__ float rsq[64][17];
  __shared__ float stm[64], str[64];
  const int a = blockIdx.y;
  const float* A1 = A1base + (size_t)a * a1stride;
  float* out = outbase + (size_t)a * ostride;
  const float* W = p.W[a];
  const float* bias = p.b[a];
  const float* g = p.g[a];
  const float* be = p.be[a];
  const int eoff = HASEXT ? p.eoff[a] : 0;
  const int K2 = HASEXT ? p.elen[a] : 0;

  const int t = threadIdx.x;
  const int tx = t & 15, ty = t >> 4;
  const int row0 = blockIdx.x * 64;
  const int Kt = K1 + K2;
  const int ar = t >> 2, ac = (t & 3) * 8;
  const int bk = t >> 3, bc = (t & 7) * 16;

  float acc[4][8];
#pragma unroll
  for (int i = 0; i < 4; ++i)
#pragma unroll
    for (int j = 0; j < 8; ++j) acc[i][j] = 0.f;

  for (int k0 = 0; k0 < Kt; k0 += 32) {
    const int grow = row0 + ar;
#pragma unroll
    for (int e = 0; e < 8; ++e) {
      const int k = k0 + ac + e;
      float v = 0.f;
      if (k < K1)      v = A1[(size_t)grow * K1 + k];
      else if (k < Kt) v = A2[(size_t)grow * 115 + eoff + (k - K1)];
      As[ac + e][ar] = v;
    }
    {
      const int k = k0 + bk;
#pragma unroll
      for (int qd = 0; qd < 4; ++qd) {
        float4 z; z.x = z.y = z.z = z.w = 0.f;
        *(float4*)&Bs[bk][bc + 4 * qd] =
            (k < Kt) ? *(const float4*)&W[(size_t)k * 128 + bc + 4 * qd] : z;
      }
    }
    __syncthreads();
#pragma unroll
    for (int kk = 0; kk < 32; ++kk) {
      float av[4], bv2[8];
      *(float4*)&av[0]  = *(const float4*)&As[kk][ty * 4];
      *(float4*)&bv2[0] = *(const float4*)&Bs[kk][tx * 4];
      *(float4*)&bv2[4] = *(const float4*)&Bs[kk][64 + tx * 4];
#pragma unroll
      for (int i = 0; i < 4; ++i)
#pragma unroll
        for (int j = 0; j < 8; ++j)
          acc[i][j] = fmaf(av[i], bv2[j], acc[i][j]);
    }
    __syncthreads();
  }

  float bv[8];
  *(float4*)&bv[0] = *(const float4*)&bias[tx * 4];
  *(float4*)&bv[4] = *(const float4*)&bias[64 + tx * 4];
#pragma unroll
  for (int i = 0; i < 4; ++i) {
    float s = 0.f, q = 0.f;
#pragma unroll
    for (int j = 0; j < 8; ++j) {
      acc[i][j] += bv[j];
      s += acc[i][j];
      q += acc[i][j] * acc[i][j];
    }
    rsum[ty * 4 + i][tx] = s;
    rsq[ty * 4 + i][tx]  = q;
  }
  __syncthreads();
  if (t < 64) {
    float s = 0.f, q = 0.f;
#pragma unroll
    for (int x = 0; x < 16; ++x) { s += rsum[t][x]; q += rsq[t][x]; }
    const float m = s * (1.f / 128.f);
    const float v = q * (1.f / 128.f) - m * m;
    stm[t] = m;
    str[t] = rsqrtf(v + 1e-5f);
  }
  __syncthreads();
#pragma unroll
  for (int i = 0; i < 4; ++i) {
    const int r = ty * 4 + i;
    const float m = stm[r], rs = str[r];
    float o[8];
#pragma unroll
    for (int j = 0; j < 8; ++j) {
      const int col = (j < 4) ? (tx * 4 + j) : (64 + tx * 4 + (j - 4));
      float y = (acc[i][j] - m) * rs * g[col] + be[col];
      if (RELU) y = fmaxf(y, 0.f);
      o[j] = y;
    }
    *(float4*)&out[(size_t)(row0 + r) * 128 + tx * 4]      = *(float4*)&o[0];
    *(float4*)&out[(size_t)(row0 + r) * 128 + 64 + tx * 4] = *(float4*)&o[4];
  }
}

// =====================================================================
// Block-wide (256 threads) sum helper
// =====================================================================
__device__ __forceinline__ float blockSum256(float v, float* sh)
{
#pragma unroll
  for (int d = 32; d; d >>= 1) v += __shfl_down(v, d, 64);
  __syncthreads();
  if ((threadIdx.x & 63) == 0) sh[threadIdx.x >> 6] = v;
  __syncthreads();
  return sh[0] + sh[1] + sh[2] + sh[3];
}

// =====================================================================
// Fused normalize+convert launch (fast path):
// blocks [0,Bz):        q row LN + L2 + bf16 out
// blocks [Bz, Bz+NEz):  key row norm + bf16(keys*rk) + rk
// =====================================================================
__global__ __launch_bounds__(256)
void norm_cvt_fused(float* __restrict__ q, const float* __restrict__ g,
                    const float* __restrict__ be, ushort_t* __restrict__ qb,
                    const float* __restrict__ keys, float* __restrict__ rk,
                    ushort_t* __restrict__ knb)
{
  __shared__ float sh[4];
  const int b = blockIdx.x, t = threadIdx.x;
  if (b < Bz) {
    const int row = b;
    float* qr = q + (size_t)row * Ez;
    float x[12];
#pragma unroll
    for (int i = 0; i < 12; ++i) x[i] = qr[t + (i << 8)];
    float s = 0.f;
#pragma unroll
    for (int i = 0; i < 12; ++i) s += x[i];
    const float m = blockSum256(s, sh) * (1.f / (float)Ez);
    float vs = 0.f;
#pragma unroll
    for (int i = 0; i < 12; ++i) { const float d = x[i] - m; vs += d * d; }
    const float v = blockSum256(vs, sh) * (1.f / (float)Ez);
    const float rs = rsqrtf(v + 1e-5f);
    float y[12]; float qs = 0.f;
#pragma unroll
    for (int i = 0; i < 12; ++i) {
      const int c = t + (i << 8);
      const float yy = (x[i] - m) * rs * g[c] + be[c];
      y[i] = yy; qs += yy * yy;
    }
    const float tot = blockSum256(qs, sh);
    const float s2 = rsqrtf(tot + 1e-12f);
#pragma unroll
    for (int i = 0; i < 12; ++i) {
      const int c = t + (i << 8);
      const float yn = y[i] * s2;
      qr[c] = yn;
      qb[(size_t)row * Ez + c] = f2bf(yn);
    }
  } else {
    const int row = b - Bz;
    const float* xr = keys + (size_t)row * Ez;
    float x[12]; float qs = 0.f;
#pragma unroll
    for (int i = 0; i < 12; ++i) { x[i] = xr[t + (i << 8)]; qs += x[i] * x[i]; }
    const float tot = blockSum256(qs, sh);
    const float s = rsqrtf(tot + 1e-12f);
    if (t == 0) rk[row] = s;
#pragma unroll
    for (int i = 0; i < 12; ++i)
      knb[(size_t)row * Ez + t + (i << 8)] = f2bf(x[i] * s);
  }
}

// Row LN (width 3072) + L2 normalize, in place (fallback)
__global__ __launch_bounds__(256)
void ln_l2_q(float* __restrict__ q, const float* __restrict__ g,
             const float* __restrict__ be)
{
  __shared__ float sh[4];
  const int row = blockIdx.x, t = threadIdx.x;
  float* qr = q + (size_t)row * Ez;
  float x[12];
#pragma unroll
  for (int i = 0; i < 12; ++i) x[i] = qr[t + (i << 8)];
  float s = 0.f;
#pragma unroll
  for (int i = 0; i < 12; ++i) s += x[i];
  const float m = blockSum256(s, sh) * (1.f / (float)Ez);
  float vs = 0.f;
#pragma unroll
  for (int i = 0; i < 12; ++i) { const float d = x[i] - m; vs += d * d; }
  const float v = blockSum256(vs, sh) * (1.f / (float)Ez);
  const float rs = rsqrtf(v + 1e-5f);
  float y[12]; float qs = 0.f;
#pragma unroll
  for (int i = 0; i < 12; ++i) {
    const int c = t + (i << 8);
    const float yy = (x[i] - m) * rs * g[c] + be[c];
    y[i] = yy; qs += yy * yy;
  }
  const float tot = blockSum256(qs, sh);
  const float s2 = rsqrtf(tot + 1e-12f);
#pragma unroll
  for (int i = 0; i < 12; ++i) qr[t + (i << 8)] = y[i] * s2;
}

// rk[n] only (fallback)
__global__ __launch_bounds__(256)
void keynorm(const float* __restrict__ keys, float* __restrict__ rk)
{
  __shared__ float sh[4];
  const int row = blockIdx.x, t = threadIdx.x;
  const float* xr = keys + (size_t)row * Ez;
  float qs = 0.f;
#pragma unroll
  for (int i = 0; i < 12; ++i) { const float x = xr[t + (i << 8)]; qs += x * x; }
  const float tot = blockSum256(qs, sh);
  if (t == 0) rk[row] = rsqrtf(tot + 1e-12f);
}

// Combined weight transpose+split: blockIdx.y<8 -> se_w2 (C=512),
// else se_w3 (C=3072). W is (512 x C), outputs (C x 512) hi/lo bf16.
__global__ __launch_bounds__(256)
void wt_split2(const float* __restrict__ w2, ushort_t* __restrict__ h2,
               ushort_t* __restrict__ l2v,
               const float* __restrict__ w3, ushort_t* __restrict__ h3,
               ushort_t* __restrict__ l3v)
{
  __shared__ float tile[64][65];
  const float* w; ushort_t* hT; ushort_t* lT; int C; int n0;
  if ((int)blockIdx.y < 8) { w = w2; hT = h2; lT = l2v; C = 512;  n0 = blockIdx.y * 64; }
  else                     { w = w3; hT = h3; lT = l3v; C = 3072; n0 = (blockIdx.y - 8) * 64; }
  const int k0 = blockIdx.x * 64;
  const int t = threadIdx.x;
  const int c = t & 63, r4 = t >> 6;
#pragma unroll
  for (int rr = 0; rr < 16; ++rr) {
    const int r = rr * 4 + r4;
    tile[r][c] = w[(size_t)(k0 + r) * C + n0 + c];
  }
  __syncthreads();
#pragma unroll
  for (int rr = 0; rr < 16; ++rr) {
    const int n = rr * 4 + r4;
    const float a = tile[c][n];
    const ushort_t h = f2bf(a);
    hT[(size_t)(n0 + n) * 512 + k0 + c] = h;
    lT[(size_t)(n0 + n) * 512 + k0 + c] = f2bf(a - bf2f(h));
  }
}

// cc_w1 (3072 x 512 fp32) -> transposed bf16 (512 x 3072), coalesced
__global__ __launch_bounds__(256)
void cvt_w1t_t(const float* __restrict__ w, ushort_t* __restrict__ out)
{
  __shared__ float tile[64][65];
  const int k0 = blockIdx.x * 64;   // 48 blocks
  const int n0 = blockIdx.y * 64;   // 8 blocks
  const int t = threadIdx.x;
  const int c = t & 63, r4 = t >> 6;
#pragma unroll
  for (int rr = 0; rr < 16; ++rr) {
    const int r = rr * 4 + r4;
    tile[r][c] = w[(size_t)(k0 + r) * 512 + n0 + c];
  }
  __syncthreads();
#pragma unroll
  for (int rr = 0; rr < 16; ++rr) {
    const int n = rr * 4 + r4;
    out[(size_t)(n0 + n) * Ez + k0 + c] = f2bf(tile[c][n]);
  }
}

// =====================================================================
// Top-16 per row of the 8192 x 4096 u16-key score matrix.
// =====================================================================
__global__ __launch_bounds__(256)
void topk16(const ushort_t* __restrict__ S, int* __restrict__ outIdx)
{
  __shared__ uint_t cand[64];
  const int row = blockIdx.x, t = threadIdx.x;
  const int w = t >> 6, lane = t & 63;
  const int base = (w << 10) + (lane << 4);
  const ushort_t* sr = S + (size_t)row * NEz + base;
  uint4 v0 = *(const uint4*)sr;
  uint4 v1 = *(const uint4*)(sr + 8);
  const uint_t cb = (uint_t)(4095 - base);
  uint_t p[16];
  p[0]  = ((v0.x & 0xFFFFu) << 12) | (cb - 0);
  p[1]  = ((v0.x >> 16)     << 12) | (cb - 1);
  p[2]  = ((v0.y & 0xFFFFu) << 12) | (cb - 2);
  p[3]  = ((v0.y >> 16)     << 12) | (cb - 3);
  p[4]  = ((v0.z & 0xFFFFu) << 12) | (cb - 4);
  p[5]  = ((v0.z >> 16)     << 12) | (cb - 5);
  p[6]  = ((v0.w & 0xFFFFu) << 12) | (cb - 6);
  p[7]  = ((v0.w >> 16)     << 12) | (cb - 7);
  p[8]  = ((v1.x & 0xFFFFu) << 12) | (cb - 8);
  p[9]  = ((v1.x >> 16)     << 12) | (cb - 9);
  p[10] = ((v1.y & 0xFFFFu) << 12) | (cb - 10);
  p[11] = ((v1.y >> 16)     << 12) | (cb - 11);
  p[12] = ((v1.z & 0xFFFFu) << 12) | (cb - 12);
  p[13] = ((v1.z >> 16)     << 12) | (cb - 13);
  p[14] = ((v1.w & 0xFFFFu) << 12) | (cb - 14);
  p[15] = ((v1.w >> 16)     << 12) | (cb - 15);

  for (int it = 0; it < 16; ++it) {
    uint_t m = p[0];
#pragma unroll
    for (int j = 1; j < 16; ++j) m = umax_(m, p[j]);
#pragma unroll
    for (int d = 1; d < 64; d <<= 1)
      m = umax_(m, (uint_t)__shfl_xor((int)m, d, 64));
    if (lane == it) cand[(w << 4) + it] = m;
#pragma unroll
    for (int j = 0; j < 16; ++j) p[j] = (p[j] == m) ? 0u : p[j];
  }
  __syncthreads();
  if (t < 64) {
    uint_t mine = cand[t];
    for (int it = 0; it < 16; ++it) {
      uint_t m = mine;
#pragma unroll
      for (int d = 1; d < 64; d <<= 1)
        m = umax_(m, (uint_t)__shfl_xor((int)m, d, 64));
      if (t == it) outIdx[(size_t)row * 16 + it] = 4095 - (int)(m & 0xFFFu);
      mine = (mine == m) ? 0u : mine;
    }
  }
}

// =====================================================================
// Fused rescore + gather: one block per batch row (16 candidates).
// ctxOut must NOT alias qn (fast path uses separate region).
// =====================================================================
template<bool BFOUT>
__global__ __launch_bounds__(256)
void rescore_gather(const float* __restrict__ qn, const float* __restrict__ keys,
                    const float* __restrict__ rk, const int* __restrict__ cand,
                    void* __restrict__ ctxOut)
{
  __shared__ float qs[Ez];
  __shared__ double sv[16];
  __shared__ int si[16];
  __shared__ int sel10[10];
  const int row = blockIdx.x, t = threadIdx.x;
  const int w = t >> 6, lane = t & 63;

  {
    const float* qr = qn + (size_t)row * Ez;
#pragma unroll
    for (int i = 0; i < 3; ++i) {
      const int c = (t << 2) + (i << 10);
      *(float4*)&qs[c] = *(const float4*)&qr[c];
    }
  }
  __syncthreads();

#pragma unroll
  for (int cc = 0; cc < 4; ++cc) {
    const int slot = w * 4 + cc;
    const int id = cand[(size_t)row * 16 + slot];
    const float* kr = keys + (size_t)id * Ez;
    double s = 0.0;
#pragma unroll
    for (int it = 0; it < 12; ++it) {
      const int c = (lane << 2) + (it << 8);
      float4 k4 = *(const float4*)&kr[c];
      float4 q4 = *(const float4*)&qs[c];
      s += (double)q4.x * (double)k4.x;
      s += (double)q4.y * (double)k4.y;
      s += (double)q4.z * (double)k4.z;
      s += (double)q4.w * (double)k4.w;
    }
#pragma unroll
    for (int d = 32; d; d >>= 1) s += __shfl_down(s, d, 64);
    if (lane == 0) { sv[slot] = s * (double)rk[id]; si[slot] = id; }
  }
  __syncthreads();

  if (t == 0) {
    for (int it = 0; it < 10; ++it) {
      int bj = 0; double bvv = sv[0]; int bi = si[0];
      for (int j = 1; j < 16; ++j) {
        const double v = sv[j]; const int i2 = si[j];
        if (v > bvv || (v == bvv && i2 < bi)) { bj = j; bvv = v; bi = i2; }
      }
      sel10[it] = bi;
      sv[bj] = -1e300;
    }
  }
  __syncthreads();

  int id[10];
#pragma unroll
  for (int j = 0; j < 10; ++j) id[j] = sel10[j];

#pragma unroll
  for (int i = 0; i < 3; ++i) {
    const int c = (t << 2) + (i << 10);
    float4 a = {0.f, 0.f, 0.f, 0.f};
#pragma unroll
    for (int j = 0; j < 10; ++j) {
      float4 v = *(const float4*)&keys[(size_t)id[j] * Ez + c];
      a.x += v.x; a.y += v.y; a.z += v.z; a.w += v.w;
    }
    if (BFOUT) {
      ushort4 o;
      o.x = f2bf(a.x * 0.1f); o.y = f2bf(a.y * 0.1f);
      o.z = f2bf(a.z * 0.1f); o.w = f2bf(a.w * 0.1f);
      *(ushort4*)&((ushort_t*)ctxOut)[(size_t)row * Ez + c] = o;
    } else {
      float4 o;
      o.x = a.x * 0.1f; o.y = a.y * 0.1f; o.z = a.z * 0.1f; o.w = a.w * 0.1f;
      *(float4*)&((float*)ctxOut)[(size_t)row * Ez + c] = o;
    }
  }
}

// =====================================================================
// Router: 115 -> 64 -> 64 -> 4, clip, + gumbel, softmax, straight-through
// =====================================================================
__global__ __launch_bounds__(256)
void router_kernel(const float* __restrict__ state, const float* __restrict__ gn,
                   const float* __restrict__ w1, const float* __restrict__ b1,
                   const float* __restrict__ w2, const float* __restrict__ b2,
                   const float* __restrict__ w3, const float* __restrict__ b3,
                   float* __restrict__ outAlpha)
{
  const int row = blockIdx.x * 256 + threadIdx.x;
  const float* sr = state + (size_t)row * Sz;
  float h1[64];
#pragma unroll
  for (int j = 0; j < 64; ++j) h1[j] = b1[j];
  for (int k = 0; k < Sz; ++k) {
    const float a = sr[k];
    const float* wr = w1 + (size_t)k * 64;
#pragma unroll
    for (int j = 0; j < 64; ++j) h1[j] = fmaf(a, wr[j], h1[j]);
  }
#pragma unroll
  for (int j = 0; j < 64; ++j) h1[j] = fmaxf(h1[j], 0.f);
  float h2[64];
#pragma unroll
  for (int j = 0; j < 64; ++j) h2[j] = b2[j];
#pragma unroll
  for (int k = 0; k < 64; ++k) {
    const float a = h1[k];
    const float* wr = w2 + (size_t)k * 64;
#pragma unroll
    for (int j = 0; j < 64; ++j) h2[j] = fmaf(a, wr[j], h2[j]);
  }
#pragma unroll
  for (int j = 0; j < 64; ++j) h2[j] = fmaxf(h2[j], 0.f);
  float z[4];
#pragma unroll
  for (int a = 0; a < 4; ++a) {
    float s = b3[a];
#pragma unroll
    for (int k = 0; k < 64; ++k) s = fmaf(h2[k], w3[k * 4 + a], s);
    s = fminf(fmaxf(s, -20.f), 20.f);
    z[a] = s + gn[(size_t)row * 4 + a];   // TAU = 1
  }
  float mz = z[0];
#pragma unroll
  for (int a = 1; a < 4; ++a) mz = fmaxf(mz, z[a]);
  float e[4]; float se = 0.f;
#pragma unroll
  for (int a = 0; a < 4; ++a) { e[a] = expf(z[a] - mz); se += e[a]; }
  const float inv = 1.f / se;
  float y[4];
#pragma unroll
  for (int a = 0; a < 4; ++a) y[a] = e[a] * inv;
  int am = 0;
#pragma unroll
  for (int a = 1; a < 4; ++a) if (y[a] > y[am]) am = a;
#pragma unroll
  for (int a = 0; a < 4; ++a) {
    const float hard = (a == am) ? 1.f : 0.f;
    outAlpha[(size_t)row * 4 + a] = y[a] + (hard - y[a]);
  }
}

// critic head, coalesced: 128 blocks, wave handles 16 rows, lane = 4 cols
__global__ __launch_bounds__(256)
void critic_head(const float* __restrict__ c2, const float* __restrict__ w3,
                 const float* __restrict__ b3, float* __restrict__ outv)
{
  const int t = threadIdx.x;
  const int w = t >> 6, lane = t & 63;
  const int row0 = blockIdx.x * 64 + w * 16;
  float wv[4];
  *(float4*)&wv[0] = *(const float4*)&w3[lane * 4];
  const float b0 = b3[0];
#pragma unroll
  for (int rr = 0; rr < 16; ++rr) {
    const int row = row0 + rr;
    float4 x = *(const float4*)&c2[(size_t)row * 256 + lane * 4];
    float s = x.x * wv[0] + x.y * wv[1] + x.z * wv[2] + x.w * wv[3];
#pragma unroll
    for (int d = 32; d; d >>= 1) s += __shfl_down(s, d, 64);
    if (lane == 0) outv[row] = s + b0;
  }
}

// all-4 actor heads fused; 32 rows/block (256 blocks = full GPU)
struct HeadP { const float* w3[4]; const float* b3[4]; };

__global__ __launch_bounds__(256)
void actor_head4(const float* __restrict__ x2g, HeadP p,
                 const float* __restrict__ alpha, float* __restrict__ outL)
{
  __shared__ float wsm[4][128 * 23];
  __shared__ float bs[4][23];
  const int t = threadIdx.x;
#pragma unroll
  for (int a = 0; a < 4; ++a) {
    for (int i = t; i < 128 * 23; i += 256) wsm[a][i] = p.w3[a][i];
    if (t < 23) bs[a][t] = p.b3[a][t];
  }
  __syncthreads();
  const int row = blockIdx.x * 32 + (t >> 3);
  const int cg = t & 7;
  float sum[3] = {0.f, 0.f, 0.f};
#pragma unroll
  for (int a = 0; a < 4; ++a) {
    const float al = alpha[(size_t)row * 4 + a];
    const float* xr = x2g + (size_t)a * Bz * 128 + (size_t)row * 128;
    float acc[3] = {0.f, 0.f, 0.f};
    for (int kk = 0; kk < 128; ++kk) {
      const float xa = xr[kk];
#pragma unroll
      for (int j = 0; j < 3; ++j) {
        const int col = cg + 8 * j;
        if (col < 23) acc[j] = fmaf(xa, wsm[a][kk * 23 + col], acc[j]);
      }
    }
#pragma unroll
    for (int j = 0; j < 3; ++j) {
      const int col = cg + 8 * j;
      if (col < 23) sum[j] += al * (acc[j] + bs[a][col]);
    }
  }
#pragma unroll
  for (int j = 0; j < 3; ++j) {
    const int col = cg + 8 * j;
    if (col < 23) outL[(size_t)row * 23 + col] = sum[j];
  }
}

// =====================================================================
extern "C" void kernel_launch(void* const* d_in, const int* in_sizes, int n_in,
                              void* d_out, int out_size, void* d_ws, size_t ws_size,
                              hipStream_t stream)
{
  const float* state  = (const float*)d_in[0];
  const float* gumbel = (const float*)d_in[1];
  const float* keys   = (const float*)d_in[2];
  const float* se_w1 = (const float*)d_in[3];
  const float* se_b1 = (const float*)d_in[4];
  const float* se_w2 = (const float*)d_in[5];
  const float* se_b2 = (const float*)d_in[6];
  const float* se_w3 = (const float*)d_in[7];
  const float* se_b3 = (const float*)d_in[8];
  const float* se_g  = (const float*)d_in[9];
  const float* se_be = (const float*)d_in[10];
  const float* cc_w1 = (const float*)d_in[11];
  const float* cc_b1 = (const float*)d_in[12];
  const float* cc_w2 = (const float*)d_in[13];
  const float* cc_b2 = (const float*)d_in[14];
  const float* cc_g  = (const float*)d_in[15];
  const float* cc_be = (const float*)d_in[16];
  const float* r_w1 = (const float*)d_in[57];
  const float* r_b1 = (const float*)d_in[58];
  const float* r_w2 = (const float*)d_in[59];
  const float* r_b2 = (const float*)d_in[60];
  const float* r_w3 = (const float*)d_in[61];
  const float* r_b3 = (const float*)d_in[62];
  const float* c_w1 = (const float*)d_in[63];
  const float* c_b1 = (const float*)d_in[64];
  const float* c_w2 = (const float*)d_in[65];
  const float* c_b2 = (const float*)d_in[66];
  const float* c_w3 = (const float*)d_in[67];
  const float* c_b3 = (const float*)d_in[68];

  // ---- workspace layout ----
  float* wsf = (float*)d_ws;
  const size_t qF = (size_t)Bz * Ez;          // 25,165,824 floats
  const size_t uF = (size_t)16777216;         // union region, floats
  float* q = wsf;
  float* U = wsf + qF;
  // U internal (time-multiplexed), float offsets:
  ushort_t* sAh  = (ushort_t*)(U + 0);          // 8192x512 halves
  ushort_t* sAl  = (ushort_t*)(U + 2097152);
  ushort_t* sBh  = (ushort_t*)(U + 4194304);
  ushort_t* sBl  = (ushort_t*)(U + 6291456);
  ushort_t* w3hT = (ushort_t*)(U + 8388608);    // 3072x512 halves
  ushort_t* w3lT = (ushort_t*)(U + 9175040);
  ushort_t* w2hT = (ushort_t*)(U + 9961472);    // 512x512 halves
  ushort_t* w2lT = (ushort_t*)(U + 10092544);
  // fallback path fp32 buffers (same region, stream-ordered):
  float* sA = U;                                 // 8192x512 fp32 (fallback)
  float* sB = U + 4194304;                       // 8192x512 fp32 (fallback)
  ushort_t* scoresU = (ushort_t*)U;              // 8192x4096 u16 (whole U)
  ushort_t* ctxb = (ushort_t*)U;                 // bf16 ctx (8192x3072 halves),
                                                 // overlays dead scores post-topk
  float* cch = U + 12582912;                     // 8192x512 fp32
  float* shr = U;                                // 8192x128 (post-ctx phase)
  float* x1g = U + 1 * 1048576;                  // 4 x 8192x128
  float* x2g = U + 5 * 1048576;                  // 4 x 8192x128
  // critic temporaries in the (not yet written) q region:
  float* cr1 = q;                                // 8192x256
  float* cr2 = q + 2097152;                      // 8192x256
  // fast-path bf16 buffers after U:
  ushort_t* qbf  = (ushort_t*)(wsf + qF + uF);   // 8192x3072
  ushort_t* knbf = qbf + qF;                     // 4096x3072
  ushort_t* w1T  = knbf + (size_t)NEz * Ez;      // 512x3072
  const size_t bfHalves = qF + (size_t)NEz * Ez + (size_t)512 * Ez;
  const size_t baseBytes = (qF + uF) * sizeof(float);
  const size_t tailBytes = 4096 * 4 + (size_t)Bz * 16 * 4;
  const bool fast = ws_size >= baseBytes + bfHalves * 2 + tailBytes;
  float* tailF = (float*)((char*)d_ws + (fast ? baseBytes + bfHalves * 2 : baseBytes));
  float* rk  = tailF;
  int* cand  = (int*)(tailF + 4096);

  float* outL = (float*)d_out;                 // 8192*23
  float* outA = outL + (size_t)Bz * 23;        // 8192*4
  float* outV = outA + (size_t)Bz * 4;         // 8192*1

  const dim3 blk(256);

  // --- encoder L1 (hi/lo split out on fast path) + critic L1 ---
  {
    GPart e0 = {state, se_w1, se_b1, fast ? nullptr : sA,
                fast ? sAh : nullptr, fast ? sAl : nullptr, 512, 115, 4};
    GPart e1 = {state, c_w1, c_b1, cr1, nullptr, nullptr, 256, 115, 2};
    gemm128_dual<<<dim3(6, 64), blk, 0, stream>>>(e0, e1);
  }
  // --- critic L2 (fp32) ---
  gemm128<true, true><<<dim3(2, 64), blk, 0, stream>>>(cr1, c_w2, c_b2, cr2, 256, 256);

  if (fast) {
    // combined weight transpose+split (se_w2 + se_w3)
    wt_split2<<<dim3(8, 56), blk, 0, stream>>>(se_w2, w2hT, w2lT, se_w3, w3hT, w3lT);
    // encoder L2 via bf16x3 MFMA: relu + hi/lo split out
    mfma3_bt<1><<<dim3(4, 64), blk, 0, stream>>>(sAh, sAl, w2hT, w2lT, se_b2,
                                                 nullptr, sBh, sBl, 512, 512);
  } else {
    gemm128<true, true><<<dim3(4, 64), blk, 0, stream>>>(sA, se_w2, se_b2, sB, 512, 512);
  }

  // critic head + router (cr1/cr2 die before q is written)
  critic_head<<<dim3(128), blk, 0, stream>>>(cr2, c_w3, c_b3, outV);
  router_kernel<<<dim3(32), blk, 0, stream>>>(state, gumbel, r_w1, r_b1, r_w2, r_b2,
                                              r_w3, r_b3, outA);

  if (fast) {
    // encoder L3 (se_w3) via bf16x3 MFMA -> q fp32
    mfma3_bt<0><<<dim3(24, 64), blk, 0, stream>>>(sBh, sBl, w3hT, w3lT, se_b3,
                                                  q, nullptr, nullptr, 3072, 512);
    // fused: q LN+L2+bf16 and keys norm+bf16 in one launch
    norm_cvt_fused<<<dim3(Bz + NEz), blk, 0, stream>>>(q, se_g, se_be, qbf,
                                                       keys, rk, knbf);
    cvt_w1t_t<<<dim3(48, 8), blk, 0, stream>>>(cc_w1, w1T);
    // screen: 256x256-tile 4-phase, single barrier per phase
    screen256<<<dim3(16, 32), dim3(512), 0, stream>>>(qbf, knbf, scoresU, NEz, Ez);
  } else {
    gemm128<false, true><<<dim3(24, 64), blk, 0, stream>>>(sB, se_w3, se_b3, q, 3072, 512);
    ln_l2_q<<<dim3(Bz), blk, 0, stream>>>(q, se_g, se_be);
    keynorm<<<dim3(NEz), blk, 0, stream>>>(keys, rk);
    gemm_scores<<<dim3(32, 64), blk, 0, stream>>>(q, keys, rk, scoresU);
  }

  // --- top-16 screen, fused fp64 rescore + top-10 set + context gather ---
  topk16<<<dim3(Bz), blk, 0, stream>>>(scoresU, cand);

  // --- context + compressor ---
  if (fast) {
    // ctx -> ctxb in U (scores dead after topk; NO aliasing with q)
    rescore_gather<true><<<dim3(Bz), blk, 0, stream>>>(q, keys, rk, cand, ctxb);
    mfma_bt64<<<dim3(4, 128), blk, 0, stream>>>(ctxb, w1T, cc_b1, cch, 512, Ez);
  } else {
    // fallback: ctx fp32 overlays q row-for-row (self-row only: safe)
    rescore_gather<false><<<dim3(Bz), blk, 0, stream>>>(q, keys, rk, cand, q);
    gemm128<true, true><<<dim3(4, 64), blk, 0, stream>>>(q, cc_w1, cc_b1, cch, 512, Ez);
  }
  {
    LN4 pcc = {};
    pcc.W[0] = cc_w2; pcc.b[0] = cc_b2; pcc.g[0] = cc_g; pcc.be[0] = cc_be;
    gemm_ln4<false, false><<<dim3(128, 1), blk, 0, stream>>>(cch, 0, 512, nullptr, pcc,
                                                             shr, 0);
  }

  // --- actors (batched over blockIdx.y) ---
  {
    LN4 p1 = {}, p2 = {};
    HeadP ph = {};
    const int eoffs[4] = {0, 20, 40, 45};
    const int elens[4] = {50, 20, 10, 15};
    for (int a = 0; a < 4; ++a) {
      const int base = 17 + 10 * a;
      p1.W[a]  = (const float*)d_in[base + 0];
      p1.b[a]  = (const float*)d_in[base + 1];
      p1.g[a]  = (const float*)d_in[base + 2];
      p1.be[a] = (const float*)d_in[base + 3];
      p1.eoff[a] = eoffs[a]; p1.elen[a] = elens[a];
      p2.W[a]  = (const float*)d_in[base + 4];
      p2.b[a]  = (const float*)d_in[base + 5];
      p2.g[a]  = (const float*)d_in[base + 6];
      p2.be[a] = (const float*)d_in[base + 7];
      ph.w3[a] = (const float*)d_in[base + 8];
      ph.b3[a] = (const float*)d_in[base + 9];
    }
    gemm_ln4<true, true ><<<dim3(128, 4), blk, 0, stream>>>(shr, 0, 128, state, p1,
                                                            x1g, (size_t)Bz * 128);
    gemm_ln4<true, false><<<dim3(128, 4), blk, 0, stream>>>(x1g, (size_t)Bz * 128, 128,
                                                            nullptr, p2,
                                                            x2g, (size_t)Bz * 128);
    actor_head4<<<dim3(256), blk, 0, stream>>>(x2g, ph, outA, outL);
  }
}